// Round 4
// baseline (5079.085 us; speedup 1.0000x reference)
//
#include <hip/hip_runtime.h>
#include <hip/hip_bf16.h>
#include <hip/hip_cooperative_groups.h>

namespace cg = cooperative_groups;

#define DEVINL __device__ __forceinline__

constexpr int B_   = 4;
constexpr int T_   = 2048;
constexpr int C_   = 1024;
constexpr int NTOK = B_ * T_;      // 8192
constexpr int HD   = 256;          // C_/4

typedef unsigned short u16;
typedef __attribute__((ext_vector_type(8))) short  frag_ab;  // 8 bf16 (4 VGPRs)
typedef __attribute__((ext_vector_type(4))) float  frag_cd;  // 4 fp32
typedef __attribute__((ext_vector_type(8))) u16    u16x8;
typedef __attribute__((ext_vector_type(4))) u16    u16x4;

DEVINL float bf2f(u16 u) {
    unsigned int x = ((unsigned int)u) << 16;
    return __uint_as_float(x);
}
DEVINL u16 f2bf(float f) {
    unsigned int x = __float_as_uint(f);
    unsigned int r = (x + 0x7fffu + ((x >> 16) & 1u)) >> 16;
    return (u16)r;
}
// f == bf2f(h) + bf2f(l) + O(2^-18 |f|); residual subtraction exact (Sterbenz).
DEVINL void split2(float f, u16& h, u16& l) {
    h = f2bf(f);
    l = f2bf(f - bf2f(h));
}
DEVINL float wave_reduce(float v) {
    #pragma unroll
    for (int off = 32; off > 0; off >>= 1) v += __shfl_down(v, off, 64);
    return v;
}
DEVINL void gl_lds16(const void* g, void* l) {
    __builtin_amdgcn_global_load_lds(
        (const __attribute__((address_space(1))) unsigned int*)g,
        (__attribute__((address_space(3))) unsigned int*)l, 16, 0, 0);
}

// XCD-aware remap for (8,64) grids: hw%8 = XCD (round-robin); give each XCD
// 8 M-panels x 8 N-cols so its A footprint (4MB split / 2MB bf16) is L2-resident
// and each A panel is fetched by exactly one XCD (was 8x over-fetch).
DEVINL void swizzle_block(int& bx, int& by) {
    const int hw = (int)(blockIdx.x + gridDim.x * blockIdx.y);
    if (gridDim.x == 8 && gridDim.y == 64) {
        const int xcd = hw & 7, idx = hw >> 3;
        by = xcd * 8 + (idx & 7);
        bx = idx >> 3;
    } else { bx = blockIdx.x; by = blockIdx.y; }
}

// ---------------------------------------------------------------------------
// dtype auto-detect (flag: 1 = bf16 inputs, 0 = f32 inputs)
// ---------------------------------------------------------------------------
__global__ __launch_bounds__(256) void detect_k(const u16* __restrict__ w,
                                                int* __restrict__ flag)
{
    int tid = threadIdx.x;
    int cnt = 0;
    for (int i = tid; i < 4096; i += 256) {
        u16 u = w[2 * i];
        int e = (u >> 7) & 0xFF;
        if (u == 0 || (e >= 96 && e <= 134)) cnt++;
    }
    __shared__ int sh[256];
    sh[tid] = cnt; __syncthreads();
    for (int s = 128; s > 0; s >>= 1) {
        if (tid < s) sh[tid] += sh[tid + s];
        __syncthreads();
    }
    if (tid == 0) *flag = (sh[0] > 2048) ? 1 : 0;
}

__global__ __launch_bounds__(256) void conv_k(const void* __restrict__ src,
                                              float* __restrict__ dst, int n,
                                              const int* __restrict__ flag)
{
    int i = blockIdx.x * 256 + threadIdx.x;
    if (i >= n) return;
    if (*flag) dst[i] = bf2f(((const u16*)src)[i]);
    else       dst[i] = ((const float*)src)[i];
}

// src(flag dtype) -> split hi/lo, 4 elems/thread
__global__ __launch_bounds__(256) void conv_split_k(const void* __restrict__ src,
                                                    u16* __restrict__ H,
                                                    u16* __restrict__ L, int n4,
                                                    const int* __restrict__ flag)
{
    int i = blockIdx.x * 256 + threadIdx.x;
    if (i >= n4) return;
    float f[4];
    if (*flag) {
        u16x4 u = ((const u16x4*)src)[i];
        f[0] = bf2f(u[0]); f[1] = bf2f(u[1]); f[2] = bf2f(u[2]); f[3] = bf2f(u[3]);
    } else {
        float4 v = ((const float4*)src)[i];
        f[0] = v.x; f[1] = v.y; f[2] = v.z; f[3] = v.w;
    }
    u16x4 h, lo;
    #pragma unroll
    for (int r = 0; r < 4; ++r) { u16 a, b; split2(f[r], a, b); h[r] = a; lo[r] = b; }
    ((u16x4*)H)[i] = h; ((u16x4*)L)[i] = lo;
}

// src(flag dtype) -> plain bf16, 4 elems/thread
__global__ __launch_bounds__(256) void convb_k(const void* __restrict__ src,
                                               u16* __restrict__ out, int n4,
                                               const int* __restrict__ flag)
{
    int i = blockIdx.x * 256 + threadIdx.x;
    if (i >= n4) return;
    u16x4 o;
    if (*flag) {
        o = ((const u16x4*)src)[i];
    } else {
        float4 v = ((const float4*)src)[i];
        o[0] = f2bf(v.x); o[1] = f2bf(v.y); o[2] = f2bf(v.z); o[3] = f2bf(v.w);
    }
    ((u16x4*)out)[i] = o;
}

__global__ __launch_bounds__(256) void sumsq_k(const float* __restrict__ X,
                                               float* __restrict__ sumsq)
{
    int i = blockIdx.x * 256 + threadIdx.x;
    float f = X[i];
    float p = wave_reduce(f * f);
    __shared__ float r[4];
    int lane = threadIdx.x & 63, w = threadIdx.x >> 6;
    if (lane == 0) r[w] = p;
    __syncthreads();
    if (threadIdx.x == 0) atomicAdd(sumsq, r[0] + r[1] + r[2] + r[3]);
}

__global__ __launch_bounds__(256) void scale_k(float* __restrict__ X,
                                               const float* __restrict__ sumsq)
{
    int i = blockIdx.x * 256 + threadIdx.x;
    float F = sqrtf(*sumsq);
    float s = 16.0f / (1.1f * F);   // Gaussian: sigma_max ~= F/16; 10% margin
    X[i] *= s;
}

// plain f32 -> split (scalar, small arrays)
__global__ __launch_bounds__(256) void split_k(const float* __restrict__ X,
                                               u16* __restrict__ H,
                                               u16* __restrict__ L, int n)
{
    int i = blockIdx.x * 256 + threadIdx.x;
    if (i >= n) return;
    u16 hi, lo; split2(X[i], hi, lo);
    H[i] = hi; L[i] = lo;
}

// Th/Tl[n*C_+k] = split(W[k*C_+n])  — LDS 32x32 tile transpose (initial only)
__global__ __launch_bounds__(256) void transpose_split_k(
    const float* __restrict__ W, u16* __restrict__ Th, u16* __restrict__ Tl)
{
    __shared__ float tile[32][33];
    const int k0 = blockIdx.y * 32;
    const int n0 = blockIdx.x * 32;
    const int tx = threadIdx.x & 31, ty = threadIdx.x >> 5;   // 32 x 8
    #pragma unroll
    for (int r = 0; r < 32; r += 8)
        tile[ty + r][tx] = W[(size_t)(k0 + ty + r) * C_ + n0 + tx];
    __syncthreads();
    #pragma unroll
    for (int r = 0; r < 32; r += 8) {
        float f = tile[tx][ty + r];                 // = W[k0+tx][n0+ty+r]
        size_t idx = (size_t)(n0 + ty + r) * C_ + k0 + tx;
        u16 hi, lo; split2(f, hi, lo);
        Th[idx] = hi; Tl[idx] = lo;
    }
}

// ---------------------------------------------------------------------------
// NS tile GEMM body (device fn): acc[m,n] = sum_k A[m,k]*B[n,k], 64x64 tile,
// BK=64 panel layout, 4-term split (hh+lh+hl+ll), double-buffered 2-phase.
// EXACT same MFMA ordering as round-3 gemm_split64 (bit-identical results).
// smem: 4 arrays x [2][2][64][32] u16 = 64 KB total.
// ---------------------------------------------------------------------------
DEVINL void ns_gemm_tile(const u16* __restrict__ Ah, const u16* __restrict__ Al,
                         const u16* __restrict__ Bh, const u16* __restrict__ Bl,
                         u16* __restrict__ smem, int bm, int bn, int tid,
                         frag_cd (&acc)[2][2])
{
    u16* sAh = smem;             // each array: 2(dbuf)*2(ks)*64*32 = 8192 u16
    u16* sAl = smem + 8192;
    u16* sBh = smem + 16384;
    u16* sBl = smem + 24576;

    const int l = tid & 63;
    const int w = tid >> 6;
    const int mbase = (w & 1) * 32, nbase = (w >> 1) * 32;
    const int lrow = l & 15, kq = (l >> 4) << 3;

    #pragma unroll
    for (int i = 0; i < 2; ++i)
        #pragma unroll
        for (int j = 0; j < 2; ++j)
            #pragma unroll
            for (int r = 0; r < 4; ++r) acc[i][j][r] = 0.0f;

    auto STAGE = [&](int buf, int k0) {
        #pragma unroll
        for (int half = 0; half < 2; ++half) {
            const int c   = tid + half * 256;
            const int row = (c >> 2) & 63;
            const int ko  = half * 32 + (c & 3) * 8;
            const size_t ga = (size_t)(bm + row) * C_ + k0 + ko;
            const size_t gb = (size_t)(bn + row) * C_ + k0 + ko;
            gl_lds16(Ah + ga, sAh + buf * 4096 + (c << 3));
            gl_lds16(Al + ga, sAl + buf * 4096 + (c << 3));
            gl_lds16(Bh + gb, sBh + buf * 4096 + (c << 3));
            gl_lds16(Bl + gb, sBl + buf * 4096 + (c << 3));
        }
    };

    STAGE(0, 0);
    __syncthreads();
    constexpr int NT = C_ >> 6;   // 16
    int cur = 0;
    for (int t = 0; t < NT; ++t) {
        if (t + 1 < NT) STAGE(cur ^ 1, (t + 1) << 6);
        #pragma unroll
        for (int ks = 0; ks < 2; ++ks) {
            frag_ab ah[2], al2[2], bh[2], bl2[2];
            #pragma unroll
            for (int i = 0; i < 2; ++i) {
                const int ro = (mbase + 16 * i + lrow) * 32 + ks * 2048 + cur * 4096;
                ah[i]  = *(const frag_ab*)&sAh[ro + kq];
                al2[i] = *(const frag_ab*)&sAl[ro + kq];
            }
            #pragma unroll
            for (int j = 0; j < 2; ++j) {
                const int ro = (nbase + 16 * j + lrow) * 32 + ks * 2048 + cur * 4096;
                bh[j]  = *(const frag_ab*)&sBh[ro + kq];
                bl2[j] = *(const frag_ab*)&sBl[ro + kq];
            }
            #pragma unroll
            for (int i = 0; i < 2; ++i)
                #pragma unroll
                for (int j = 0; j < 2; ++j) {
                    acc[i][j] = __builtin_amdgcn_mfma_f32_16x16x32_bf16(
                        ah[i], bh[j], acc[i][j], 0, 0, 0);
                    acc[i][j] = __builtin_amdgcn_mfma_f32_16x16x32_bf16(
                        al2[i], bh[j], acc[i][j], 0, 0, 0);
                    acc[i][j] = __builtin_amdgcn_mfma_f32_16x16x32_bf16(
                        ah[i], bl2[j], acc[i][j], 0, 0, 0);
                    acc[i][j] = __builtin_amdgcn_mfma_f32_16x16x32_bf16(
                        al2[i], bl2[j], acc[i][j], 0, 0, 0);
                }
        }
        __syncthreads();
        cur ^= 1;
    }
}

// ---------------------------------------------------------------------------
// Persistent cooperative Newton-Schulz: 23 iterations, 2 grid syncs each.
// Grid = 256 blocks (one 64^2 tile each). Phase G: G = X^T X (A=B=W^T split).
// Phase Y: Y = a*X + b*(X G); epilogue writes Yf f32, row-split (next X) and
// LDS-transposed split (next W^T / final scan W^T). Replaces 69 kernel
// launches; W bit-identical to the discrete-launch version.
// ---------------------------------------------------------------------------
__global__ __launch_bounds__(256) void ns_k(
    u16* __restrict__ WTh, u16* __restrict__ WTl,
    u16* __restrict__ X0h, u16* __restrict__ X0l,
    u16* __restrict__ X1h, u16* __restrict__ X1l,
    u16* __restrict__ Gh,  u16* __restrict__ Gl,
    float* __restrict__ W0, float* __restrict__ W1)
{
    cg::grid_group grid = cg::this_grid();
    __shared__ u16 smem[32768];   // 64 KB

    const int b  = (int)blockIdx.x;
    const int bx = b & 15, by = b >> 4;
    const int bm = by * 64, bn = bx * 64;
    const int tid = threadIdx.x;
    const int l = tid & 63, w = tid >> 6;
    const int mbase = (w & 1) * 32, nbase = (w >> 1) * 32;
    const int lrow = l & 15, kq = (l >> 4) << 3;
    const int quad = l >> 4;

    u16* tileH = smem;            // 64*68 u16 (aliases staging; dead at epilogue)
    u16* tileL = smem + 4352;

    u16*   Xh[2] = { X0h, X1h };
    u16*   Xl[2] = { X0l, X1l };
    float* Wf[2] = { W0, W1 };
    int cur = 0, wf = 0;

    frag_cd acc[2][2];
    for (int it = 0; it < 23; ++it) {
        const bool polish = (it >= 18);
        const float aco = polish ? 1.5f : 2.0f;
        const float bco = polish ? -0.5f : -1.0f;

        // ---- Phase G: G = X^T X ----
        ns_gemm_tile(WTh, WTl, WTh, WTl, smem, bm, bn, tid, acc);
        #pragma unroll
        for (int i = 0; i < 2; ++i)
            #pragma unroll
            for (int j = 0; j < 2; ++j) {
                const int coln = bn + nbase + 16 * j + lrow;
                #pragma unroll
                for (int r = 0; r < 4; ++r) {
                    const int rowm = bm + mbase + 16 * i + quad * 4 + r;
                    const size_t idx = (size_t)rowm * C_ + coln;
                    u16 hi, lo; split2(acc[i][j][r], hi, lo);
                    Gh[idx] = hi; Gl[idx] = lo;
                }
            }
        __threadfence();
        grid.sync();

        // ---- Phase Y: Y = aco*X + bco*(X G)  (G symmetric -> B=G row-major) ----
        ns_gemm_tile(Xh[cur], Xl[cur], Gh, Gl, smem, bm, bn, tid, acc);
        const float* D  = Wf[wf];
        float*       Yf = Wf[wf ^ 1];
        u16* Nh = Xh[cur ^ 1];
        u16* Nl = Xl[cur ^ 1];
        #pragma unroll
        for (int i = 0; i < 2; ++i)
            #pragma unroll
            for (int j = 0; j < 2; ++j) {
                const int coln = bn + nbase + 16 * j + lrow;
                #pragma unroll
                for (int r = 0; r < 4; ++r) {
                    const int rowm = bm + mbase + 16 * i + quad * 4 + r;
                    const size_t idx = (size_t)rowm * C_ + coln;
                    float v = bco * acc[i][j][r] + aco * D[idx];
                    Yf[idx] = v;
                    u16 hi, lo; split2(v, hi, lo);
                    Nh[idx] = hi; Nl[idx] = lo;
                    const int rl = mbase + 16 * i + quad * 4 + r;   // local row
                    const int cl = nbase + 16 * j + lrow;           // local col
                    tileH[rl * 68 + cl] = hi;
                    tileL[rl * 68 + cl] = lo;
                }
            }
        __syncthreads();
        // transposed coalesced write: WT[(bn+jj)*C + bm+ii] = tile[ii][jj]
        {
            const int jj  = tid >> 2;          // 0..63
            const int ii0 = (tid & 3) << 4;    // 0,16,32,48
            u16x8 ph0, ph1, pl0, pl1;
            #pragma unroll
            for (int e = 0; e < 8; ++e) {
                ph0[e] = tileH[(ii0 + e) * 68 + jj];
                pl0[e] = tileL[(ii0 + e) * 68 + jj];
                ph1[e] = tileH[(ii0 + 8 + e) * 68 + jj];
                pl1[e] = tileL[(ii0 + 8 + e) * 68 + jj];
            }
            const size_t tb = (size_t)(bn + jj) * C_ + bm + ii0;
            *(u16x8*)&WTh[tb]     = ph0;
            *(u16x8*)&WTh[tb + 8] = ph1;
            *(u16x8*)&WTl[tb]     = pl0;
            *(u16x8*)&WTl[tb + 8] = pl1;
        }
        __syncthreads();           // tile LDS dead before next iter's staging
        __threadfence();
        grid.sync();

        cur ^= 1; wf ^= 1;
    }
    // final: X f32 in W1 (23 flips), W^T split in WTh/WTl
}

// ---------------------------------------------------------------------------
// Scan split-bf16 MFMA GEMM: C[m,n] = sum_k A[m,k]*B[n,k], 3-term (bit-identical
// arithmetic to round-1 gemm_split). 128x128 tile, BK=32, double-buffered
// 2-phase prefetch (one barrier/k-step), XCD-swizzled blocks.
// ---------------------------------------------------------------------------
__global__ __launch_bounds__(256) void gemm_split(
    const u16* __restrict__ Ah, const u16* __restrict__ Al,
    const u16* __restrict__ Bh, const u16* __restrict__ Bl,
    float* __restrict__ Cf, u16* __restrict__ Ch, u16* __restrict__ Cl,
    int M, int N, int K)
{
    __shared__ u16 sAh[2][128][32];   // 16 KB each, 64 KB total
    __shared__ u16 sAl[2][128][32];
    __shared__ u16 sBh[2][128][32];
    __shared__ u16 sBl[2][128][32];

    int bx, by; swizzle_block(bx, by);
    const int bm = by * 128, bn = bx * 128;
    const int tid = threadIdx.x;
    const int l = tid & 63, w = tid >> 6;
    const int mbase = (w & 1) * 64, nbase = (w >> 1) * 64;
    const int lrow = l & 15, kq = (l >> 4) << 3;

    frag_cd acc[4][4];
    #pragma unroll
    for (int i = 0; i < 4; ++i)
        #pragma unroll
        for (int j = 0; j < 4; ++j)
            #pragma unroll
            for (int r = 0; r < 4; ++r) acc[i][j][r] = 0.0f;

    auto STAGE = [&](int buf, int k0) {
        #pragma unroll
        for (int half = 0; half < 2; ++half) {
            const int c   = tid + half * 256;
            const int row = c >> 2;
            const int ko  = (c & 3) << 3;
            const size_t ga = (size_t)(bm + row) * K + k0 + ko;
            const size_t gb = (size_t)(bn + row) * K + k0 + ko;
            gl_lds16(Ah + ga, &sAh[buf][0][0] + (c << 3));
            gl_lds16(Al + ga, &sAl[buf][0][0] + (c << 3));
            gl_lds16(Bh + gb, &sBh[buf][0][0] + (c << 3));
            gl_lds16(Bl + gb, &sBl[buf][0][0] + (c << 3));
        }
    };

    STAGE(0, 0);
    __syncthreads();
    const int NT = K >> 5;
    int cur = 0;
    for (int t = 0; t < NT; ++t) {
        if (t + 1 < NT) STAGE(cur ^ 1, (t + 1) << 5);
        frag_ab ah[4], al4[4], bh[4], bl4[4];
        #pragma unroll
        for (int i = 0; i < 4; ++i) {
            const int ro = mbase + 16 * i + lrow;
            ah[i]  = *(const frag_ab*)&sAh[cur][ro][kq];
            al4[i] = *(const frag_ab*)&sAl[cur][ro][kq];
        }
        #pragma unroll
        for (int j = 0; j < 4; ++j) {
            const int ro = nbase + 16 * j + lrow;
            bh[j]  = *(const frag_ab*)&sBh[cur][ro][kq];
            bl4[j] = *(const frag_ab*)&sBl[cur][ro][kq];
        }
        #pragma unroll
        for (int i = 0; i < 4; ++i)
            #pragma unroll
            for (int j = 0; j < 4; ++j) {
                acc[i][j] = __builtin_amdgcn_mfma_f32_16x16x32_bf16(
                    ah[i], bh[j], acc[i][j], 0, 0, 0);
                acc[i][j] = __builtin_amdgcn_mfma_f32_16x16x32_bf16(
                    al4[i], bh[j], acc[i][j], 0, 0, 0);
                acc[i][j] = __builtin_amdgcn_mfma_f32_16x16x32_bf16(
                    ah[i], bl4[j], acc[i][j], 0, 0, 0);
            }
        __syncthreads();
        cur ^= 1;
    }

    const int quad = l >> 4;
    #pragma unroll
    for (int i = 0; i < 4; ++i) {
        #pragma unroll
        for (int j = 0; j < 4; ++j) {
            const int coln = bn + nbase + 16 * j + lrow;
            #pragma unroll
            for (int r = 0; r < 4; ++r) {
                const int rowm = bm + mbase + 16 * i + quad * 4 + r;
                const size_t idx = (size_t)rowm * N + coln;
                float v = acc[i][j][r];
                if (Cf) Cf[idx] = v;
                if (Ch) { u16 hi, lo; split2(v, hi, lo); Ch[idx] = hi; Cl[idx] = lo; }
            }
        }
    }
}

// ---------------------------------------------------------------------------
// Plain bf16 MFMA GEMM (v, Y): C[m,n] = sum_k A[m,k]*B[n,k], A/B pre-converted
// u16 bf16 (pure global_load_lds staging). 128x128, BK=64 panel layout,
// double-buffered 2-phase, XCD swizzle.
// ---------------------------------------------------------------------------
__global__ __launch_bounds__(256) void gemm_bf16(
    const u16* __restrict__ Ab, const u16* __restrict__ Bb,
    void* __restrict__ Cdst, int cmode, const int* __restrict__ flag,
    int M, int N, int K)
{
    __shared__ u16 As[2][2][128][32];   // [dbuf][ks][row][k]  32 KB
    __shared__ u16 Bs[2][2][128][32];   // 64 KB total
    const int cbf = (cmode == 1) ? *flag : 0;

    int bx, by; swizzle_block(bx, by);
    const int bm = by * 128, bn = bx * 128;
    const int tid = threadIdx.x;
    const int l = tid & 63, w = tid >> 6;
    const int mbase = (w & 1) * 64, nbase = (w >> 1) * 64;
    const int lrow = l & 15, kq = (l >> 4) << 3;

    frag_cd acc[4][4];
    #pragma unroll
    for (int i = 0; i < 4; ++i)
        #pragma unroll
        for (int j = 0; j < 4; ++j)
            #pragma unroll
            for (int r = 0; r < 4; ++r) acc[i][j][r] = 0.0f;

    auto STAGE = [&](int buf, int k0) {
        #pragma unroll
        for (int half = 0; half < 4; ++half) {
            const int c   = tid + half * 256;
            const int ks  = c >> 9;
            const int row = (c >> 2) & 127;
            const int ko  = ks * 32 + (c & 3) * 8;
            const size_t ga = (size_t)(bm + row) * K + k0 + ko;
            const size_t gb = (size_t)(bn + row) * K + k0 + ko;
            gl_lds16(Ab + ga, &As[buf][0][0][0] + (c << 3));
            gl_lds16(Bb + gb, &Bs[buf][0][0][0] + (c << 3));
        }
    };

    STAGE(0, 0);
    __syncthreads();
    const int NT = K >> 6;
    int cur = 0;
    for (int t = 0; t < NT; ++t) {
        if (t + 1 < NT) STAGE(cur ^ 1, (t + 1) << 6);
        #pragma unroll
        for (int ks = 0; ks < 2; ++ks) {
            frag_ab a[4], b[4];
            #pragma unroll
            for (int i = 0; i < 4; ++i)
                a[i] = *(const frag_ab*)&As[cur][ks][mbase + 16 * i + lrow][kq];
            #pragma unroll
            for (int j = 0; j < 4; ++j)
                b[j] = *(const frag_ab*)&Bs[cur][ks][nbase + 16 * j + lrow][kq];
            #pragma unroll
            for (int i = 0; i < 4; ++i)
                #pragma unroll
                for (int j = 0; j < 4; ++j)
                    acc[i][j] = __builtin_amdgcn_mfma_f32_16x16x32_bf16(
                        a[i], b[j], acc[i][j], 0, 0, 0);
        }
        __syncthreads();
        cur ^= 1;
    }

    const int quad = l >> 4;
    #pragma unroll
    for (int i = 0; i < 4; ++i) {
        #pragma unroll
        for (int j = 0; j < 4; ++j) {
            const int coln = bn + nbase + 16 * j + lrow;
            #pragma unroll
            for (int r = 0; r < 4; ++r) {
                const int rowm = bm + mbase + 16 * i + quad * 4 + r;
                const size_t idx = (size_t)rowm * N + coln;
                float v = acc[i][j][r];
                if (cbf) ((u16*)Cdst)[idx] = f2bf(v);
                else     ((float*)Cdst)[idx] = v;
            }
        }
    }
}

// ---------------------------------------------------------------------------
// qv = bf16(recon(qh,ql) * v) — A operand for the Y GEMM
// ---------------------------------------------------------------------------
__global__ __launch_bounds__(256) void qvb_k(const u16* __restrict__ qh,
                                             const u16* __restrict__ ql,
                                             const float* __restrict__ V,
                                             u16* __restrict__ out, int n4)
{
    int i = blockIdx.x * 256 + threadIdx.x;
    if (i >= n4) return;
    u16x4 h = ((const u16x4*)qh)[i], lo = ((const u16x4*)ql)[i];
    float4 v = ((const float4*)V)[i];
    u16x4 o;
    o[0] = f2bf((bf2f(h[0]) + bf2f(lo[0])) * v.x);
    o[1] = f2bf((bf2f(h[1]) + bf2f(lo[1])) * v.y);
    o[2] = f2bf((bf2f(h[2]) + bf2f(lo[2])) * v.z);
    o[3] = f2bf((bf2f(h[3]) + bf2f(lo[3])) * v.w);
    ((u16x4*)out)[i] = o;
}

// store recon(q) into d_out at element offset (in float4/u16x4 units)
__global__ __launch_bounds__(256) void store_split_k(
    const u16* __restrict__ h, const u16* __restrict__ l,
    void* __restrict__ out, int n4, size_t off4,
    const int* __restrict__ flag)
{
    int i = blockIdx.x * 256 + threadIdx.x;
    if (i >= n4) return;
    u16x4 hh = ((const u16x4*)h)[i], ll = ((const u16x4*)l)[i];
    float4 f;
    f.x = bf2f(hh[0]) + bf2f(ll[0]);
    f.y = bf2f(hh[1]) + bf2f(ll[1]);
    f.z = bf2f(hh[2]) + bf2f(ll[2]);
    f.w = bf2f(hh[3]) + bf2f(ll[3]);
    if (*flag) {
        u16x4 o; o[0] = f2bf(f.x); o[1] = f2bf(f.y); o[2] = f2bf(f.z); o[3] = f2bf(f.w);
        ((u16x4*)out)[off4 + i] = o;
    } else {
        ((float4*)out)[off4 + i] = f;
    }
}

// idW[j] = sum_i identf[i] * W[i,j] — 64 blocks x 16 rows, atomic combine
__global__ __launch_bounds__(256) void idw2_k(
    const float* __restrict__ identf, const float* __restrict__ W,
    float* __restrict__ idW)
{
    const int b = blockIdx.x;
    const int j = threadIdx.x;
    float a0 = 0, a1 = 0, a2 = 0, a3 = 0;
    #pragma unroll
    for (int ii = 0; ii < 16; ++ii) {
        const int i = b * 16 + ii;
        const float s = identf[i];
        const float* row = W + (size_t)i * C_;
        a0 += s * row[j];
        a1 += s * row[j + 256];
        a2 += s * row[j + 512];
        a3 += s * row[j + 768];
    }
    atomicAdd(idW + j, a0);       atomicAdd(idW + j + 256, a1);
    atomicAdd(idW + j + 512, a2); atomicAdd(idW + j + 768, a3);
}

// ---------------------------------------------------------------------------
// scan combine: one block (256 threads) per token. UNCHANGED (proven).
// ---------------------------------------------------------------------------
__global__ __launch_bounds__(256) void combine2_k(
    const u16* __restrict__ curh, const u16* __restrict__ curl,
    const float* __restrict__ xW,
    const float* __restrict__ idW, const float* __restrict__ identf,
    u16* __restrict__ nxth, u16* __restrict__ nxtl, int d)
{
    const int token = blockIdx.x;
    const int t = token & (T_ - 1);
    const int j = threadIdx.x;
    const bool hl = (t >= d);
    const size_t rbase = (size_t)token * C_;
    const size_t lbase = hl ? (size_t)(token - d) * C_ : 0;
    const float* leftW  = hl ? xW + lbase : idW;
    const float* rightW = xW + rbase;

    float q[4], k[4], v[4];
    #pragma unroll
    for (int m = 0; m < 4; ++m) {
        const int off = m * HD + j;
        k[m] = bf2f(curh[rbase + off]) + bf2f(curl[rbase + off]);
        if (hl) q[m] = bf2f(curh[lbase + off]) + bf2f(curl[lbase + off]);
        else    q[m] = identf[off];
        v[m] = leftW[off] + rightW[off];
    }

    __shared__ float red[4][16];
    __shared__ float att[16];
    const int lane = j & 63, wid = j >> 6;

    #pragma unroll
    for (int a = 0; a < 4; ++a)
        #pragma unroll
        for (int b = 0; b < 4; ++b) {
            float p = wave_reduce(q[a] * k[b]);
            if (lane == 0) red[wid][a * 4 + b] = p;
        }
    __syncthreads();
    if (j < 16) red[0][j] = (red[0][j] + red[1][j] + red[2][j] + red[3][j]) * 0.0625f;
    __syncthreads();
    if (j < 4) {
        float s0 = red[0][j * 4 + 0], s1 = red[0][j * 4 + 1];
        float s2 = red[0][j * 4 + 2], s3 = red[0][j * 4 + 3];
        float mx = fmaxf(fmaxf(s0, s1), fmaxf(s2, s3));
        float e0 = __expf(s0 - mx), e1 = __expf(s1 - mx);
        float e2 = __expf(s2 - mx), e3 = __expf(s3 - mx);
        float inv = 1.0f / (e0 + e1 + e2 + e3);
        att[j * 4 + 0] = e0 * inv; att[j * 4 + 1] = e1 * inv;
        att[j * 4 + 2] = e2 * inv; att[j * 4 + 3] = e3 * inv;
    }
    __syncthreads();

    float z[4];
    #pragma unroll
    for (int a = 0; a < 4; ++a)
        z[a] = att[a * 4 + 0] * v[0] + att[a * 4 + 1] * v[1]
             + att[a * 4 + 2] * v[2] + att[a * 4 + 3] * v[3];

    #pragma unroll
    for (int a = 0; a < 4; ++a) {
        float p = wave_reduce(z[a] * z[a]);
        if (lane == 0) red[wid][a] = p;
    }
    __syncthreads();
    if (j < 4) {
        float ss = red[0][j] + red[1][j] + red[2][j] + red[3][j];
        att[j] = rsqrtf(ss * (1.0f / HD) + 1e-8f);
    }
    __syncthreads();

    #pragma unroll
    for (int m = 0; m < 4; ++m) {
        const int off = m * HD + j;
        float zn  = z[m] * att[m] * (1.0f / (float)(m + 1));
        float out = q[m] + zn;
        u16 hi, lo; split2(out, hi, lo);
        nxth[rbase + off] = hi;
        nxtl[rbase + off] = lo;
    }
}

// ---------------------------------------------------------------------------
extern "C" void kernel_launch(void* const* d_in, const int* in_sizes, int n_in,
                              void* d_out, int out_size, void* d_ws, size_t ws_size,
                              hipStream_t stream)
{
    const void* x     = d_in[0];
    const void* Wup   = d_in[1];
    const void* Wv    = d_in[2];
    const void* Wproj = d_in[3];
    const void* ident = d_in[4];
    const void* Wraw  = d_in[5];

    float* ws = (float*)d_ws;
    int*   flagp  = (int*)ws;                    // meta[0]
    float* sumsqp = ws + 1;                      // meta[1]
    float* W0     = ws + 256;                    // 1M f32
    float* W1     = W0 + (1 << 20);              // 1M f32
    float* identf = W1 + (1 << 20);              // 1024
    float* idW    = identf + 1024;               // 1024
    float* F1     = idW + 1024;                  // 8M f32 (xW / v scratch)
    u16*   WTh    = (u16*)(F1 + (size_t)NTOK * C_);  // W^T split hi (1M u16)
    u16*   WTl    = WTh + (1 << 20);
    u16*   WUh    = WTl + (1 << 20);             // Wup split / WVb
    u16*   WUl    = WUh + (1 << 20);             //            / WPb
    u16*   Q0h    = WUl + (1 << 20);             // q split dbuf A (8M u16 ea)
    u16*   Q0l    = Q0h + (size_t)NTOK * C_;
    u16*   Q1h    = Q0l + (size_t)NTOK * C_;     // q split dbuf B
    u16*   Q1l    = Q1h + (size_t)NTOK * C_;

    const int NC = C_ * C_;          // 1M
    const int NX = NTOK * C_;        // 8M

    // ---- dtype detection ----
    detect_k<<<1, 256, 0, stream>>>((const u16*)Wup, flagp);

    // ---- polar(W_raw): scale then persistent cooperative Newton-Schulz ----
    hipMemsetAsync(sumsqp, 0, sizeof(float), stream);
    conv_k<<<NC / 256, 256, 0, stream>>>(Wraw, W0, NC, flagp);
    sumsq_k<<<NC / 256, 256, 0, stream>>>(W0, sumsqp);
    scale_k<<<NC / 256, 256, 0, stream>>>(W0, sumsqp);

    // NS scratch aliases into the (currently dead) Q0 region
    u16* X0h = Q0h;
    u16* X0l = Q0h + (1 << 20);
    u16* X1h = Q0h + 2 * (1 << 20);
    u16* X1l = Q0h + 3 * (1 << 20);
    u16* Gh  = Q0h + 4 * (1 << 20);
    u16* Gl  = Q0h + 5 * (1 << 20);

    split_k<<<NC / 256, 256, 0, stream>>>(W0, X0h, X0l, NC);
    transpose_split_k<<<dim3(32, 32), 256, 0, stream>>>(W0, WTh, WTl);

    {
        void* nsargs[] = { (void*)&WTh, (void*)&WTl,
                           (void*)&X0h, (void*)&X0l,
                           (void*)&X1h, (void*)&X1l,
                           (void*)&Gh,  (void*)&Gl,
                           (void*)&W0,  (void*)&W1 };
        hipLaunchCooperativeKernel((void*)ns_k, dim3(256), dim3(256),
                                   nsargs, 0, stream);
    }
    // final X f32 in W1; W^T split in WTh/WTl

    conv_k<<<4, 256, 0, stream>>>(ident, identf, 1024, flagp);
    hipMemsetAsync(idW, 0, C_ * sizeof(float), stream);
    idw2_k<<<64, 256, 0, stream>>>(identf, W1, idW);

    const dim3 g128(C_ / 128, NTOK / 128);   // (8, 64)

    // ---- q0 = x @ Wup^T  (split-bf16 MFMA) ----
    conv_split_k<<<NX / 1024, 256, 0, stream>>>(x, Q1h, Q1l, NX / 4, flagp);
    conv_split_k<<<NC / 1024, 256, 0, stream>>>(Wup, WUh, WUl, NC / 4, flagp);
    gemm_split<<<g128, 256, 0, stream>>>(Q1h, Q1l, WUh, WUl,
                                         nullptr, Q0h, Q0l, NTOK, C_, C_);

    // ---- scan: 11 Hillis-Steele steps, q carried as split bf16 pairs ----
    u16 *ch = Q0h, *cl = Q0l, *nh = Q1h, *nl = Q1l;
    for (int d = 1; d < T_; d <<= 1) {
        gemm_split<<<g128, 256, 0, stream>>>(ch, cl, WTh, WTl,
                                             F1, nullptr, nullptr, NTOK, C_, C_);
        combine2_k<<<NTOK, 256, 0, stream>>>(ch, cl, F1, idW, identf, nh, nl, d);
        u16* t1 = ch; ch = nh; nh = t1;
        u16* t2 = cl; cl = nl; nl = t2;
    }
    // 11 steps (odd) -> ch/cl = Q1h/Q1l hold q; Q0*, F1, WU* free

    // ---- pre-convert weights / x to bf16 ----
    convb_k<<<NC / 1024, 256, 0, stream>>>(Wv,    WUh, NC / 4, flagp);   // WVb
    convb_k<<<NC / 1024, 256, 0, stream>>>(Wproj, WUl, NC / 4, flagp);   // WPb
    convb_k<<<NX / 1024, 256, 0, stream>>>(x,     Q0h, NX / 4, flagp);   // xb

    // ---- v = x @ Wv^T  (pure bf16 MFMA) -> F1 f32 ----
    gemm_bf16<<<g128, 256, 0, stream>>>(Q0h, WUh, F1, 0, flagp, NTOK, C_, C_);

    // ---- Y = (q .* v) @ Wproj^T -> d_out[0:NX] ----
    qvb_k<<<NX / 1024, 256, 0, stream>>>(ch, cl, F1, Q0l, NX / 4);
    gemm_bf16<<<g128, 256, 0, stream>>>(Q0l, WUl, d_out, 1, flagp, NTOK, C_, C_);

    // ---- second output: q ----
    store_split_k<<<NX / 1024, 256, 0, stream>>>(ch, cl, d_out, NX / 4,
                                                 (size_t)(NX / 4), flagp);
}

// Round 5
// 2310.459 us; speedup vs baseline: 2.1983x; 2.1983x over previous
//
#include <hip/hip_runtime.h>
#include <hip/hip_bf16.h>

#define DEVINL __device__ __forceinline__

constexpr int B_   = 4;
constexpr int T_   = 2048;
constexpr int C_   = 1024;
constexpr int NTOK = B_ * T_;      // 8192
constexpr int HD   = 256;          // C_/4

typedef unsigned short u16;
typedef __attribute__((ext_vector_type(8))) short  frag_ab;  // 8 bf16 (4 VGPRs)
typedef __attribute__((ext_vector_type(4))) float  frag_cd;  // 4 fp32
typedef __attribute__((ext_vector_type(8))) u16    u16x8;
typedef __attribute__((ext_vector_type(4))) u16    u16x4;

DEVINL float bf2f(u16 u) {
    unsigned int x = ((unsigned int)u) << 16;
    return __uint_as_float(x);
}
DEVINL u16 f2bf(float f) {
    unsigned int x = __float_as_uint(f);
    unsigned int r = (x + 0x7fffu + ((x >> 16) & 1u)) >> 16;
    return (u16)r;
}
// f == bf2f(h) + bf2f(l) + O(2^-18 |f|); residual subtraction exact (Sterbenz).
DEVINL void split2(float f, u16& h, u16& l) {
    h = f2bf(f);
    l = f2bf(f - bf2f(h));
}
DEVINL float wave_reduce(float v) {
    #pragma unroll
    for (int off = 32; off > 0; off >>= 1) v += __shfl_down(v, off, 64);
    return v;
}
DEVINL void gl_lds16(const void* g, void* l) {
    __builtin_amdgcn_global_load_lds(
        (const __attribute__((address_space(1))) unsigned int*)g,
        (__attribute__((address_space(3))) unsigned int*)l, 16, 0, 0);
}

// XCD-aware remap for (8,64) grids: hw%8 = XCD (round-robin); give each XCD
// 8 M-panels x 8 N-cols so its A footprint (4MB split / 2MB bf16) is L2-resident
// and each A panel is fetched by exactly one XCD (was 8x over-fetch).
DEVINL void swizzle_block(int& bx, int& by) {
    const int hw = (int)(blockIdx.x + gridDim.x * blockIdx.y);
    if (gridDim.x == 8 && gridDim.y == 64) {
        const int xcd = hw & 7, idx = hw >> 3;
        by = xcd * 8 + (idx & 7);
        bx = idx >> 3;
    } else { bx = blockIdx.x; by = blockIdx.y; }
}

// ---------------------------------------------------------------------------
// dtype auto-detect (flag: 1 = bf16 inputs, 0 = f32 inputs)
// ---------------------------------------------------------------------------
__global__ __launch_bounds__(256) void detect_k(const u16* __restrict__ w,
                                                int* __restrict__ flag)
{
    int tid = threadIdx.x;
    int cnt = 0;
    for (int i = tid; i < 4096; i += 256) {
        u16 u = w[2 * i];
        int e = (u >> 7) & 0xFF;
        if (u == 0 || (e >= 96 && e <= 134)) cnt++;
    }
    __shared__ int sh[256];
    sh[tid] = cnt; __syncthreads();
    for (int s = 128; s > 0; s >>= 1) {
        if (tid < s) sh[tid] += sh[tid + s];
        __syncthreads();
    }
    if (tid == 0) *flag = (sh[0] > 2048) ? 1 : 0;
}

__global__ __launch_bounds__(256) void conv_k(const void* __restrict__ src,
                                              float* __restrict__ dst, int n,
                                              const int* __restrict__ flag)
{
    int i = blockIdx.x * 256 + threadIdx.x;
    if (i >= n) return;
    if (*flag) dst[i] = bf2f(((const u16*)src)[i]);
    else       dst[i] = ((const float*)src)[i];
}

// src(flag dtype) -> split hi/lo, 4 elems/thread
__global__ __launch_bounds__(256) void conv_split_k(const void* __restrict__ src,
                                                    u16* __restrict__ H,
                                                    u16* __restrict__ L, int n4,
                                                    const int* __restrict__ flag)
{
    int i = blockIdx.x * 256 + threadIdx.x;
    if (i >= n4) return;
    float f[4];
    if (*flag) {
        u16x4 u = ((const u16x4*)src)[i];
        f[0] = bf2f(u[0]); f[1] = bf2f(u[1]); f[2] = bf2f(u[2]); f[3] = bf2f(u[3]);
    } else {
        float4 v = ((const float4*)src)[i];
        f[0] = v.x; f[1] = v.y; f[2] = v.z; f[3] = v.w;
    }
    u16x4 h, lo;
    #pragma unroll
    for (int r = 0; r < 4; ++r) { u16 a, b; split2(f[r], a, b); h[r] = a; lo[r] = b; }
    ((u16x4*)H)[i] = h; ((u16x4*)L)[i] = lo;
}

// src(flag dtype) -> plain bf16, 4 elems/thread
__global__ __launch_bounds__(256) void convb_k(const void* __restrict__ src,
                                               u16* __restrict__ out, int n4,
                                               const int* __restrict__ flag)
{
    int i = blockIdx.x * 256 + threadIdx.x;
    if (i >= n4) return;
    u16x4 o;
    if (*flag) {
        o = ((const u16x4*)src)[i];
    } else {
        float4 v = ((const float4*)src)[i];
        o[0] = f2bf(v.x); o[1] = f2bf(v.y); o[2] = f2bf(v.z); o[3] = f2bf(v.w);
    }
    ((u16x4*)out)[i] = o;
}

__global__ __launch_bounds__(256) void sumsq_k(const float* __restrict__ X,
                                               float* __restrict__ sumsq)
{
    int i = blockIdx.x * 256 + threadIdx.x;
    float f = X[i];
    float p = wave_reduce(f * f);
    __shared__ float r[4];
    int lane = threadIdx.x & 63, w = threadIdx.x >> 6;
    if (lane == 0) r[w] = p;
    __syncthreads();
    if (threadIdx.x == 0) atomicAdd(sumsq, r[0] + r[1] + r[2] + r[3]);
}

__global__ __launch_bounds__(256) void scale_k(float* __restrict__ X,
                                               const float* __restrict__ sumsq)
{
    int i = blockIdx.x * 256 + threadIdx.x;
    float F = sqrtf(*sumsq);
    float s = 16.0f / (1.1f * F);   // Gaussian: sigma_max ~= F/16; 10% margin
    X[i] *= s;
}

// plain f32 -> split (scalar, small arrays)
__global__ __launch_bounds__(256) void split_k(const float* __restrict__ X,
                                               u16* __restrict__ H,
                                               u16* __restrict__ L, int n)
{
    int i = blockIdx.x * 256 + threadIdx.x;
    if (i >= n) return;
    u16 hi, lo; split2(X[i], hi, lo);
    H[i] = hi; L[i] = lo;
}

// Th/Tl[n*C_+k] = split(W[k*C_+n])  — LDS 32x32 tile transpose (initial only)
__global__ __launch_bounds__(256) void transpose_split_k(
    const float* __restrict__ W, u16* __restrict__ Th, u16* __restrict__ Tl)
{
    __shared__ float tile[32][33];
    const int k0 = blockIdx.y * 32;
    const int n0 = blockIdx.x * 32;
    const int tx = threadIdx.x & 31, ty = threadIdx.x >> 5;   // 32 x 8
    #pragma unroll
    for (int r = 0; r < 32; r += 8)
        tile[ty + r][tx] = W[(size_t)(k0 + ty + r) * C_ + n0 + tx];
    __syncthreads();
    #pragma unroll
    for (int r = 0; r < 32; r += 8) {
        float f = tile[tx][ty + r];                 // = W[k0+tx][n0+ty+r]
        size_t idx = (size_t)(n0 + ty + r) * C_ + k0 + tx;
        u16 hi, lo; split2(f, hi, lo);
        Th[idx] = hi; Tl[idx] = lo;
    }
}

// ---------------------------------------------------------------------------
// NS split-bf16 MFMA GEMM: C[m,n] = beta*sum_k A[m,k]*B[n,k] + alpha*D[m,n]
// 64x64 tile, BK=64 panel layout, 4-term (hh+lh+hl+ll), double-buffered
// 2-phase prefetch. Optional epilogue outputs: f32 (Cf), row-major split
// (Ch/Cl), and LDS-transposed split (Th/Tl) — the transpose fold is lifted
// verbatim from the (numerically proven) round-4 ns_k epilogue and produces
// WT bit-identical to the separate transpose_split_k pass it replaces.
// ---------------------------------------------------------------------------
__global__ __launch_bounds__(256) void gemm_split64(
    const u16* __restrict__ Ah, const u16* __restrict__ Al,
    const u16* __restrict__ Bh, const u16* __restrict__ Bl,
    float* __restrict__ Cf, u16* __restrict__ Ch, u16* __restrict__ Cl,
    const float* __restrict__ D, float alpha, float beta,
    int M, int N, int K,
    u16* __restrict__ Th, u16* __restrict__ Tl)
{
    __shared__ u16 sAh[2][2][64][32];   // [dbuf][ks][row][k]  16 KB
    __shared__ u16 sAl[2][2][64][32];
    __shared__ u16 sBh[2][2][64][32];
    __shared__ u16 sBl[2][2][64][32];   // total 64 KB

    const int bm = blockIdx.y * 64, bn = blockIdx.x * 64;
    const int tid = threadIdx.x;
    const int l = tid & 63, w = tid >> 6;
    const int mbase = (w & 1) * 32, nbase = (w >> 1) * 32;
    const int lrow = l & 15, kq = (l >> 4) << 3;

    frag_cd acc[2][2];
    #pragma unroll
    for (int i = 0; i < 2; ++i)
        #pragma unroll
        for (int j = 0; j < 2; ++j)
            #pragma unroll
            for (int r = 0; r < 4; ++r) acc[i][j][r] = 0.0f;

    auto STAGE = [&](int buf, int k0) {
        #pragma unroll
        for (int half = 0; half < 2; ++half) {
            const int c   = tid + half * 256;
            const int row = (c >> 2) & 63;
            const int ko  = half * 32 + (c & 3) * 8;
            const size_t ga = (size_t)(bm + row) * K + k0 + ko;
            const size_t gb = (size_t)(bn + row) * K + k0 + ko;
            gl_lds16(Ah + ga, &sAh[0][0][0][0] + buf * 4096 + (c << 3));
            gl_lds16(Al + ga, &sAl[0][0][0][0] + buf * 4096 + (c << 3));
            gl_lds16(Bh + gb, &sBh[0][0][0][0] + buf * 4096 + (c << 3));
            gl_lds16(Bl + gb, &sBl[0][0][0][0] + buf * 4096 + (c << 3));
        }
    };

    STAGE(0, 0);
    __syncthreads();
    const int NT = K >> 6;
    int cur = 0;
    for (int t = 0; t < NT; ++t) {
        if (t + 1 < NT) STAGE(cur ^ 1, (t + 1) << 6);
        #pragma unroll
        for (int ks = 0; ks < 2; ++ks) {
            frag_ab ah[2], al2[2], bh[2], bl2[2];
            #pragma unroll
            for (int i = 0; i < 2; ++i) {
                const int ro = mbase + 16 * i + lrow;
                ah[i]  = *(const frag_ab*)&sAh[cur][ks][ro][kq];
                al2[i] = *(const frag_ab*)&sAl[cur][ks][ro][kq];
            }
            #pragma unroll
            for (int j = 0; j < 2; ++j) {
                const int ro = nbase + 16 * j + lrow;
                bh[j]  = *(const frag_ab*)&sBh[cur][ks][ro][kq];
                bl2[j] = *(const frag_ab*)&sBl[cur][ks][ro][kq];
            }
            #pragma unroll
            for (int i = 0; i < 2; ++i)
                #pragma unroll
                for (int j = 0; j < 2; ++j) {
                    acc[i][j] = __builtin_amdgcn_mfma_f32_16x16x32_bf16(
                        ah[i], bh[j], acc[i][j], 0, 0, 0);
                    acc[i][j] = __builtin_amdgcn_mfma_f32_16x16x32_bf16(
                        al2[i], bh[j], acc[i][j], 0, 0, 0);
                    acc[i][j] = __builtin_amdgcn_mfma_f32_16x16x32_bf16(
                        ah[i], bl2[j], acc[i][j], 0, 0, 0);
                    acc[i][j] = __builtin_amdgcn_mfma_f32_16x16x32_bf16(
                        al2[i], bl2[j], acc[i][j], 0, 0, 0);
                }
        }
        __syncthreads();
        cur ^= 1;
    }

    // epilogue (after final K-loop barrier: staging LDS is dead, reusable)
    const int quad = l >> 4;
    u16* tileH = &sAh[0][0][0][0];   // 64*68 u16 = 8.5 KB, fits in sAh
    u16* tileL = &sAl[0][0][0][0];
    #pragma unroll
    for (int i = 0; i < 2; ++i) {
        #pragma unroll
        for (int j = 0; j < 2; ++j) {
            const int coln = bn + nbase + 16 * j + lrow;
            #pragma unroll
            for (int r = 0; r < 4; ++r) {
                const int rowm = bm + mbase + 16 * i + quad * 4 + r;
                const size_t idx = (size_t)rowm * N + coln;
                float v = beta * acc[i][j][r];
                if (D) v += alpha * D[idx];
                if (Cf) Cf[idx] = v;
                u16 hi, lo; split2(v, hi, lo);
                if (Ch) { Ch[idx] = hi; Cl[idx] = lo; }
                if (Th) {
                    const int rl = mbase + 16 * i + quad * 4 + r;   // local row
                    const int cl = nbase + 16 * j + lrow;           // local col
                    tileH[rl * 68 + cl] = hi;
                    tileL[rl * 68 + cl] = lo;
                }
            }
        }
    }
    if (Th) {
        __syncthreads();
        // transposed coalesced write: T[(bn+jj)*N + bm+ii] = tile[ii][jj]
        const int jj  = tid >> 2;          // 0..63
        const int ii0 = (tid & 3) << 4;    // 0,16,32,48
        u16x8 ph0, ph1, pl0, pl1;
        #pragma unroll
        for (int e = 0; e < 8; ++e) {
            ph0[e] = tileH[(ii0 + e) * 68 + jj];
            pl0[e] = tileL[(ii0 + e) * 68 + jj];
            ph1[e] = tileH[(ii0 + 8 + e) * 68 + jj];
            pl1[e] = tileL[(ii0 + 8 + e) * 68 + jj];
        }
        const size_t tb = (size_t)(bn + jj) * N + bm + ii0;
        *(u16x8*)&Th[tb]     = ph0;
        *(u16x8*)&Th[tb + 8] = ph1;
        *(u16x8*)&Tl[tb]     = pl0;
        *(u16x8*)&Tl[tb + 8] = pl1;
    }
}

// ---------------------------------------------------------------------------
// Scan split-bf16 MFMA GEMM: C[m,n] = sum_k A[m,k]*B[n,k], 3-term (bit-identical
// arithmetic to round-1 gemm_split). 128x128 tile, BK=32, double-buffered
// 2-phase prefetch (one barrier/k-step), XCD-swizzled blocks.
// ---------------------------------------------------------------------------
__global__ __launch_bounds__(256) void gemm_split(
    const u16* __restrict__ Ah, const u16* __restrict__ Al,
    const u16* __restrict__ Bh, const u16* __restrict__ Bl,
    float* __restrict__ Cf, u16* __restrict__ Ch, u16* __restrict__ Cl,
    int M, int N, int K)
{
    __shared__ u16 sAh[2][128][32];   // 16 KB each, 64 KB total
    __shared__ u16 sAl[2][128][32];
    __shared__ u16 sBh[2][128][32];
    __shared__ u16 sBl[2][128][32];

    int bx, by; swizzle_block(bx, by);
    const int bm = by * 128, bn = bx * 128;
    const int tid = threadIdx.x;
    const int l = tid & 63, w = tid >> 6;
    const int mbase = (w & 1) * 64, nbase = (w >> 1) * 64;
    const int lrow = l & 15, kq = (l >> 4) << 3;

    frag_cd acc[4][4];
    #pragma unroll
    for (int i = 0; i < 4; ++i)
        #pragma unroll
        for (int j = 0; j < 4; ++j)
            #pragma unroll
            for (int r = 0; r < 4; ++r) acc[i][j][r] = 0.0f;

    auto STAGE = [&](int buf, int k0) {
        #pragma unroll
        for (int half = 0; half < 2; ++half) {
            const int c   = tid + half * 256;
            const int row = c >> 2;
            const int ko  = (c & 3) << 3;
            const size_t ga = (size_t)(bm + row) * K + k0 + ko;
            const size_t gb = (size_t)(bn + row) * K + k0 + ko;
            gl_lds16(Ah + ga, &sAh[buf][0][0] + (c << 3));
            gl_lds16(Al + ga, &sAl[buf][0][0] + (c << 3));
            gl_lds16(Bh + gb, &sBh[buf][0][0] + (c << 3));
            gl_lds16(Bl + gb, &sBl[buf][0][0] + (c << 3));
        }
    };

    STAGE(0, 0);
    __syncthreads();
    const int NT = K >> 5;
    int cur = 0;
    for (int t = 0; t < NT; ++t) {
        if (t + 1 < NT) STAGE(cur ^ 1, (t + 1) << 5);
        frag_ab ah[4], al4[4], bh[4], bl4[4];
        #pragma unroll
        for (int i = 0; i < 4; ++i) {
            const int ro = mbase + 16 * i + lrow;
            ah[i]  = *(const frag_ab*)&sAh[cur][ro][kq];
            al4[i] = *(const frag_ab*)&sAl[cur][ro][kq];
        }
        #pragma unroll
        for (int j = 0; j < 4; ++j) {
            const int ro = nbase + 16 * j + lrow;
            bh[j]  = *(const frag_ab*)&sBh[cur][ro][kq];
            bl4[j] = *(const frag_ab*)&sBl[cur][ro][kq];
        }
        #pragma unroll
        for (int i = 0; i < 4; ++i)
            #pragma unroll
            for (int j = 0; j < 4; ++j) {
                acc[i][j] = __builtin_amdgcn_mfma_f32_16x16x32_bf16(
                    ah[i], bh[j], acc[i][j], 0, 0, 0);
                acc[i][j] = __builtin_amdgcn_mfma_f32_16x16x32_bf16(
                    al4[i], bh[j], acc[i][j], 0, 0, 0);
                acc[i][j] = __builtin_amdgcn_mfma_f32_16x16x32_bf16(
                    ah[i], bl4[j], acc[i][j], 0, 0, 0);
            }
        __syncthreads();
        cur ^= 1;
    }

    const int quad = l >> 4;
    #pragma unroll
    for (int i = 0; i < 4; ++i) {
        #pragma unroll
        for (int j = 0; j < 4; ++j) {
            const int coln = bn + nbase + 16 * j + lrow;
            #pragma unroll
            for (int r = 0; r < 4; ++r) {
                const int rowm = bm + mbase + 16 * i + quad * 4 + r;
                const size_t idx = (size_t)rowm * N + coln;
                float v = acc[i][j][r];
                if (Cf) Cf[idx] = v;
                if (Ch) { u16 hi, lo; split2(v, hi, lo); Ch[idx] = hi; Cl[idx] = lo; }
            }
        }
    }
}

// ---------------------------------------------------------------------------
// Plain bf16 MFMA GEMM (v, Y): C[m,n] = sum_k A[m,k]*B[n,k], A/B pre-converted
// u16 bf16 (pure global_load_lds staging). 128x128, BK=64 panel layout,
// double-buffered 2-phase, XCD swizzle.
// ---------------------------------------------------------------------------
__global__ __launch_bounds__(256) void gemm_bf16(
    const u16* __restrict__ Ab, const u16* __restrict__ Bb,
    void* __restrict__ Cdst, int cmode, const int* __restrict__ flag,
    int M, int N, int K)
{
    __shared__ u16 As[2][2][128][32];   // [dbuf][ks][row][k]  32 KB
    __shared__ u16 Bs[2][2][128][32];   // 64 KB total
    const int cbf = (cmode == 1) ? *flag : 0;

    int bx, by; swizzle_block(bx, by);
    const int bm = by * 128, bn = bx * 128;
    const int tid = threadIdx.x;
    const int l = tid & 63, w = tid >> 6;
    const int mbase = (w & 1) * 64, nbase = (w >> 1) * 64;
    const int lrow = l & 15, kq = (l >> 4) << 3;

    frag_cd acc[4][4];
    #pragma unroll
    for (int i = 0; i < 4; ++i)
        #pragma unroll
        for (int j = 0; j < 4; ++j)
            #pragma unroll
            for (int r = 0; r < 4; ++r) acc[i][j][r] = 0.0f;

    auto STAGE = [&](int buf, int k0) {
        #pragma unroll
        for (int half = 0; half < 4; ++half) {
            const int c   = tid + half * 256;
            const int ks  = c >> 9;
            const int row = (c >> 2) & 127;
            const int ko  = ks * 32 + (c & 3) * 8;
            const size_t ga = (size_t)(bm + row) * K + k0 + ko;
            const size_t gb = (size_t)(bn + row) * K + k0 + ko;
            gl_lds16(Ab + ga, &As[buf][0][0][0] + (c << 3));
            gl_lds16(Bb + gb, &Bs[buf][0][0][0] + (c << 3));
        }
    };

    STAGE(0, 0);
    __syncthreads();
    const int NT = K >> 6;
    int cur = 0;
    for (int t = 0; t < NT; ++t) {
        if (t + 1 < NT) STAGE(cur ^ 1, (t + 1) << 6);
        #pragma unroll
        for (int ks = 0; ks < 2; ++ks) {
            frag_ab a[4], b[4];
            #pragma unroll
            for (int i = 0; i < 4; ++i)
                a[i] = *(const frag_ab*)&As[cur][ks][mbase + 16 * i + lrow][kq];
            #pragma unroll
            for (int j = 0; j < 4; ++j)
                b[j] = *(const frag_ab*)&Bs[cur][ks][nbase + 16 * j + lrow][kq];
            #pragma unroll
            for (int i = 0; i < 4; ++i)
                #pragma unroll
                for (int j = 0; j < 4; ++j)
                    acc[i][j] = __builtin_amdgcn_mfma_f32_16x16x32_bf16(
                        a[i], b[j], acc[i][j], 0, 0, 0);
        }
        __syncthreads();
        cur ^= 1;
    }

    const int quad = l >> 4;
    #pragma unroll
    for (int i = 0; i < 4; ++i) {
        #pragma unroll
        for (int j = 0; j < 4; ++j) {
            const int coln = bn + nbase + 16 * j + lrow;
            #pragma unroll
            for (int r = 0; r < 4; ++r) {
                const int rowm = bm + mbase + 16 * i + quad * 4 + r;
                const size_t idx = (size_t)rowm * N + coln;
                float v = acc[i][j][r];
                if (cbf) ((u16*)Cdst)[idx] = f2bf(v);
                else     ((float*)Cdst)[idx] = v;
            }
        }
    }
}

// ---------------------------------------------------------------------------
// qv = bf16(recon(qh,ql) * v) — A operand for the Y GEMM
// ---------------------------------------------------------------------------
__global__ __launch_bounds__(256) void qvb_k(const u16* __restrict__ qh,
                                             const u16* __restrict__ ql,
                                             const float* __restrict__ V,
                                             u16* __restrict__ out, int n4)
{
    int i = blockIdx.x * 256 + threadIdx.x;
    if (i >= n4) return;
    u16x4 h = ((const u16x4*)qh)[i], lo = ((const u16x4*)ql)[i];
    float4 v = ((const float4*)V)[i];
    u16x4 o;
    o[0] = f2bf((bf2f(h[0]) + bf2f(lo[0])) * v.x);
    o[1] = f2bf((bf2f(h[1]) + bf2f(lo[1])) * v.y);
    o[2] = f2bf((bf2f(h[2]) + bf2f(lo[2])) * v.z);
    o[3] = f2bf((bf2f(h[3]) + bf2f(lo[3])) * v.w);
    ((u16x4*)out)[i] = o;
}

// store recon(q) into d_out at element offset (in float4/u16x4 units)
__global__ __launch_bounds__(256) void store_split_k(
    const u16* __restrict__ h, const u16* __restrict__ l,
    void* __restrict__ out, int n4, size_t off4,
    const int* __restrict__ flag)
{
    int i = blockIdx.x * 256 + threadIdx.x;
    if (i >= n4) return;
    u16x4 hh = ((const u16x4*)h)[i], ll = ((const u16x4*)l)[i];
    float4 f;
    f.x = bf2f(hh[0]) + bf2f(ll[0]);
    f.y = bf2f(hh[1]) + bf2f(ll[1]);
    f.z = bf2f(hh[2]) + bf2f(ll[2]);
    f.w = bf2f(hh[3]) + bf2f(ll[3]);
    if (*flag) {
        u16x4 o; o[0] = f2bf(f.x); o[1] = f2bf(f.y); o[2] = f2bf(f.z); o[3] = f2bf(f.w);
        ((u16x4*)out)[off4 + i] = o;
    } else {
        ((float4*)out)[off4 + i] = f;
    }
}

// idW[j] = sum_i identf[i] * W[i,j] — 64 blocks x 16 rows, atomic combine
__global__ __launch_bounds__(256) void idw2_k(
    const float* __restrict__ identf, const float* __restrict__ W,
    float* __restrict__ idW)
{
    const int b = blockIdx.x;
    const int j = threadIdx.x;
    float a0 = 0, a1 = 0, a2 = 0, a3 = 0;
    #pragma unroll
    for (int ii = 0; ii < 16; ++ii) {
        const int i = b * 16 + ii;
        const float s = identf[i];
        const float* row = W + (size_t)i * C_;
        a0 += s * row[j];
        a1 += s * row[j + 256];
        a2 += s * row[j + 512];
        a3 += s * row[j + 768];
    }
    atomicAdd(idW + j, a0);       atomicAdd(idW + j + 256, a1);
    atomicAdd(idW + j + 512, a2); atomicAdd(idW + j + 768, a3);
}

// ---------------------------------------------------------------------------
// scan combine: one block (256 threads) per token. UNCHANGED (proven).
// ---------------------------------------------------------------------------
__global__ __launch_bounds__(256) void combine2_k(
    const u16* __restrict__ curh, const u16* __restrict__ curl,
    const float* __restrict__ xW,
    const float* __restrict__ idW, const float* __restrict__ identf,
    u16* __restrict__ nxth, u16* __restrict__ nxtl, int d)
{
    const int token = blockIdx.x;
    const int t = token & (T_ - 1);
    const int j = threadIdx.x;
    const bool hl = (t >= d);
    const size_t rbase = (size_t)token * C_;
    const size_t lbase = hl ? (size_t)(token - d) * C_ : 0;
    const float* leftW  = hl ? xW + lbase : idW;
    const float* rightW = xW + rbase;

    float q[4], k[4], v[4];
    #pragma unroll
    for (int m = 0; m < 4; ++m) {
        const int off = m * HD + j;
        k[m] = bf2f(curh[rbase + off]) + bf2f(curl[rbase + off]);
        if (hl) q[m] = bf2f(curh[lbase + off]) + bf2f(curl[lbase + off]);
        else    q[m] = identf[off];
        v[m] = leftW[off] + rightW[off];
    }

    __shared__ float red[4][16];
    __shared__ float att[16];
    const int lane = j & 63, wid = j >> 6;

    #pragma unroll
    for (int a = 0; a < 4; ++a)
        #pragma unroll
        for (int b = 0; b < 4; ++b) {
            float p = wave_reduce(q[a] * k[b]);
            if (lane == 0) red[wid][a * 4 + b] = p;
        }
    __syncthreads();
    if (j < 16) red[0][j] = (red[0][j] + red[1][j] + red[2][j] + red[3][j]) * 0.0625f;
    __syncthreads();
    if (j < 4) {
        float s0 = red[0][j * 4 + 0], s1 = red[0][j * 4 + 1];
        float s2 = red[0][j * 4 + 2], s3 = red[0][j * 4 + 3];
        float mx = fmaxf(fmaxf(s0, s1), fmaxf(s2, s3));
        float e0 = __expf(s0 - mx), e1 = __expf(s1 - mx);
        float e2 = __expf(s2 - mx), e3 = __expf(s3 - mx);
        float inv = 1.0f / (e0 + e1 + e2 + e3);
        att[j * 4 + 0] = e0 * inv; att[j * 4 + 1] = e1 * inv;
        att[j * 4 + 2] = e2 * inv; att[j * 4 + 3] = e3 * inv;
    }
    __syncthreads();

    float z[4];
    #pragma unroll
    for (int a = 0; a < 4; ++a)
        z[a] = att[a * 4 + 0] * v[0] + att[a * 4 + 1] * v[1]
             + att[a * 4 + 2] * v[2] + att[a * 4 + 3] * v[3];

    #pragma unroll
    for (int a = 0; a < 4; ++a) {
        float p = wave_reduce(z[a] * z[a]);
        if (lane == 0) red[wid][a] = p;
    }
    __syncthreads();
    if (j < 4) {
        float ss = red[0][j] + red[1][j] + red[2][j] + red[3][j];
        att[j] = rsqrtf(ss * (1.0f / HD) + 1e-8f);
    }
    __syncthreads();

    #pragma unroll
    for (int m = 0; m < 4; ++m) {
        const int off = m * HD + j;
        float zn  = z[m] * att[m] * (1.0f / (float)(m + 1));
        float out = q[m] + zn;
        u16 hi, lo; split2(out, hi, lo);
        nxth[rbase + off] = hi;
        nxtl[rbase + off] = lo;
    }
}

// ---------------------------------------------------------------------------
extern "C" void kernel_launch(void* const* d_in, const int* in_sizes, int n_in,
                              void* d_out, int out_size, void* d_ws, size_t ws_size,
                              hipStream_t stream)
{
    const void* x     = d_in[0];
    const void* Wup   = d_in[1];
    const void* Wv    = d_in[2];
    const void* Wproj = d_in[3];
    const void* ident = d_in[4];
    const void* Wraw  = d_in[5];

    float* ws = (float*)d_ws;
    int*   flagp  = (int*)ws;                    // meta[0]
    float* sumsqp = ws + 1;                      // meta[1]
    float* W0     = ws + 256;                    // 1M f32
    float* W1     = W0 + (1 << 20);              // 1M f32
    float* identf = W1 + (1 << 20);              // 1024
    float* idW    = identf + 1024;               // 1024
    float* F1     = idW + 1024;                  // 8M f32 (xW / v scratch)
    u16*   WTh    = (u16*)(F1 + (size_t)NTOK * C_);  // W^T split hi (1M u16)
    u16*   WTl    = WTh + (1 << 20);
    u16*   WUh    = WTl + (1 << 20);             // Wup split / WVb
    u16*   WUl    = WUh + (1 << 20);             //            / WPb
    u16*   Q0h    = WUl + (1 << 20);             // q split dbuf A (8M u16 ea)
    u16*   Q0l    = Q0h + (size_t)NTOK * C_;
    u16*   Q1h    = Q0l + (size_t)NTOK * C_;     // q split dbuf B
    u16*   Q1l    = Q1h + (size_t)NTOK * C_;

    const int NC = C_ * C_;          // 1M
    const int NX = NTOK * C_;        // 8M

    // ---- dtype detection ----
    detect_k<<<1, 256, 0, stream>>>((const u16*)Wup, flagp);

    // ---- polar(W_raw) via Newton-Schulz, split-bf16 MFMA (4-term) ----
    hipMemsetAsync(sumsqp, 0, sizeof(float), stream);
    conv_k<<<NC / 256, 256, 0, stream>>>(Wraw, W0, NC, flagp);
    sumsq_k<<<NC / 256, 256, 0, stream>>>(W0, sumsqp);
    scale_k<<<NC / 256, 256, 0, stream>>>(W0, sumsqp);

    // NS split scratch aliases (Q0 region is dead until q0; WU* dead until q0)
    u16* Gh   = WUh;  u16* Gl = WUl;
    u16* Xh2[2] = { Q0h,                 Q0h + 2 * (1 << 20) };
    u16* Xl2[2] = { Q0h + (1 << 20),     Q0h + 3 * (1 << 20) };

    split_k<<<NC / 256, 256, 0, stream>>>(W0, Xh2[0], Xl2[0], NC);
    transpose_split_k<<<dim3(32, 32), 256, 0, stream>>>(W0, WTh, WTl);

    float* Xf = W0; float* Yf = W1; int cur = 0;
    const dim3 gNS(16, 16);
    for (int it = 0; it < 23; ++it) {           // 18 doubling + 5 polish
        bool polish = (it >= 18);
        float a = polish ? 1.5f : 2.0f;
        float b = polish ? -0.5f : -1.0f;
        // G = X^T X  (A = B = X^T split) -> split output
        gemm_split64<<<gNS, 256, 0, stream>>>(WTh, WTl, WTh, WTl,
                                              nullptr, Gh, Gl,
                                              nullptr, 0.0f, 1.0f, C_, C_, C_,
                                              nullptr, nullptr);
        // Y = b*(X G) + a*X  (G symmetric) -> f32 + row split + fused W^T split
        gemm_split64<<<gNS, 256, 0, stream>>>(Xh2[cur], Xl2[cur], Gh, Gl,
                                              Yf, Xh2[cur ^ 1], Xl2[cur ^ 1],
                                              Xf, a, b, C_, C_, C_,
                                              WTh, WTl);
        float* tmp = Xf; Xf = Yf; Yf = tmp; cur ^= 1;
    }
    // Xf = polar(W_raw) f32 ; WTh/WTl = W^T split, ready for the scan

    conv_k<<<4, 256, 0, stream>>>(ident, identf, 1024, flagp);
    hipMemsetAsync(idW, 0, C_ * sizeof(float), stream);
    idw2_k<<<64, 256, 0, stream>>>(identf, Xf, idW);

    const dim3 g128(C_ / 128, NTOK / 128);   // (8, 64)

    // ---- q0 = x @ Wup^T  (split-bf16 MFMA) ----
    conv_split_k<<<NX / 1024, 256, 0, stream>>>(x, Q1h, Q1l, NX / 4, flagp);
    conv_split_k<<<NC / 1024, 256, 0, stream>>>(Wup, WUh, WUl, NC / 4, flagp);
    gemm_split<<<g128, 256, 0, stream>>>(Q1h, Q1l, WUh, WUl,
                                         nullptr, Q0h, Q0l, NTOK, C_, C_);

    // ---- scan: 11 Hillis-Steele steps, q carried as split bf16 pairs ----
    u16 *ch = Q0h, *cl = Q0l, *nh = Q1h, *nl = Q1l;
    for (int d = 1; d < T_; d <<= 1) {
        gemm_split<<<g128, 256, 0, stream>>>(ch, cl, WTh, WTl,
                                             F1, nullptr, nullptr, NTOK, C_, C_);
        combine2_k<<<NTOK, 256, 0, stream>>>(ch, cl, F1, idW, identf, nh, nl, d);
        u16* t1 = ch; ch = nh; nh = t1;
        u16* t2 = cl; cl = nl; nl = t2;
    }
    // 11 steps (odd) -> ch/cl = Q1h/Q1l hold q; Q0*, F1, WU* free

    // ---- pre-convert weights / x to bf16 ----
    convb_k<<<NC / 1024, 256, 0, stream>>>(Wv,    WUh, NC / 4, flagp);   // WVb
    convb_k<<<NC / 1024, 256, 0, stream>>>(Wproj, WUl, NC / 4, flagp);   // WPb
    convb_k<<<NX / 1024, 256, 0, stream>>>(x,     Q0h, NX / 4, flagp);   // xb

    // ---- v = x @ Wv^T  (pure bf16 MFMA) -> F1 f32 ----
    gemm_bf16<<<g128, 256, 0, stream>>>(Q0h, WUh, F1, 0, flagp, NTOK, C_, C_);

    // ---- Y = (q .* v) @ Wproj^T -> d_out[0:NX] ----
    qvb_k<<<NX / 1024, 256, 0, stream>>>(ch, cl, F1, Q0l, NX / 4);
    gemm_bf16<<<g128, 256, 0, stream>>>(Q0l, WUl, d_out, 1, flagp, NTOK, C_, C_);

    // ---- second output: q ----
    store_split_k<<<NX / 1024, 256, 0, stream>>>(ch, cl, d_out, NX / 4,
                                                 (size_t)(NX / 4), flagp);
}

// Round 6
// 2255.389 us; speedup vs baseline: 2.2520x; 1.0244x over previous
//
#include <hip/hip_runtime.h>
#include <hip/hip_bf16.h>

#define DEVINL __device__ __forceinline__

constexpr int B_   = 4;
constexpr int T_   = 2048;
constexpr int C_   = 1024;
constexpr int NTOK = B_ * T_;      // 8192
constexpr int HD   = 256;          // C_/4

typedef unsigned short u16;
typedef __attribute__((ext_vector_type(8))) short  frag_ab;  // 8 bf16 (4 VGPRs)
typedef __attribute__((ext_vector_type(4))) float  frag_cd;  // 4 fp32
typedef __attribute__((ext_vector_type(8))) u16    u16x8;
typedef __attribute__((ext_vector_type(4))) u16    u16x4;

DEVINL float bf2f(u16 u) {
    unsigned int x = ((unsigned int)u) << 16;
    return __uint_as_float(x);
}
DEVINL u16 f2bf(float f) {
    unsigned int x = __float_as_uint(f);
    unsigned int r = (x + 0x7fffu + ((x >> 16) & 1u)) >> 16;
    return (u16)r;
}
// f == bf2f(h) + bf2f(l) + O(2^-18 |f|); residual subtraction exact (Sterbenz).
DEVINL void split2(float f, u16& h, u16& l) {
    h = f2bf(f);
    l = f2bf(f - bf2f(h));
}
DEVINL float wave_reduce(float v) {
    #pragma unroll
    for (int off = 32; off > 0; off >>= 1) v += __shfl_down(v, off, 64);
    return v;
}
DEVINL void gl_lds16(const void* g, void* l) {
    __builtin_amdgcn_global_load_lds(
        (const __attribute__((address_space(1))) unsigned int*)g,
        (__attribute__((address_space(3))) unsigned int*)l, 16, 0, 0);
}

// XCD-aware remap for (8,64) grids: hw%8 = XCD (round-robin); give each XCD
// 8 M-panels x 8 N-cols so its A footprint (4MB split / 2MB bf16) is L2-resident
// and each A panel is fetched by exactly one XCD (was 8x over-fetch).
DEVINL void swizzle_block(int& bx, int& by) {
    const int hw = (int)(blockIdx.x + gridDim.x * blockIdx.y);
    if (gridDim.x == 8 && gridDim.y == 64) {
        const int xcd = hw & 7, idx = hw >> 3;
        by = xcd * 8 + (idx & 7);
        bx = idx >> 3;
    } else { bx = blockIdx.x; by = blockIdx.y; }
}

// ---------------------------------------------------------------------------
// dtype auto-detect (flag: 1 = bf16 inputs, 0 = f32 inputs)
// ---------------------------------------------------------------------------
__global__ __launch_bounds__(256) void detect_k(const u16* __restrict__ w,
                                                int* __restrict__ flag)
{
    int tid = threadIdx.x;
    int cnt = 0;
    for (int i = tid; i < 4096; i += 256) {
        u16 u = w[2 * i];
        int e = (u >> 7) & 0xFF;
        if (u == 0 || (e >= 96 && e <= 134)) cnt++;
    }
    __shared__ int sh[256];
    sh[tid] = cnt; __syncthreads();
    for (int s = 128; s > 0; s >>= 1) {
        if (tid < s) sh[tid] += sh[tid + s];
        __syncthreads();
    }
    if (tid == 0) *flag = (sh[0] > 2048) ? 1 : 0;
}

__global__ __launch_bounds__(256) void conv_k(const void* __restrict__ src,
                                              float* __restrict__ dst, int n,
                                              const int* __restrict__ flag)
{
    int i = blockIdx.x * 256 + threadIdx.x;
    if (i >= n) return;
    if (*flag) dst[i] = bf2f(((const u16*)src)[i]);
    else       dst[i] = ((const float*)src)[i];
}

// src(flag dtype) -> split hi/lo, 4 elems/thread
__global__ __launch_bounds__(256) void conv_split_k(const void* __restrict__ src,
                                                    u16* __restrict__ H,
                                                    u16* __restrict__ L, int n4,
                                                    const int* __restrict__ flag)
{
    int i = blockIdx.x * 256 + threadIdx.x;
    if (i >= n4) return;
    float f[4];
    if (*flag) {
        u16x4 u = ((const u16x4*)src)[i];
        f[0] = bf2f(u[0]); f[1] = bf2f(u[1]); f[2] = bf2f(u[2]); f[3] = bf2f(u[3]);
    } else {
        float4 v = ((const float4*)src)[i];
        f[0] = v.x; f[1] = v.y; f[2] = v.z; f[3] = v.w;
    }
    u16x4 h, lo;
    #pragma unroll
    for (int r = 0; r < 4; ++r) { u16 a, b; split2(f[r], a, b); h[r] = a; lo[r] = b; }
    ((u16x4*)H)[i] = h; ((u16x4*)L)[i] = lo;
}

// src(flag dtype) -> plain bf16, 4 elems/thread
__global__ __launch_bounds__(256) void convb_k(const void* __restrict__ src,
                                               u16* __restrict__ out, int n4,
                                               const int* __restrict__ flag)
{
    int i = blockIdx.x * 256 + threadIdx.x;
    if (i >= n4) return;
    u16x4 o;
    if (*flag) {
        o = ((const u16x4*)src)[i];
    } else {
        float4 v = ((const float4*)src)[i];
        o[0] = f2bf(v.x); o[1] = f2bf(v.y); o[2] = f2bf(v.z); o[3] = f2bf(v.w);
    }
    ((u16x4*)out)[i] = o;
}

__global__ __launch_bounds__(256) void sumsq_k(const float* __restrict__ X,
                                               float* __restrict__ sumsq)
{
    int i = blockIdx.x * 256 + threadIdx.x;
    float f = X[i];
    float p = wave_reduce(f * f);
    __shared__ float r[4];
    int lane = threadIdx.x & 63, w = threadIdx.x >> 6;
    if (lane == 0) r[w] = p;
    __syncthreads();
    if (threadIdx.x == 0) atomicAdd(sumsq, r[0] + r[1] + r[2] + r[3]);
}

__global__ __launch_bounds__(256) void scale_k(float* __restrict__ X,
                                               const float* __restrict__ sumsq)
{
    int i = blockIdx.x * 256 + threadIdx.x;
    float F = sqrtf(*sumsq);
    float s = 16.0f / (1.1f * F);   // Gaussian: sigma_max ~= F/16; 10% margin
    X[i] *= s;
}

// plain f32 -> split (scalar, small arrays)
__global__ __launch_bounds__(256) void split_k(const float* __restrict__ X,
                                               u16* __restrict__ H,
                                               u16* __restrict__ L, int n)
{
    int i = blockIdx.x * 256 + threadIdx.x;
    if (i >= n) return;
    u16 hi, lo; split2(X[i], hi, lo);
    H[i] = hi; L[i] = lo;
}

// Th/Tl[n*C_+k] = split(W[k*C_+n])  — LDS 32x32 tile transpose (initial only)
__global__ __launch_bounds__(256) void transpose_split_k(
    const float* __restrict__ W, u16* __restrict__ Th, u16* __restrict__ Tl)
{
    __shared__ float tile[32][33];
    const int k0 = blockIdx.y * 32;
    const int n0 = blockIdx.x * 32;
    const int tx = threadIdx.x & 31, ty = threadIdx.x >> 5;   // 32 x 8
    #pragma unroll
    for (int r = 0; r < 32; r += 8)
        tile[ty + r][tx] = W[(size_t)(k0 + ty + r) * C_ + n0 + tx];
    __syncthreads();
    #pragma unroll
    for (int r = 0; r < 32; r += 8) {
        float f = tile[tx][ty + r];                 // = W[k0+tx][n0+ty+r]
        size_t idx = (size_t)(n0 + ty + r) * C_ + k0 + tx;
        u16 hi, lo; split2(f, hi, lo);
        Th[idx] = hi; Tl[idx] = lo;
    }
}

// ---------------------------------------------------------------------------
// NS split-bf16 MFMA GEMM: C[m,n] = beta*sum_k A[m,k]*B[n,k] + alpha*D[m,n]
// 64x64 tile, BK=128 ([2][4][64][32] panel layout — 8 k-steps instead of 16,
// halving the barrier-drain count of this latency-bound 1-block/CU kernel),
// 4-term (hh+lh+hl+ll), double-buffered 2-phase prefetch, 128 KB LDS.
// K-chunk order (t*128+ks*32, ks=0..3) == old (t*64+ks*32, ks=0..1): the
// accumulator sees the same ascending 32-wide chunks -> bit-identical.
// Optional epilogue outputs: f32 (Cf), row-major split (Ch/Cl), and
// LDS-transposed split (Th/Tl) (fold proven in rounds 4/5).
// ---------------------------------------------------------------------------
__global__ __launch_bounds__(256) void gemm_split64(
    const u16* __restrict__ Ah, const u16* __restrict__ Al,
    const u16* __restrict__ Bh, const u16* __restrict__ Bl,
    float* __restrict__ Cf, u16* __restrict__ Ch, u16* __restrict__ Cl,
    const float* __restrict__ D, float alpha, float beta,
    int M, int N, int K,
    u16* __restrict__ Th, u16* __restrict__ Tl)
{
    __shared__ u16 sAh[2][4][64][32];   // [dbuf][ks][row][k]  32 KB
    __shared__ u16 sAl[2][4][64][32];
    __shared__ u16 sBh[2][4][64][32];
    __shared__ u16 sBl[2][4][64][32];   // total 128 KB (1 block/CU)

    const int bm = blockIdx.y * 64, bn = blockIdx.x * 64;
    const int tid = threadIdx.x;
    const int l = tid & 63, w = tid >> 6;
    const int mbase = (w & 1) * 32, nbase = (w >> 1) * 32;
    const int lrow = l & 15, kq = (l >> 4) << 3;

    frag_cd acc[2][2];
    #pragma unroll
    for (int i = 0; i < 2; ++i)
        #pragma unroll
        for (int j = 0; j < 2; ++j)
            #pragma unroll
            for (int r = 0; r < 4; ++r) acc[i][j][r] = 0.0f;

    // per array per stage: 64x128 u16 = 1024 16B-chunks; c = tid + 256*half
    // c = ks*256 + row*4 + q  -> LDS linear c*8 (lane-linear for gl_lds)
    auto STAGE = [&](int buf, int k0) {
        #pragma unroll
        for (int half = 0; half < 4; ++half) {
            const int c   = tid + half * 256;
            const int ks  = c >> 8;
            const int row = (c >> 2) & 63;
            const int ko  = ks * 32 + (c & 3) * 8;
            const size_t ga = (size_t)(bm + row) * K + k0 + ko;
            const size_t gb = (size_t)(bn + row) * K + k0 + ko;
            gl_lds16(Ah + ga, &sAh[0][0][0][0] + buf * 8192 + (c << 3));
            gl_lds16(Al + ga, &sAl[0][0][0][0] + buf * 8192 + (c << 3));
            gl_lds16(Bh + gb, &sBh[0][0][0][0] + buf * 8192 + (c << 3));
            gl_lds16(Bl + gb, &sBl[0][0][0][0] + buf * 8192 + (c << 3));
        }
    };

    STAGE(0, 0);
    __syncthreads();
    const int NT = K >> 7;   // 8
    int cur = 0;
    for (int t = 0; t < NT; ++t) {
        if (t + 1 < NT) STAGE(cur ^ 1, (t + 1) << 7);
        #pragma unroll
        for (int ks = 0; ks < 4; ++ks) {
            frag_ab ah[2], al2[2], bh[2], bl2[2];
            #pragma unroll
            for (int i = 0; i < 2; ++i) {
                const int ro = mbase + 16 * i + lrow;
                ah[i]  = *(const frag_ab*)&sAh[cur][ks][ro][kq];
                al2[i] = *(const frag_ab*)&sAl[cur][ks][ro][kq];
            }
            #pragma unroll
            for (int j = 0; j < 2; ++j) {
                const int ro = nbase + 16 * j + lrow;
                bh[j]  = *(const frag_ab*)&sBh[cur][ks][ro][kq];
                bl2[j] = *(const frag_ab*)&sBl[cur][ks][ro][kq];
            }
            #pragma unroll
            for (int i = 0; i < 2; ++i)
                #pragma unroll
                for (int j = 0; j < 2; ++j) {
                    acc[i][j] = __builtin_amdgcn_mfma_f32_16x16x32_bf16(
                        ah[i], bh[j], acc[i][j], 0, 0, 0);
                    acc[i][j] = __builtin_amdgcn_mfma_f32_16x16x32_bf16(
                        al2[i], bh[j], acc[i][j], 0, 0, 0);
                    acc[i][j] = __builtin_amdgcn_mfma_f32_16x16x32_bf16(
                        ah[i], bl2[j], acc[i][j], 0, 0, 0);
                    acc[i][j] = __builtin_amdgcn_mfma_f32_16x16x32_bf16(
                        al2[i], bl2[j], acc[i][j], 0, 0, 0);
                }
        }
        __syncthreads();
        cur ^= 1;
    }

    // epilogue (after final K-loop barrier: staging LDS is dead, reusable)
    const int quad = l >> 4;
    u16* tileH = &sAh[0][0][0][0];   // 64*68 u16 = 8.5 KB, fits in sAh
    u16* tileL = &sAl[0][0][0][0];
    #pragma unroll
    for (int i = 0; i < 2; ++i) {
        #pragma unroll
        for (int j = 0; j < 2; ++j) {
            const int coln = bn + nbase + 16 * j + lrow;
            #pragma unroll
            for (int r = 0; r < 4; ++r) {
                const int rowm = bm + mbase + 16 * i + quad * 4 + r;
                const size_t idx = (size_t)rowm * N + coln;
                float v = beta * acc[i][j][r];
                if (D) v += alpha * D[idx];
                if (Cf) Cf[idx] = v;
                u16 hi, lo; split2(v, hi, lo);
                if (Ch) { Ch[idx] = hi; Cl[idx] = lo; }
                if (Th) {
                    const int rl = mbase + 16 * i + quad * 4 + r;   // local row
                    const int cl = nbase + 16 * j + lrow;           // local col
                    tileH[rl * 68 + cl] = hi;
                    tileL[rl * 68 + cl] = lo;
                }
            }
        }
    }
    if (Th) {
        __syncthreads();
        // transposed coalesced write: T[(bn+jj)*N + bm+ii] = tile[ii][jj]
        const int jj  = tid >> 2;          // 0..63
        const int ii0 = (tid & 3) << 4;    // 0,16,32,48
        u16x8 ph0, ph1, pl0, pl1;
        #pragma unroll
        for (int e = 0; e < 8; ++e) {
            ph0[e] = tileH[(ii0 + e) * 68 + jj];
            pl0[e] = tileL[(ii0 + e) * 68 + jj];
            ph1[e] = tileH[(ii0 + 8 + e) * 68 + jj];
            pl1[e] = tileL[(ii0 + 8 + e) * 68 + jj];
        }
        const size_t tb = (size_t)(bn + jj) * N + bm + ii0;
        *(u16x8*)&Th[tb]     = ph0;
        *(u16x8*)&Th[tb + 8] = ph1;
        *(u16x8*)&Tl[tb]     = pl0;
        *(u16x8*)&Tl[tb + 8] = pl1;
    }
}

// ---------------------------------------------------------------------------
// Scan split-bf16 MFMA GEMM: C[m,n] = sum_k A[m,k]*B[n,k], 3-term (bit-identical
// arithmetic to round-1 gemm_split). 128x128 tile, BK=32, double-buffered
// 2-phase prefetch (one barrier/k-step), XCD-swizzled blocks.
// ---------------------------------------------------------------------------
__global__ __launch_bounds__(256) void gemm_split(
    const u16* __restrict__ Ah, const u16* __restrict__ Al,
    const u16* __restrict__ Bh, const u16* __restrict__ Bl,
    float* __restrict__ Cf, u16* __restrict__ Ch, u16* __restrict__ Cl,
    int M, int N, int K)
{
    __shared__ u16 sAh[2][128][32];   // 16 KB each, 64 KB total
    __shared__ u16 sAl[2][128][32];
    __shared__ u16 sBh[2][128][32];
    __shared__ u16 sBl[2][128][32];

    int bx, by; swizzle_block(bx, by);
    const int bm = by * 128, bn = bx * 128;
    const int tid = threadIdx.x;
    const int l = tid & 63, w = tid >> 6;
    const int mbase = (w & 1) * 64, nbase = (w >> 1) * 64;
    const int lrow = l & 15, kq = (l >> 4) << 3;

    frag_cd acc[4][4];
    #pragma unroll
    for (int i = 0; i < 4; ++i)
        #pragma unroll
        for (int j = 0; j < 4; ++j)
            #pragma unroll
            for (int r = 0; r < 4; ++r) acc[i][j][r] = 0.0f;

    auto STAGE = [&](int buf, int k0) {
        #pragma unroll
        for (int half = 0; half < 2; ++half) {
            const int c   = tid + half * 256;
            const int row = c >> 2;
            const int ko  = (c & 3) << 3;
            const size_t ga = (size_t)(bm + row) * K + k0 + ko;
            const size_t gb = (size_t)(bn + row) * K + k0 + ko;
            gl_lds16(Ah + ga, &sAh[buf][0][0] + (c << 3));
            gl_lds16(Al + ga, &sAl[buf][0][0] + (c << 3));
            gl_lds16(Bh + gb, &sBh[buf][0][0] + (c << 3));
            gl_lds16(Bl + gb, &sBl[buf][0][0] + (c << 3));
        }
    };

    STAGE(0, 0);
    __syncthreads();
    const int NT = K >> 5;
    int cur = 0;
    for (int t = 0; t < NT; ++t) {
        if (t + 1 < NT) STAGE(cur ^ 1, (t + 1) << 5);
        frag_ab ah[4], al4[4], bh[4], bl4[4];
        #pragma unroll
        for (int i = 0; i < 4; ++i) {
            const int ro = mbase + 16 * i + lrow;
            ah[i]  = *(const frag_ab*)&sAh[cur][ro][kq];
            al4[i] = *(const frag_ab*)&sAl[cur][ro][kq];
        }
        #pragma unroll
        for (int j = 0; j < 4; ++j) {
            const int ro = nbase + 16 * j + lrow;
            bh[j]  = *(const frag_ab*)&sBh[cur][ro][kq];
            bl4[j] = *(const frag_ab*)&sBl[cur][ro][kq];
        }
        #pragma unroll
        for (int i = 0; i < 4; ++i)
            #pragma unroll
            for (int j = 0; j < 4; ++j) {
                acc[i][j] = __builtin_amdgcn_mfma_f32_16x16x32_bf16(
                    ah[i], bh[j], acc[i][j], 0, 0, 0);
                acc[i][j] = __builtin_amdgcn_mfma_f32_16x16x32_bf16(
                    al4[i], bh[j], acc[i][j], 0, 0, 0);
                acc[i][j] = __builtin_amdgcn_mfma_f32_16x16x32_bf16(
                    ah[i], bl4[j], acc[i][j], 0, 0, 0);
            }
        __syncthreads();
        cur ^= 1;
    }

    const int quad = l >> 4;
    #pragma unroll
    for (int i = 0; i < 4; ++i) {
        #pragma unroll
        for (int j = 0; j < 4; ++j) {
            const int coln = bn + nbase + 16 * j + lrow;
            #pragma unroll
            for (int r = 0; r < 4; ++r) {
                const int rowm = bm + mbase + 16 * i + quad * 4 + r;
                const size_t idx = (size_t)rowm * N + coln;
                float v = acc[i][j][r];
                if (Cf) Cf[idx] = v;
                if (Ch) { u16 hi, lo; split2(v, hi, lo); Ch[idx] = hi; Cl[idx] = lo; }
            }
        }
    }
}

// ---------------------------------------------------------------------------
// Plain bf16 MFMA GEMM (v, Y): C[m,n] = sum_k A[m,k]*B[n,k], A/B pre-converted
// u16 bf16 (pure global_load_lds staging). 128x128, BK=64 panel layout,
// double-buffered 2-phase, XCD swizzle.
// ---------------------------------------------------------------------------
__global__ __launch_bounds__(256) void gemm_bf16(
    const u16* __restrict__ Ab, const u16* __restrict__ Bb,
    void* __restrict__ Cdst, int cmode, const int* __restrict__ flag,
    int M, int N, int K)
{
    __shared__ u16 As[2][2][128][32];   // [dbuf][ks][row][k]  32 KB
    __shared__ u16 Bs[2][2][128][32];   // 64 KB total
    const int cbf = (cmode == 1) ? *flag : 0;

    int bx, by; swizzle_block(bx, by);
    const int bm = by * 128, bn = bx * 128;
    const int tid = threadIdx.x;
    const int l = tid & 63, w = tid >> 6;
    const int mbase = (w & 1) * 64, nbase = (w >> 1) * 64;
    const int lrow = l & 15, kq = (l >> 4) << 3;

    frag_cd acc[4][4];
    #pragma unroll
    for (int i = 0; i < 4; ++i)
        #pragma unroll
        for (int j = 0; j < 4; ++j)
            #pragma unroll
            for (int r = 0; r < 4; ++r) acc[i][j][r] = 0.0f;

    auto STAGE = [&](int buf, int k0) {
        #pragma unroll
        for (int half = 0; half < 4; ++half) {
            const int c   = tid + half * 256;
            const int ks  = c >> 9;
            const int row = (c >> 2) & 127;
            const int ko  = ks * 32 + (c & 3) * 8;
            const size_t ga = (size_t)(bm + row) * K + k0 + ko;
            const size_t gb = (size_t)(bn + row) * K + k0 + ko;
            gl_lds16(Ab + ga, &As[buf][0][0][0] + (c << 3));
            gl_lds16(Bb + gb, &Bs[buf][0][0][0] + (c << 3));
        }
    };

    STAGE(0, 0);
    __syncthreads();
    const int NT = K >> 6;
    int cur = 0;
    for (int t = 0; t < NT; ++t) {
        if (t + 1 < NT) STAGE(cur ^ 1, (t + 1) << 6);
        #pragma unroll
        for (int ks = 0; ks < 2; ++ks) {
            frag_ab a[4], b[4];
            #pragma unroll
            for (int i = 0; i < 4; ++i)
                a[i] = *(const frag_ab*)&As[cur][ks][mbase + 16 * i + lrow][kq];
            #pragma unroll
            for (int j = 0; j < 4; ++j)
                b[j] = *(const frag_ab*)&Bs[cur][ks][nbase + 16 * j + lrow][kq];
            #pragma unroll
            for (int i = 0; i < 4; ++i)
                #pragma unroll
                for (int j = 0; j < 4; ++j)
                    acc[i][j] = __builtin_amdgcn_mfma_f32_16x16x32_bf16(
                        a[i], b[j], acc[i][j], 0, 0, 0);
        }
        __syncthreads();
        cur ^= 1;
    }

    const int quad = l >> 4;
    #pragma unroll
    for (int i = 0; i < 4; ++i) {
        #pragma unroll
        for (int j = 0; j < 4; ++j) {
            const int coln = bn + nbase + 16 * j + lrow;
            #pragma unroll
            for (int r = 0; r < 4; ++r) {
                const int rowm = bm + mbase + 16 * i + quad * 4 + r;
                const size_t idx = (size_t)rowm * N + coln;
                float v = acc[i][j][r];
                if (cbf) ((u16*)Cdst)[idx] = f2bf(v);
                else     ((float*)Cdst)[idx] = v;
            }
        }
    }
}

// ---------------------------------------------------------------------------
// qv = bf16(recon(qh,ql) * v) — A operand for the Y GEMM
// ---------------------------------------------------------------------------
__global__ __launch_bounds__(256) void qvb_k(const u16* __restrict__ qh,
                                             const u16* __restrict__ ql,
                                             const float* __restrict__ V,
                                             u16* __restrict__ out, int n4)
{
    int i = blockIdx.x * 256 + threadIdx.x;
    if (i >= n4) return;
    u16x4 h = ((const u16x4*)qh)[i], lo = ((const u16x4*)ql)[i];
    float4 v = ((const float4*)V)[i];
    u16x4 o;
    o[0] = f2bf((bf2f(h[0]) + bf2f(lo[0])) * v.x);
    o[1] = f2bf((bf2f(h[1]) + bf2f(lo[1])) * v.y);
    o[2] = f2bf((bf2f(h[2]) + bf2f(lo[2])) * v.z);
    o[3] = f2bf((bf2f(h[3]) + bf2f(lo[3])) * v.w);
    ((u16x4*)out)[i] = o;
}

// store recon(q) into d_out at element offset (in float4/u16x4 units)
__global__ __launch_bounds__(256) void store_split_k(
    const u16* __restrict__ h, const u16* __restrict__ l,
    void* __restrict__ out, int n4, size_t off4,
    const int* __restrict__ flag)
{
    int i = blockIdx.x * 256 + threadIdx.x;
    if (i >= n4) return;
    u16x4 hh = ((const u16x4*)h)[i], ll = ((const u16x4*)l)[i];
    float4 f;
    f.x = bf2f(hh[0]) + bf2f(ll[0]);
    f.y = bf2f(hh[1]) + bf2f(ll[1]);
    f.z = bf2f(hh[2]) + bf2f(ll[2]);
    f.w = bf2f(hh[3]) + bf2f(ll[3]);
    if (*flag) {
        u16x4 o; o[0] = f2bf(f.x); o[1] = f2bf(f.y); o[2] = f2bf(f.z); o[3] = f2bf(f.w);
        ((u16x4*)out)[off4 + i] = o;
    } else {
        ((float4*)out)[off4 + i] = f;
    }
}

// idW[j] = sum_i identf[i] * W[i,j] — 64 blocks x 16 rows, atomic combine
__global__ __launch_bounds__(256) void idw2_k(
    const float* __restrict__ identf, const float* __restrict__ W,
    float* __restrict__ idW)
{
    const int b = blockIdx.x;
    const int j = threadIdx.x;
    float a0 = 0, a1 = 0, a2 = 0, a3 = 0;
    #pragma unroll
    for (int ii = 0; ii < 16; ++ii) {
        const int i = b * 16 + ii;
        const float s = identf[i];
        const float* row = W + (size_t)i * C_;
        a0 += s * row[j];
        a1 += s * row[j + 256];
        a2 += s * row[j + 512];
        a3 += s * row[j + 768];
    }
    atomicAdd(idW + j, a0);       atomicAdd(idW + j + 256, a1);
    atomicAdd(idW + j + 512, a2); atomicAdd(idW + j + 768, a3);
}

// ---------------------------------------------------------------------------
// scan combine: one block (256 threads) per token. Math UNCHANGED (proven);
// token remap makes F1/cur/nxt accesses XCD-local: the scan GEMM's swizzle
// writes F1 rows [g*1024,(g+1)*1024) from XCD g, and blockIdx hw%8 = XCD, so
// token = (bid&7)*1024 + bid>>3 puts each block on the XCD that produced its
// row (right-reads 100% local; left-neighbor ~82% local averaged over d).
// ---------------------------------------------------------------------------
__global__ __launch_bounds__(256) void combine2_k(
    const u16* __restrict__ curh, const u16* __restrict__ curl,
    const float* __restrict__ xW,
    const float* __restrict__ idW, const float* __restrict__ identf,
    u16* __restrict__ nxth, u16* __restrict__ nxtl, int d)
{
    const int bid = (int)blockIdx.x;
    const int token = ((bid & 7) << 10) | (bid >> 3);
    const int t = token & (T_ - 1);
    const int j = threadIdx.x;
    const bool hl = (t >= d);
    const size_t rbase = (size_t)token * C_;
    const size_t lbase = hl ? (size_t)(token - d) * C_ : 0;
    const float* leftW  = hl ? xW + lbase : idW;
    const float* rightW = xW + rbase;

    float q[4], k[4], v[4];
    #pragma unroll
    for (int m = 0; m < 4; ++m) {
        const int off = m * HD + j;
        k[m] = bf2f(curh[rbase + off]) + bf2f(curl[rbase + off]);
        if (hl) q[m] = bf2f(curh[lbase + off]) + bf2f(curl[lbase + off]);
        else    q[m] = identf[off];
        v[m] = leftW[off] + rightW[off];
    }

    __shared__ float red[4][16];
    __shared__ float att[16];
    const int lane = j & 63, wid = j >> 6;

    #pragma unroll
    for (int a = 0; a < 4; ++a)
        #pragma unroll
        for (int b = 0; b < 4; ++b) {
            float p = wave_reduce(q[a] * k[b]);
            if (lane == 0) red[wid][a * 4 + b] = p;
        }
    __syncthreads();
    if (j < 16) red[0][j] = (red[0][j] + red[1][j] + red[2][j] + red[3][j]) * 0.0625f;
    __syncthreads();
    if (j < 4) {
        float s0 = red[0][j * 4 + 0], s1 = red[0][j * 4 + 1];
        float s2 = red[0][j * 4 + 2], s3 = red[0][j * 4 + 3];
        float mx = fmaxf(fmaxf(s0, s1), fmaxf(s2, s3));
        float e0 = __expf(s0 - mx), e1 = __expf(s1 - mx);
        float e2 = __expf(s2 - mx), e3 = __expf(s3 - mx);
        float inv = 1.0f / (e0 + e1 + e2 + e3);
        att[j * 4 + 0] = e0 * inv; att[j * 4 + 1] = e1 * inv;
        att[j * 4 + 2] = e2 * inv; att[j * 4 + 3] = e3 * inv;
    }
    __syncthreads();

    float z[4];
    #pragma unroll
    for (int a = 0; a < 4; ++a)
        z[a] = att[a * 4 + 0] * v[0] + att[a * 4 + 1] * v[1]
             + att[a * 4 + 2] * v[2] + att[a * 4 + 3] * v[3];

    #pragma unroll
    for (int a = 0; a < 4; ++a) {
        float p = wave_reduce(z[a] * z[a]);
        if (lane == 0) red[wid][a] = p;
    }
    __syncthreads();
    if (j < 4) {
        float ss = red[0][j] + red[1][j] + red[2][j] + red[3][j];
        att[j] = rsqrtf(ss * (1.0f / HD) + 1e-8f);
    }
    __syncthreads();

    #pragma unroll
    for (int m = 0; m < 4; ++m) {
        const int off = m * HD + j;
        float zn  = z[m] * att[m] * (1.0f / (float)(m + 1));
        float out = q[m] + zn;
        u16 hi, lo; split2(out, hi, lo);
        nxth[rbase + off] = hi;
        nxtl[rbase + off] = lo;
    }
}

// ---------------------------------------------------------------------------
extern "C" void kernel_launch(void* const* d_in, const int* in_sizes, int n_in,
                              void* d_out, int out_size, void* d_ws, size_t ws_size,
                              hipStream_t stream)
{
    const void* x     = d_in[0];
    const void* Wup   = d_in[1];
    const void* Wv    = d_in[2];
    const void* Wproj = d_in[3];
    const void* ident = d_in[4];
    const void* Wraw  = d_in[5];

    float* ws = (float*)d_ws;
    int*   flagp  = (int*)ws;                    // meta[0]
    float* sumsqp = ws + 1;                      // meta[1]
    float* W0     = ws + 256;                    // 1M f32
    float* W1     = W0 + (1 << 20);              // 1M f32
    float* identf = W1 + (1 << 20);              // 1024
    float* idW    = identf + 1024;               // 1024
    float* F1     = idW + 1024;                  // 8M f32 (xW / v scratch)
    u16*   WTh    = (u16*)(F1 + (size_t)NTOK * C_);  // W^T split hi (1M u16)
    u16*   WTl    = WTh + (1 << 20);
    u16*   WUh    = WTl + (1 << 20);             // Wup split / WVb
    u16*   WUl    = WUh + (1 << 20);             //            / WPb
    u16*   Q0h    = WUl + (1 << 20);             // q split dbuf A (8M u16 ea)
    u16*   Q0l    = Q0h + (size_t)NTOK * C_;
    u16*   Q1h    = Q0l + (size_t)NTOK * C_;     // q split dbuf B
    u16*   Q1l    = Q1h + (size_t)NTOK * C_;

    const int NC = C_ * C_;          // 1M
    const int NX = NTOK * C_;        // 8M

    // ---- dtype detection ----
    detect_k<<<1, 256, 0, stream>>>((const u16*)Wup, flagp);

    // ---- polar(W_raw) via Newton-Schulz, split-bf16 MFMA (4-term) ----
    hipMemsetAsync(sumsqp, 0, sizeof(float), stream);
    conv_k<<<NC / 256, 256, 0, stream>>>(Wraw, W0, NC, flagp);
    sumsq_k<<<NC / 256, 256, 0, stream>>>(W0, sumsqp);
    scale_k<<<NC / 256, 256, 0, stream>>>(W0, sumsqp);

    // NS split scratch aliases (Q0 region is dead until q0; WU* dead until q0)
    u16* Gh   = WUh;  u16* Gl = WUl;
    u16* Xh2[2] = { Q0h,                 Q0h + 2 * (1 << 20) };
    u16* Xl2[2] = { Q0h + (1 << 20),     Q0h + 3 * (1 << 20) };

    split_k<<<NC / 256, 256, 0, stream>>>(W0, Xh2[0], Xl2[0], NC);
    transpose_split_k<<<dim3(32, 32), 256, 0, stream>>>(W0, WTh, WTl);

    float* Xf = W0; float* Yf = W1; int cur = 0;
    const dim3 gNS(16, 16);
    for (int it = 0; it < 23; ++it) {           // 18 doubling + 5 polish
        bool polish = (it >= 18);
        float a = polish ? 1.5f : 2.0f;
        float b = polish ? -0.5f : -1.0f;
        // G = X^T X  (A = B = X^T split) -> split output
        gemm_split64<<<gNS, 256, 0, stream>>>(WTh, WTl, WTh, WTl,
                                              nullptr, Gh, Gl,
                                              nullptr, 0.0f, 1.0f, C_, C_, C_,
                                              nullptr, nullptr);
        // Y = b*(X G) + a*X  (G symmetric) -> f32 + row split + fused W^T split
        gemm_split64<<<gNS, 256, 0, stream>>>(Xh2[cur], Xl2[cur], Gh, Gl,
                                              Yf, Xh2[cur ^ 1], Xl2[cur ^ 1],
                                              Xf, a, b, C_, C_, C_,
                                              WTh, WTl);
        float* tmp = Xf; Xf = Yf; Yf = tmp; cur ^= 1;
    }
    // Xf = polar(W_raw) f32 ; WTh/WTl = W^T split, ready for the scan

    conv_k<<<4, 256, 0, stream>>>(ident, identf, 1024, flagp);
    hipMemsetAsync(idW, 0, C_ * sizeof(float), stream);
    idw2_k<<<64, 256, 0, stream>>>(identf, Xf, idW);

    const dim3 g128(C_ / 128, NTOK / 128);   // (8, 64)

    // ---- q0 = x @ Wup^T  (split-bf16 MFMA) ----
    conv_split_k<<<NX / 1024, 256, 0, stream>>>(x, Q1h, Q1l, NX / 4, flagp);
    conv_split_k<<<NC / 1024, 256, 0, stream>>>(Wup, WUh, WUl, NC / 4, flagp);
    gemm_split<<<g128, 256, 0, stream>>>(Q1h, Q1l, WUh, WUl,
                                         nullptr, Q0h, Q0l, NTOK, C_, C_);

    // ---- scan: 11 Hillis-Steele steps, q carried as split bf16 pairs ----
    u16 *ch = Q0h, *cl = Q0l, *nh = Q1h, *nl = Q1l;
    for (int d = 1; d < T_; d <<= 1) {
        gemm_split<<<g128, 256, 0, stream>>>(ch, cl, WTh, WTl,
                                             F1, nullptr, nullptr, NTOK, C_, C_);
        combine2_k<<<NTOK, 256, 0, stream>>>(ch, cl, F1, idW, identf, nh, nl, d);
        u16* t1 = ch; ch = nh; nh = t1;
        u16* t2 = cl; cl = nl; nl = t2;
    }
    // 11 steps (odd) -> ch/cl = Q1h/Q1l hold q; Q0*, F1, WU* free

    // ---- pre-convert weights / x to bf16 ----
    convb_k<<<NC / 1024, 256, 0, stream>>>(Wv,    WUh, NC / 4, flagp);   // WVb
    convb_k<<<NC / 1024, 256, 0, stream>>>(Wproj, WUl, NC / 4, flagp);   // WPb
    convb_k<<<NX / 1024, 256, 0, stream>>>(x,     Q0h, NX / 4, flagp);   // xb

    // ---- v = x @ Wv^T  (pure bf16 MFMA) -> F1 f32 ----
    gemm_bf16<<<g128, 256, 0, stream>>>(Q0h, WUh, F1, 0, flagp, NTOK, C_, C_);

    // ---- Y = (q .* v) @ Wproj^T -> d_out[0:NX] ----
    qvb_k<<<NX / 1024, 256, 0, stream>>>(ch, cl, F1, Q0l, NX / 4);
    gemm_bf16<<<g128, 256, 0, stream>>>(Q0l, WUl, d_out, 1, flagp, NTOK, C_, C_);

    // ---- second output: q ----
    store_split_k<<<NX / 1024, 256, 0, stream>>>(ch, cl, d_out, NX / 4,
                                                 (size_t)(NX / 4), flagp);
}

// Round 7
// 2027.384 us; speedup vs baseline: 2.5052x; 1.1125x over previous
//
#include <hip/hip_runtime.h>
#include <hip/hip_bf16.h>

#define DEVINL __device__ __forceinline__

constexpr int B_   = 4;
constexpr int T_   = 2048;
constexpr int C_   = 1024;
constexpr int NTOK = B_ * T_;      // 8192
constexpr int HD   = 256;          // C_/4

typedef unsigned short u16;
typedef __attribute__((ext_vector_type(8))) short  frag_ab;  // 8 bf16 (4 VGPRs)
typedef __attribute__((ext_vector_type(4))) float  frag_cd;  // 4 fp32
typedef __attribute__((ext_vector_type(8))) u16    u16x8;
typedef __attribute__((ext_vector_type(4))) u16    u16x4;

DEVINL float bf2f(u16 u) {
    unsigned int x = ((unsigned int)u) << 16;
    return __uint_as_float(x);
}
DEVINL u16 f2bf(float f) {
    unsigned int x = __float_as_uint(f);
    unsigned int r = (x + 0x7fffu + ((x >> 16) & 1u)) >> 16;
    return (u16)r;
}
// f == bf2f(h) + bf2f(l) + O(2^-18 |f|); residual subtraction exact (Sterbenz).
DEVINL void split2(float f, u16& h, u16& l) {
    h = f2bf(f);
    l = f2bf(f - bf2f(h));
}
DEVINL float wave_reduce(float v) {
    #pragma unroll
    for (int off = 32; off > 0; off >>= 1) v += __shfl_down(v, off, 64);
    return v;
}
DEVINL void gl_lds16(const void* g, void* l) {
    __builtin_amdgcn_global_load_lds(
        (const __attribute__((address_space(1))) unsigned int*)g,
        (__attribute__((address_space(3))) unsigned int*)l, 16, 0, 0);
}

// XCD-aware remap for (8,64) grids: hw%8 = XCD (round-robin); give each XCD
// 8 M-panels x 8 N-cols so its A footprint (4MB split / 2MB bf16) is L2-resident
// and each A panel is fetched by exactly one XCD (was 8x over-fetch).
DEVINL void swizzle_block(int& bx, int& by) {
    const int hw = (int)(blockIdx.x + gridDim.x * blockIdx.y);
    if (gridDim.x == 8 && gridDim.y == 64) {
        const int xcd = hw & 7, idx = hw >> 3;
        by = xcd * 8 + (idx & 7);
        bx = idx >> 3;
    } else { bx = blockIdx.x; by = blockIdx.y; }
}

// ---------------------------------------------------------------------------
// dtype auto-detect (flag: 1 = bf16 inputs, 0 = f32 inputs)
// ---------------------------------------------------------------------------
__global__ __launch_bounds__(256) void detect_k(const u16* __restrict__ w,
                                                int* __restrict__ flag)
{
    int tid = threadIdx.x;
    int cnt = 0;
    for (int i = tid; i < 4096; i += 256) {
        u16 u = w[2 * i];
        int e = (u >> 7) & 0xFF;
        if (u == 0 || (e >= 96 && e <= 134)) cnt++;
    }
    __shared__ int sh[256];
    sh[tid] = cnt; __syncthreads();
    for (int s = 128; s > 0; s >>= 1) {
        if (tid < s) sh[tid] += sh[tid + s];
        __syncthreads();
    }
    if (tid == 0) *flag = (sh[0] > 2048) ? 1 : 0;
}

__global__ __launch_bounds__(256) void conv_k(const void* __restrict__ src,
                                              float* __restrict__ dst, int n,
                                              const int* __restrict__ flag)
{
    int i = blockIdx.x * 256 + threadIdx.x;
    if (i >= n) return;
    if (*flag) dst[i] = bf2f(((const u16*)src)[i]);
    else       dst[i] = ((const float*)src)[i];
}

// src(flag dtype) -> split hi/lo, 4 elems/thread
__global__ __launch_bounds__(256) void conv_split_k(const void* __restrict__ src,
                                                    u16* __restrict__ H,
                                                    u16* __restrict__ L, int n4,
                                                    const int* __restrict__ flag)
{
    int i = blockIdx.x * 256 + threadIdx.x;
    if (i >= n4) return;
    float f[4];
    if (*flag) {
        u16x4 u = ((const u16x4*)src)[i];
        f[0] = bf2f(u[0]); f[1] = bf2f(u[1]); f[2] = bf2f(u[2]); f[3] = bf2f(u[3]);
    } else {
        float4 v = ((const float4*)src)[i];
        f[0] = v.x; f[1] = v.y; f[2] = v.z; f[3] = v.w;
    }
    u16x4 h, lo;
    #pragma unroll
    for (int r = 0; r < 4; ++r) { u16 a, b; split2(f[r], a, b); h[r] = a; lo[r] = b; }
    ((u16x4*)H)[i] = h; ((u16x4*)L)[i] = lo;
}

// src(flag dtype) -> plain bf16, 4 elems/thread
__global__ __launch_bounds__(256) void convb_k(const void* __restrict__ src,
                                               u16* __restrict__ out, int n4,
                                               const int* __restrict__ flag)
{
    int i = blockIdx.x * 256 + threadIdx.x;
    if (i >= n4) return;
    u16x4 o;
    if (*flag) {
        o = ((const u16x4*)src)[i];
    } else {
        float4 v = ((const float4*)src)[i];
        o[0] = f2bf(v.x); o[1] = f2bf(v.y); o[2] = f2bf(v.z); o[3] = f2bf(v.w);
    }
    ((u16x4*)out)[i] = o;
}

__global__ __launch_bounds__(256) void sumsq_k(const float* __restrict__ X,
                                               float* __restrict__ sumsq)
{
    int i = blockIdx.x * 256 + threadIdx.x;
    float f = X[i];
    float p = wave_reduce(f * f);
    __shared__ float r[4];
    int lane = threadIdx.x & 63, w = threadIdx.x >> 6;
    if (lane == 0) r[w] = p;
    __syncthreads();
    if (threadIdx.x == 0) atomicAdd(sumsq, r[0] + r[1] + r[2] + r[3]);
}

__global__ __launch_bounds__(256) void scale_k(float* __restrict__ X,
                                               const float* __restrict__ sumsq)
{
    int i = blockIdx.x * 256 + threadIdx.x;
    float F = sqrtf(*sumsq);
    float s = 16.0f / (1.1f * F);   // Gaussian: sigma_max ~= F/16; 10% margin
    X[i] *= s;
}

// plain f32 -> split (scalar, small arrays)
__global__ __launch_bounds__(256) void split_k(const float* __restrict__ X,
                                               u16* __restrict__ H,
                                               u16* __restrict__ L, int n)
{
    int i = blockIdx.x * 256 + threadIdx.x;
    if (i >= n) return;
    u16 hi, lo; split2(X[i], hi, lo);
    H[i] = hi; L[i] = lo;
}

// Th/Tl[n*C_+k] = split(W[k*C_+n])  — LDS 32x32 tile transpose (initial only)
__global__ __launch_bounds__(256) void transpose_split_k(
    const float* __restrict__ W, u16* __restrict__ Th, u16* __restrict__ Tl)
{
    __shared__ float tile[32][33];
    const int k0 = blockIdx.y * 32;
    const int n0 = blockIdx.x * 32;
    const int tx = threadIdx.x & 31, ty = threadIdx.x >> 5;   // 32 x 8
    #pragma unroll
    for (int r = 0; r < 32; r += 8)
        tile[ty + r][tx] = W[(size_t)(k0 + ty + r) * C_ + n0 + tx];
    __syncthreads();
    #pragma unroll
    for (int r = 0; r < 32; r += 8) {
        float f = tile[tx][ty + r];                 // = W[k0+tx][n0+ty+r]
        size_t idx = (size_t)(n0 + ty + r) * C_ + k0 + tx;
        u16 hi, lo; split2(f, hi, lo);
        Th[idx] = hi; Tl[idx] = lo;
    }
}

// ---------------------------------------------------------------------------
// NS split-bf16 MFMA GEMM: C[m,n] = beta*sum_k A[m,k]*B[n,k] + alpha*D[m,n]
// 64x64 tile, BK=128 ([2][4][64][32] panel layout — 8 k-steps, halving the
// barrier-drain count of this latency-bound 1-block/CU kernel), 4-term
// (hh+lh+hl+ll), double-buffered 2-phase prefetch, 128 KB LDS.
// Optional epilogue outputs: f32 (Cf), row-major split (Ch/Cl), and
// LDS-transposed split (Th/Tl) (fold proven in rounds 4/5).
// ---------------------------------------------------------------------------
__global__ __launch_bounds__(256) void gemm_split64(
    const u16* __restrict__ Ah, const u16* __restrict__ Al,
    const u16* __restrict__ Bh, const u16* __restrict__ Bl,
    float* __restrict__ Cf, u16* __restrict__ Ch, u16* __restrict__ Cl,
    const float* __restrict__ D, float alpha, float beta,
    int M, int N, int K,
    u16* __restrict__ Th, u16* __restrict__ Tl)
{
    __shared__ u16 sAh[2][4][64][32];   // [dbuf][ks][row][k]  32 KB
    __shared__ u16 sAl[2][4][64][32];
    __shared__ u16 sBh[2][4][64][32];
    __shared__ u16 sBl[2][4][64][32];   // total 128 KB (1 block/CU)

    const int bm = blockIdx.y * 64, bn = blockIdx.x * 64;
    const int tid = threadIdx.x;
    const int l = tid & 63, w = tid >> 6;
    const int mbase = (w & 1) * 32, nbase = (w >> 1) * 32;
    const int lrow = l & 15, kq = (l >> 4) << 3;

    frag_cd acc[2][2];
    #pragma unroll
    for (int i = 0; i < 2; ++i)
        #pragma unroll
        for (int j = 0; j < 2; ++j)
            #pragma unroll
            for (int r = 0; r < 4; ++r) acc[i][j][r] = 0.0f;

    auto STAGE = [&](int buf, int k0) {
        #pragma unroll
        for (int half = 0; half < 4; ++half) {
            const int c   = tid + half * 256;
            const int ks  = c >> 8;
            const int row = (c >> 2) & 63;
            const int ko  = ks * 32 + (c & 3) * 8;
            const size_t ga = (size_t)(bm + row) * K + k0 + ko;
            const size_t gb = (size_t)(bn + row) * K + k0 + ko;
            gl_lds16(Ah + ga, &sAh[0][0][0][0] + buf * 8192 + (c << 3));
            gl_lds16(Al + ga, &sAl[0][0][0][0] + buf * 8192 + (c << 3));
            gl_lds16(Bh + gb, &sBh[0][0][0][0] + buf * 8192 + (c << 3));
            gl_lds16(Bl + gb, &sBl[0][0][0][0] + buf * 8192 + (c << 3));
        }
    };

    STAGE(0, 0);
    __syncthreads();
    const int NT = K >> 7;   // 8
    int cur = 0;
    for (int t = 0; t < NT; ++t) {
        if (t + 1 < NT) STAGE(cur ^ 1, (t + 1) << 7);
        #pragma unroll
        for (int ks = 0; ks < 4; ++ks) {
            frag_ab ah[2], al2[2], bh[2], bl2[2];
            #pragma unroll
            for (int i = 0; i < 2; ++i) {
                const int ro = mbase + 16 * i + lrow;
                ah[i]  = *(const frag_ab*)&sAh[cur][ks][ro][kq];
                al2[i] = *(const frag_ab*)&sAl[cur][ks][ro][kq];
            }
            #pragma unroll
            for (int j = 0; j < 2; ++j) {
                const int ro = nbase + 16 * j + lrow;
                bh[j]  = *(const frag_ab*)&sBh[cur][ks][ro][kq];
                bl2[j] = *(const frag_ab*)&sBl[cur][ks][ro][kq];
            }
            #pragma unroll
            for (int i = 0; i < 2; ++i)
                #pragma unroll
                for (int j = 0; j < 2; ++j) {
                    acc[i][j] = __builtin_amdgcn_mfma_f32_16x16x32_bf16(
                        ah[i], bh[j], acc[i][j], 0, 0, 0);
                    acc[i][j] = __builtin_amdgcn_mfma_f32_16x16x32_bf16(
                        al2[i], bh[j], acc[i][j], 0, 0, 0);
                    acc[i][j] = __builtin_amdgcn_mfma_f32_16x16x32_bf16(
                        ah[i], bl2[j], acc[i][j], 0, 0, 0);
                    acc[i][j] = __builtin_amdgcn_mfma_f32_16x16x32_bf16(
                        al2[i], bl2[j], acc[i][j], 0, 0, 0);
                }
        }
        __syncthreads();
        cur ^= 1;
    }

    // epilogue (after final K-loop barrier: staging LDS is dead, reusable)
    const int quad = l >> 4;
    u16* tileH = &sAh[0][0][0][0];   // 64*68 u16 = 8.5 KB, fits in sAh
    u16* tileL = &sAl[0][0][0][0];
    #pragma unroll
    for (int i = 0; i < 2; ++i) {
        #pragma unroll
        for (int j = 0; j < 2; ++j) {
            const int coln = bn + nbase + 16 * j + lrow;
            #pragma unroll
            for (int r = 0; r < 4; ++r) {
                const int rowm = bm + mbase + 16 * i + quad * 4 + r;
                const size_t idx = (size_t)rowm * N + coln;
                float v = beta * acc[i][j][r];
                if (D) v += alpha * D[idx];
                if (Cf) Cf[idx] = v;
                u16 hi, lo; split2(v, hi, lo);
                if (Ch) { Ch[idx] = hi; Cl[idx] = lo; }
                if (Th) {
                    const int rl = mbase + 16 * i + quad * 4 + r;   // local row
                    const int cl = nbase + 16 * j + lrow;           // local col
                    tileH[rl * 68 + cl] = hi;
                    tileL[rl * 68 + cl] = lo;
                }
            }
        }
    }
    if (Th) {
        __syncthreads();
        // transposed coalesced write: T[(bn+jj)*N + bm+ii] = tile[ii][jj]
        const int jj  = tid >> 2;          // 0..63
        const int ii0 = (tid & 3) << 4;    // 0,16,32,48
        u16x8 ph0, ph1, pl0, pl1;
        #pragma unroll
        for (int e = 0; e < 8; ++e) {
            ph0[e] = tileH[(ii0 + e) * 68 + jj];
            pl0[e] = tileL[(ii0 + e) * 68 + jj];
            ph1[e] = tileH[(ii0 + 8 + e) * 68 + jj];
            pl1[e] = tileL[(ii0 + 8 + e) * 68 + jj];
        }
        const size_t tb = (size_t)(bn + jj) * N + bm + ii0;
        *(u16x8*)&Th[tb]     = ph0;
        *(u16x8*)&Th[tb + 8] = ph1;
        *(u16x8*)&Tl[tb]     = pl0;
        *(u16x8*)&Tl[tb + 8] = pl1;
    }
}

// ---------------------------------------------------------------------------
// Scan split-bf16 MFMA GEMM: C[m,n] = sum_k A[m,k]*B[n,k], 3-term (bit-identical
// arithmetic to round-1 gemm_split). 128x128 tile, BK=32, double-buffered
// 2-phase prefetch (one barrier/k-step), XCD-swizzled blocks.
// ---------------------------------------------------------------------------
__global__ __launch_bounds__(256) void gemm_split(
    const u16* __restrict__ Ah, const u16* __restrict__ Al,
    const u16* __restrict__ Bh, const u16* __restrict__ Bl,
    float* __restrict__ Cf, u16* __restrict__ Ch, u16* __restrict__ Cl,
    int M, int N, int K)
{
    __shared__ u16 sAh[2][128][32];   // 16 KB each, 64 KB total
    __shared__ u16 sAl[2][128][32];
    __shared__ u16 sBh[2][128][32];
    __shared__ u16 sBl[2][128][32];

    int bx, by; swizzle_block(bx, by);
    const int bm = by * 128, bn = bx * 128;
    const int tid = threadIdx.x;
    const int l = tid & 63, w = tid >> 6;
    const int mbase = (w & 1) * 64, nbase = (w >> 1) * 64;
    const int lrow = l & 15, kq = (l >> 4) << 3;

    frag_cd acc[4][4];
    #pragma unroll
    for (int i = 0; i < 4; ++i)
        #pragma unroll
        for (int j = 0; j < 4; ++j)
            #pragma unroll
            for (int r = 0; r < 4; ++r) acc[i][j][r] = 0.0f;

    auto STAGE = [&](int buf, int k0) {
        #pragma unroll
        for (int half = 0; half < 2; ++half) {
            const int c   = tid + half * 256;
            const int row = c >> 2;
            const int ko  = (c & 3) << 3;
            const size_t ga = (size_t)(bm + row) * K + k0 + ko;
            const size_t gb = (size_t)(bn + row) * K + k0 + ko;
            gl_lds16(Ah + ga, &sAh[buf][0][0] + (c << 3));
            gl_lds16(Al + ga, &sAl[buf][0][0] + (c << 3));
            gl_lds16(Bh + gb, &sBh[buf][0][0] + (c << 3));
            gl_lds16(Bl + gb, &sBl[buf][0][0] + (c << 3));
        }
    };

    STAGE(0, 0);
    __syncthreads();
    const int NT = K >> 5;
    int cur = 0;
    for (int t = 0; t < NT; ++t) {
        if (t + 1 < NT) STAGE(cur ^ 1, (t + 1) << 5);
        frag_ab ah[4], al4[4], bh[4], bl4[4];
        #pragma unroll
        for (int i = 0; i < 4; ++i) {
            const int ro = mbase + 16 * i + lrow;
            ah[i]  = *(const frag_ab*)&sAh[cur][ro][kq];
            al4[i] = *(const frag_ab*)&sAl[cur][ro][kq];
        }
        #pragma unroll
        for (int j = 0; j < 4; ++j) {
            const int ro = nbase + 16 * j + lrow;
            bh[j]  = *(const frag_ab*)&sBh[cur][ro][kq];
            bl4[j] = *(const frag_ab*)&sBl[cur][ro][kq];
        }
        #pragma unroll
        for (int i = 0; i < 4; ++i)
            #pragma unroll
            for (int j = 0; j < 4; ++j) {
                acc[i][j] = __builtin_amdgcn_mfma_f32_16x16x32_bf16(
                    ah[i], bh[j], acc[i][j], 0, 0, 0);
                acc[i][j] = __builtin_amdgcn_mfma_f32_16x16x32_bf16(
                    al4[i], bh[j], acc[i][j], 0, 0, 0);
                acc[i][j] = __builtin_amdgcn_mfma_f32_16x16x32_bf16(
                    ah[i], bl4[j], acc[i][j], 0, 0, 0);
            }
        __syncthreads();
        cur ^= 1;
    }

    const int quad = l >> 4;
    #pragma unroll
    for (int i = 0; i < 4; ++i) {
        #pragma unroll
        for (int j = 0; j < 4; ++j) {
            const int coln = bn + nbase + 16 * j + lrow;
            #pragma unroll
            for (int r = 0; r < 4; ++r) {
                const int rowm = bm + mbase + 16 * i + quad * 4 + r;
                const size_t idx = (size_t)rowm * N + coln;
                float v = acc[i][j][r];
                if (Cf) Cf[idx] = v;
                if (Ch) { u16 hi, lo; split2(v, hi, lo); Ch[idx] = hi; Cl[idx] = lo; }
            }
        }
    }
}

// ---------------------------------------------------------------------------
// Plain bf16 MFMA GEMM (v, Y): C[m,n] = sum_k A[m,k]*B[n,k], A/B pre-converted
// u16 bf16 (pure global_load_lds staging). 128x128, BK=64 panel layout,
// double-buffered 2-phase, XCD swizzle.
// ---------------------------------------------------------------------------
__global__ __launch_bounds__(256) void gemm_bf16(
    const u16* __restrict__ Ab, const u16* __restrict__ Bb,
    void* __restrict__ Cdst, int cmode, const int* __restrict__ flag,
    int M, int N, int K)
{
    __shared__ u16 As[2][2][128][32];   // [dbuf][ks][row][k]  32 KB
    __shared__ u16 Bs[2][2][128][32];   // 64 KB total
    const int cbf = (cmode == 1) ? *flag : 0;

    int bx, by; swizzle_block(bx, by);
    const int bm = by * 128, bn = bx * 128;
    const int tid = threadIdx.x;
    const int l = tid & 63, w = tid >> 6;
    const int mbase = (w & 1) * 64, nbase = (w >> 1) * 64;
    const int lrow = l & 15, kq = (l >> 4) << 3;

    frag_cd acc[4][4];
    #pragma unroll
    for (int i = 0; i < 4; ++i)
        #pragma unroll
        for (int j = 0; j < 4; ++j)
            #pragma unroll
            for (int r = 0; r < 4; ++r) acc[i][j][r] = 0.0f;

    auto STAGE = [&](int buf, int k0) {
        #pragma unroll
        for (int half = 0; half < 4; ++half) {
            const int c   = tid + half * 256;
            const int ks  = c >> 9;
            const int row = (c >> 2) & 127;
            const int ko  = ks * 32 + (c & 3) * 8;
            const size_t ga = (size_t)(bm + row) * K + k0 + ko;
            const size_t gb = (size_t)(bn + row) * K + k0 + ko;
            gl_lds16(Ab + ga, &As[buf][0][0][0] + (c << 3));
            gl_lds16(Bb + gb, &Bs[buf][0][0][0] + (c << 3));
        }
    };

    STAGE(0, 0);
    __syncthreads();
    const int NT = K >> 6;
    int cur = 0;
    for (int t = 0; t < NT; ++t) {
        if (t + 1 < NT) STAGE(cur ^ 1, (t + 1) << 6);
        #pragma unroll
        for (int ks = 0; ks < 2; ++ks) {
            frag_ab a[4], b[4];
            #pragma unroll
            for (int i = 0; i < 4; ++i)
                a[i] = *(const frag_ab*)&As[cur][ks][mbase + 16 * i + lrow][kq];
            #pragma unroll
            for (int j = 0; j < 4; ++j)
                b[j] = *(const frag_ab*)&Bs[cur][ks][nbase + 16 * j + lrow][kq];
            #pragma unroll
            for (int i = 0; i < 4; ++i)
                #pragma unroll
                for (int j = 0; j < 4; ++j)
                    acc[i][j] = __builtin_amdgcn_mfma_f32_16x16x32_bf16(
                        a[i], b[j], acc[i][j], 0, 0, 0);
        }
        __syncthreads();
        cur ^= 1;
    }

    const int quad = l >> 4;
    #pragma unroll
    for (int i = 0; i < 4; ++i) {
        #pragma unroll
        for (int j = 0; j < 4; ++j) {
            const int coln = bn + nbase + 16 * j + lrow;
            #pragma unroll
            for (int r = 0; r < 4; ++r) {
                const int rowm = bm + mbase + 16 * i + quad * 4 + r;
                const size_t idx = (size_t)rowm * N + coln;
                float v = acc[i][j][r];
                if (cbf) ((u16*)Cdst)[idx] = f2bf(v);
                else     ((float*)Cdst)[idx] = v;
            }
        }
    }
}

// ---------------------------------------------------------------------------
// qv = bf16(recon(qh,ql) * v) — A operand for the Y GEMM
// ---------------------------------------------------------------------------
__global__ __launch_bounds__(256) void qvb_k(const u16* __restrict__ qh,
                                             const u16* __restrict__ ql,
                                             const float* __restrict__ V,
                                             u16* __restrict__ out, int n4)
{
    int i = blockIdx.x * 256 + threadIdx.x;
    if (i >= n4) return;
    u16x4 h = ((const u16x4*)qh)[i], lo = ((const u16x4*)ql)[i];
    float4 v = ((const float4*)V)[i];
    u16x4 o;
    o[0] = f2bf((bf2f(h[0]) + bf2f(lo[0])) * v.x);
    o[1] = f2bf((bf2f(h[1]) + bf2f(lo[1])) * v.y);
    o[2] = f2bf((bf2f(h[2]) + bf2f(lo[2])) * v.z);
    o[3] = f2bf((bf2f(h[3]) + bf2f(lo[3])) * v.w);
    ((u16x4*)out)[i] = o;
}

// store recon(q) into d_out at element offset (in float4/u16x4 units)
__global__ __launch_bounds__(256) void store_split_k(
    const u16* __restrict__ h, const u16* __restrict__ l,
    void* __restrict__ out, int n4, size_t off4,
    const int* __restrict__ flag)
{
    int i = blockIdx.x * 256 + threadIdx.x;
    if (i >= n4) return;
    u16x4 hh = ((const u16x4*)h)[i], ll = ((const u16x4*)l)[i];
    float4 f;
    f.x = bf2f(hh[0]) + bf2f(ll[0]);
    f.y = bf2f(hh[1]) + bf2f(ll[1]);
    f.z = bf2f(hh[2]) + bf2f(ll[2]);
    f.w = bf2f(hh[3]) + bf2f(ll[3]);
    if (*flag) {
        u16x4 o; o[0] = f2bf(f.x); o[1] = f2bf(f.y); o[2] = f2bf(f.z); o[3] = f2bf(f.w);
        ((u16x4*)out)[off4 + i] = o;
    } else {
        ((float4*)out)[off4 + i] = f;
    }
}

// idW[j] = sum_i identf[i] * W[i,j] — 64 blocks x 16 rows, atomic combine
__global__ __launch_bounds__(256) void idw2_k(
    const float* __restrict__ identf, const float* __restrict__ W,
    float* __restrict__ idW)
{
    const int b = blockIdx.x;
    const int j = threadIdx.x;
    float a0 = 0, a1 = 0, a2 = 0, a3 = 0;
    #pragma unroll
    for (int ii = 0; ii < 16; ++ii) {
        const int i = b * 16 + ii;
        const float s = identf[i];
        const float* row = W + (size_t)i * C_;
        a0 += s * row[j];
        a1 += s * row[j + 256];
        a2 += s * row[j + 512];
        a3 += s * row[j + 768];
    }
    atomicAdd(idW + j, a0);       atomicAdd(idW + j + 256, a1);
    atomicAdd(idW + j + 512, a2); atomicAdd(idW + j + 768, a3);
}

// ---------------------------------------------------------------------------
// scan combine, vectorized: one block per token (identity mapping — the
// round-6 XCD token remap is REVERTED: it filled each XCD's L2 with dirty
// streamed-once A lines, evicting the 8x-reused B panel of the next GEMM).
// Thread t owns elements [4t, 4t+4): all global loads are u16x4/float4,
// wave w owns SDPA lane w. Only k and v staged in LDS (8 KB); scores via
// per-thread float4 dot + 64-lane wave_reduce (all 4 waves active).
// Same math as proven combine2_k; reduction regrouping reassociates f32
// sums at ~1e-7 relative (invisible under the bf16 output floor).
// ---------------------------------------------------------------------------
__global__ __launch_bounds__(256) void combine3_k(
    const u16* __restrict__ curh, const u16* __restrict__ curl,
    const float* __restrict__ xW,
    const float* __restrict__ idW, const float* __restrict__ identf,
    u16* __restrict__ nxth, u16* __restrict__ nxtl, int d)
{
    const int token = blockIdx.x;
    const int t = token & (T_ - 1);
    const int tid = threadIdx.x;
    const bool hl = (t >= d);
    const size_t rbase = (size_t)token * C_;
    const size_t lbase = hl ? (size_t)(token - d) * C_ : 0;
    const float* leftW  = hl ? xW + lbase : idW;
    const float* rightW = xW + rbase;

    const int e0   = tid << 2;          // element base (4 consecutive)
    const int a    = tid >> 6;          // SDPA lane owned by this wave
    const int dd   = (tid & 63) << 2;   // within-lane element offset
    const int lane = tid & 63;

    float q4[4], k4[4], v4[4];
    {
        u16x4 kh = *(const u16x4*)&curh[rbase + e0];
        u16x4 kl = *(const u16x4*)&curl[rbase + e0];
        #pragma unroll
        for (int e = 0; e < 4; ++e) k4[e] = bf2f(kh[e]) + bf2f(kl[e]);
        if (hl) {
            u16x4 qh = *(const u16x4*)&curh[lbase + e0];
            u16x4 ql = *(const u16x4*)&curl[lbase + e0];
            #pragma unroll
            for (int e = 0; e < 4; ++e) q4[e] = bf2f(qh[e]) + bf2f(ql[e]);
        } else {
            float4 iv = *(const float4*)&identf[e0];
            q4[0] = iv.x; q4[1] = iv.y; q4[2] = iv.z; q4[3] = iv.w;
        }
        float4 lw = *(const float4*)&leftW[e0];
        float4 rw = *(const float4*)&rightW[e0];
        v4[0] = lw.x + rw.x; v4[1] = lw.y + rw.y;
        v4[2] = lw.z + rw.z; v4[3] = lw.w + rw.w;
    }

    __shared__ float ks[4][256];
    __shared__ float vs[4][256];
    __shared__ float red[16];
    __shared__ float att[16];
    __shared__ float rs4[4];
    {
        float4 kv = { k4[0], k4[1], k4[2], k4[3] };
        float4 vv = { v4[0], v4[1], v4[2], v4[3] };
        *(float4*)&ks[a][dd] = kv;
        *(float4*)&vs[a][dd] = vv;
    }
    __syncthreads();

    // wave a computes scores S[a][b] = (1/16) * sum_d q[a][d] k[b][d]
    #pragma unroll
    for (int b = 0; b < 4; ++b) {
        float4 kk = *(const float4*)&ks[b][dd];
        float pp = q4[0] * kk.x + q4[1] * kk.y + q4[2] * kk.z + q4[3] * kk.w;
        float sb = wave_reduce(pp);
        if (lane == 0) red[a * 4 + b] = sb * 0.0625f;
    }
    __syncthreads();
    if (tid < 4) {
        float s0 = red[tid * 4 + 0], s1 = red[tid * 4 + 1];
        float s2 = red[tid * 4 + 2], s3 = red[tid * 4 + 3];
        float mx = fmaxf(fmaxf(s0, s1), fmaxf(s2, s3));
        float x0 = __expf(s0 - mx), x1 = __expf(s1 - mx);
        float x2 = __expf(s2 - mx), x3 = __expf(s3 - mx);
        float inv = 1.0f / (x0 + x1 + x2 + x3);
        att[tid * 4 + 0] = x0 * inv; att[tid * 4 + 1] = x1 * inv;
        att[tid * 4 + 2] = x2 * inv; att[tid * 4 + 3] = x3 * inv;
    }
    __syncthreads();

    // z[a][d] = sum_b att[a][b] v[b][d]  (this thread: 4 d's of lane a)
    const float a0 = att[a * 4 + 0], a1 = att[a * 4 + 1];
    const float a2 = att[a * 4 + 2], a3 = att[a * 4 + 3];
    float4 v0 = *(const float4*)&vs[0][dd];
    float4 v1 = *(const float4*)&vs[1][dd];
    float4 v2 = *(const float4*)&vs[2][dd];
    float4 v3 = *(const float4*)&vs[3][dd];
    float z4[4];
    z4[0] = a0 * v0.x + a1 * v1.x + a2 * v2.x + a3 * v3.x;
    z4[1] = a0 * v0.y + a1 * v1.y + a2 * v2.y + a3 * v3.y;
    z4[2] = a0 * v0.z + a1 * v1.z + a2 * v2.z + a3 * v3.z;
    z4[3] = a0 * v0.w + a1 * v1.w + a2 * v2.w + a3 * v3.w;

    // rms over lane a's 256 elements (one wave_reduce per wave)
    float ssp = z4[0] * z4[0] + z4[1] * z4[1] + z4[2] * z4[2] + z4[3] * z4[3];
    float ss = wave_reduce(ssp);
    if (lane == 0) rs4[a] = rsqrtf(ss * (1.0f / HD) + 1e-8f);
    __syncthreads();

    const float rs = rs4[a] * (1.0f / (float)(a + 1));
    u16x4 oh, ol;
    #pragma unroll
    for (int e = 0; e < 4; ++e) {
        float out = q4[e] + z4[e] * rs;
        u16 hi, lo; split2(out, hi, lo);
        oh[e] = hi; ol[e] = lo;
    }
    *(u16x4*)&nxth[rbase + e0] = oh;
    *(u16x4*)&nxtl[rbase + e0] = ol;
}

// ---------------------------------------------------------------------------
extern "C" void kernel_launch(void* const* d_in, const int* in_sizes, int n_in,
                              void* d_out, int out_size, void* d_ws, size_t ws_size,
                              hipStream_t stream)
{
    const void* x     = d_in[0];
    const void* Wup   = d_in[1];
    const void* Wv    = d_in[2];
    const void* Wproj = d_in[3];
    const void* ident = d_in[4];
    const void* Wraw  = d_in[5];

    float* ws = (float*)d_ws;
    int*   flagp  = (int*)ws;                    // meta[0]
    float* sumsqp = ws + 1;                      // meta[1]
    float* W0     = ws + 256;                    // 1M f32
    float* W1     = W0 + (1 << 20);              // 1M f32
    float* identf = W1 + (1 << 20);              // 1024
    float* idW    = identf + 1024;               // 1024
    float* F1     = idW + 1024;                  // 8M f32 (xW / v scratch)
    u16*   WTh    = (u16*)(F1 + (size_t)NTOK * C_);  // W^T split hi (1M u16)
    u16*   WTl    = WTh + (1 << 20);
    u16*   WUh    = WTl + (1 << 20);             // Wup split / WVb
    u16*   WUl    = WUh + (1 << 20);             //            / WPb
    u16*   Q0h    = WUl + (1 << 20);             // q split dbuf A (8M u16 ea)
    u16*   Q0l    = Q0h + (size_t)NTOK * C_;
    u16*   Q1h    = Q0l + (size_t)NTOK * C_;     // q split dbuf B
    u16*   Q1l    = Q1h + (size_t)NTOK * C_;

    const int NC = C_ * C_;          // 1M
    const int NX = NTOK * C_;        // 8M

    // ---- dtype detection ----
    detect_k<<<1, 256, 0, stream>>>((const u16*)Wup, flagp);

    // ---- polar(W_raw) via Newton-Schulz, split-bf16 MFMA (4-term) ----
    hipMemsetAsync(sumsqp, 0, sizeof(float), stream);
    conv_k<<<NC / 256, 256, 0, stream>>>(Wraw, W0, NC, flagp);
    sumsq_k<<<NC / 256, 256, 0, stream>>>(W0, sumsqp);
    scale_k<<<NC / 256, 256, 0, stream>>>(W0, sumsqp);

    // NS split scratch aliases (Q0 region is dead until q0; WU* dead until q0)
    u16* Gh   = WUh;  u16* Gl = WUl;
    u16* Xh2[2] = { Q0h,                 Q0h + 2 * (1 << 20) };
    u16* Xl2[2] = { Q0h + (1 << 20),     Q0h + 3 * (1 << 20) };

    split_k<<<NC / 256, 256, 0, stream>>>(W0, Xh2[0], Xl2[0], NC);
    transpose_split_k<<<dim3(32, 32), 256, 0, stream>>>(W0, WTh, WTl);

    float* Xf = W0; float* Yf = W1; int cur = 0;
    const dim3 gNS(16, 16);
    for (int it = 0; it < 23; ++it) {           // 18 doubling + 5 polish
        bool polish = (it >= 18);
        float a = polish ? 1.5f : 2.0f;
        float b = polish ? -0.5f : -1.0f;
        // G = X^T X  (A = B = X^T split) -> split output
        gemm_split64<<<gNS, 256, 0, stream>>>(WTh, WTl, WTh, WTl,
                                              nullptr, Gh, Gl,
                                              nullptr, 0.0f, 1.0f, C_, C_, C_,
                                              nullptr, nullptr);
        // Y = b*(X G) + a*X  (G symmetric) -> f32 + row split + fused W^T split
        gemm_split64<<<gNS, 256, 0, stream>>>(Xh2[cur], Xl2[cur], Gh, Gl,
                                              Yf, Xh2[cur ^ 1], Xl2[cur ^ 1],
                                              Xf, a, b, C_, C_, C_,
                                              WTh, WTl);
        float* tmp = Xf; Xf = Yf; Yf = tmp; cur ^= 1;
    }
    // Xf = polar(W_raw) f32 ; WTh/WTl = W^T split, ready for the scan

    conv_k<<<4, 256, 0, stream>>>(ident, identf, 1024, flagp);
    hipMemsetAsync(idW, 0, C_ * sizeof(float), stream);
    idw2_k<<<64, 256, 0, stream>>>(identf, Xf, idW);

    const dim3 g128(C_ / 128, NTOK / 128);   // (8, 64)

    // ---- q0 = x @ Wup^T  (split-bf16 MFMA) ----
    conv_split_k<<<NX / 1024, 256, 0, stream>>>(x, Q1h, Q1l, NX / 4, flagp);
    conv_split_k<<<NC / 1024, 256, 0, stream>>>(Wup, WUh, WUl, NC / 4, flagp);
    gemm_split<<<g128, 256, 0, stream>>>(Q1h, Q1l, WUh, WUl,
                                         nullptr, Q0h, Q0l, NTOK, C_, C_);

    // ---- scan: 11 Hillis-Steele steps, q carried as split bf16 pairs ----
    u16 *ch = Q0h, *cl = Q0l, *nh = Q1h, *nl = Q1l;
    for (int d = 1; d < T_; d <<= 1) {
        gemm_split<<<g128, 256, 0, stream>>>(ch, cl, WTh, WTl,
                                             F1, nullptr, nullptr, NTOK, C_, C_);
        combine3_k<<<NTOK, 256, 0, stream>>>(ch, cl, F1, idW, identf, nh, nl, d);
        u16* t1 = ch; ch = nh; nh = t1;
        u16* t2 = cl; cl = nl; nl = t2;
    }
    // 11 steps (odd) -> ch/cl = Q1h/Q1l hold q; Q0*, F1, WU* free

    // ---- pre-convert weights / x to bf16 ----
    convb_k<<<NC / 1024, 256, 0, stream>>>(Wv,    WUh, NC / 4, flagp);   // WVb
    convb_k<<<NC / 1024, 256, 0, stream>>>(Wproj, WUl, NC / 4, flagp);   // WPb
    convb_k<<<NX / 1024, 256, 0, stream>>>(x,     Q0h, NX / 4, flagp);   // xb

    // ---- v = x @ Wv^T  (pure bf16 MFMA) -> F1 f32 ----
    gemm_bf16<<<g128, 256, 0, stream>>>(Q0h, WUh, F1, 0, flagp, NTOK, C_, C_);

    // ---- Y = (q .* v) @ Wproj^T -> d_out[0:NX] ----
    qvb_k<<<NX / 1024, 256, 0, stream>>>(ch, cl, F1, Q0l, NX / 4);
    gemm_bf16<<<g128, 256, 0, stream>>>(Q0l, WUl, d_out, 1, flagp, NTOK, C_, C_);

    // ---- second output: q ----
    store_split_k<<<NX / 1024, 256, 0, stream>>>(ch, cl, d_out, NX / 4,
                                                 (size_t)(NX / 4), flagp);
}

// Round 8
// 1891.022 us; speedup vs baseline: 2.6859x; 1.0721x over previous
//
#include <hip/hip_runtime.h>
#include <hip/hip_bf16.h>

#define DEVINL __device__ __forceinline__

constexpr int B_   = 4;
constexpr int T_   = 2048;
constexpr int C_   = 1024;
constexpr int NTOK = B_ * T_;      // 8192
constexpr int HD   = 256;          // C_/4

typedef unsigned short u16;
typedef __attribute__((ext_vector_type(8))) short  frag_ab;  // 8 bf16 (4 VGPRs)
typedef __attribute__((ext_vector_type(4))) float  frag_cd;  // 4 fp32
typedef __attribute__((ext_vector_type(8))) u16    u16x8;
typedef __attribute__((ext_vector_type(4))) u16    u16x4;

DEVINL float bf2f(u16 u) {
    unsigned int x = ((unsigned int)u) << 16;
    return __uint_as_float(x);
}
DEVINL u16 f2bf(float f) {
    unsigned int x = __float_as_uint(f);
    unsigned int r = (x + 0x7fffu + ((x >> 16) & 1u)) >> 16;
    return (u16)r;
}
// f == bf2f(h) + bf2f(l) + O(2^-18 |f|); residual subtraction exact (Sterbenz).
DEVINL void split2(float f, u16& h, u16& l) {
    h = f2bf(f);
    l = f2bf(f - bf2f(h));
}
DEVINL float wave_reduce(float v) {
    #pragma unroll
    for (int off = 32; off > 0; off >>= 1) v += __shfl_down(v, off, 64);
    return v;
}
DEVINL void gl_lds16(const void* g, void* l) {
    __builtin_amdgcn_global_load_lds(
        (const __attribute__((address_space(1))) unsigned int*)g,
        (__attribute__((address_space(3))) unsigned int*)l, 16, 0, 0);
}

// XCD-aware remap for (8,64) grids: hw%8 = XCD (round-robin); give each XCD
// 8 M-panels x 8 N-cols so its A footprint (4MB split / 2MB bf16) is L2-resident
// and each A panel is fetched by exactly one XCD (was 8x over-fetch).
DEVINL void swizzle_block(int& bx, int& by) {
    const int hw = (int)(blockIdx.x + gridDim.x * blockIdx.y);
    if (gridDim.x == 8 && gridDim.y == 64) {
        const int xcd = hw & 7, idx = hw >> 3;
        by = xcd * 8 + (idx & 7);
        bx = idx >> 3;
    } else { bx = blockIdx.x; by = blockIdx.y; }
}

// ---------------------------------------------------------------------------
// dtype auto-detect (flag: 1 = bf16 inputs, 0 = f32 inputs)
// ---------------------------------------------------------------------------
__global__ __launch_bounds__(256) void detect_k(const u16* __restrict__ w,
                                                int* __restrict__ flag)
{
    int tid = threadIdx.x;
    int cnt = 0;
    for (int i = tid; i < 4096; i += 256) {
        u16 u = w[2 * i];
        int e = (u >> 7) & 0xFF;
        if (u == 0 || (e >= 96 && e <= 134)) cnt++;
    }
    __shared__ int sh[256];
    sh[tid] = cnt; __syncthreads();
    for (int s = 128; s > 0; s >>= 1) {
        if (tid < s) sh[tid] += sh[tid + s];
        __syncthreads();
    }
    if (tid == 0) *flag = (sh[0] > 2048) ? 1 : 0;
}

// Wraw conversion + Frobenius sumsq in one pass (bit-identical to conv+sumsq)
__global__ __launch_bounds__(256) void conv_sumsq_k(const void* __restrict__ src,
                                                    float* __restrict__ dst,
                                                    const int* __restrict__ flag,
                                                    float* __restrict__ sumsq)
{
    int i = blockIdx.x * 256 + threadIdx.x;
    float f = (*flag) ? bf2f(((const u16*)src)[i]) : ((const float*)src)[i];
    dst[i] = f;
    float p = wave_reduce(f * f);
    __shared__ float r[4];
    int lane = threadIdx.x & 63, w = threadIdx.x >> 6;
    if (lane == 0) r[w] = p;
    __syncthreads();
    if (threadIdx.x == 0) atomicAdd(sumsq, r[0] + r[1] + r[2] + r[3]);
}

// scale X in place + write row-major split (bit-identical to scale+split)
__global__ __launch_bounds__(256) void scale_split_k(float* __restrict__ X,
                                                     const float* __restrict__ sumsq,
                                                     u16* __restrict__ H,
                                                     u16* __restrict__ L)
{
    int i = blockIdx.x * 256 + threadIdx.x;
    float F = sqrtf(*sumsq);
    float s = 16.0f / (1.1f * F);   // Gaussian: sigma_max ~= F/16; 10% margin
    float f = X[i] * s;
    X[i] = f;
    u16 hi, lo; split2(f, hi, lo);
    H[i] = hi; L[i] = lo;
}

// identf conversion + idW zeroing (grid 4 x 256)
__global__ __launch_bounds__(256) void ident_init_k(const void* __restrict__ ident,
                                                    float* __restrict__ identf,
                                                    float* __restrict__ idW,
                                                    const int* __restrict__ flag)
{
    int j = blockIdx.x * 256 + threadIdx.x;
    identf[j] = (*flag) ? bf2f(((const u16*)ident)[j]) : ((const float*)ident)[j];
    idW[j] = 0.0f;
}

// Th/Tl[n*C_+k] = split(W[k*C_+n])  — LDS 32x32 tile transpose (initial only)
__global__ __launch_bounds__(256) void transpose_split_k(
    const float* __restrict__ W, u16* __restrict__ Th, u16* __restrict__ Tl)
{
    __shared__ float tile[32][33];
    const int k0 = blockIdx.y * 32;
    const int n0 = blockIdx.x * 32;
    const int tx = threadIdx.x & 31, ty = threadIdx.x >> 5;   // 32 x 8
    #pragma unroll
    for (int r = 0; r < 32; r += 8)
        tile[ty + r][tx] = W[(size_t)(k0 + ty + r) * C_ + n0 + tx];
    __syncthreads();
    #pragma unroll
    for (int r = 0; r < 32; r += 8) {
        float f = tile[tx][ty + r];                 // = W[k0+tx][n0+ty+r]
        size_t idx = (size_t)(n0 + ty + r) * C_ + k0 + tx;
        u16 hi, lo; split2(f, hi, lo);
        Th[idx] = hi; Tl[idx] = lo;
    }
}

// ---------------------------------------------------------------------------
// NS split-bf16 MFMA GEMM: C[m,n] = beta*sum_k A[m,k]*B[n,k]
//                                   + alpha*D[m,n] + alpha2*D2[m,n]
// 64x64 tile, BK=128, 4-term (hh+lh+hl+ll), double-buffered 2-phase prefetch,
// 128 KB LDS. Optional epilogue outputs: f32 (Cf), row-major split (Ch/Cl),
// LDS-transposed split (Th/Tl) (fold proven rounds 4-7). D2 added for the
// quintic iteration's aX + bH term.
// ---------------------------------------------------------------------------
__global__ __launch_bounds__(256) void gemm_split64(
    const u16* __restrict__ Ah, const u16* __restrict__ Al,
    const u16* __restrict__ Bh, const u16* __restrict__ Bl,
    float* __restrict__ Cf, u16* __restrict__ Ch, u16* __restrict__ Cl,
    const float* __restrict__ D, float alpha,
    const float* __restrict__ D2, float alpha2, float beta,
    int M, int N, int K,
    u16* __restrict__ Th, u16* __restrict__ Tl)
{
    __shared__ u16 sAh[2][4][64][32];   // [dbuf][ks][row][k]  32 KB
    __shared__ u16 sAl[2][4][64][32];
    __shared__ u16 sBh[2][4][64][32];
    __shared__ u16 sBl[2][4][64][32];   // total 128 KB (1 block/CU)

    const int bm = blockIdx.y * 64, bn = blockIdx.x * 64;
    const int tid = threadIdx.x;
    const int l = tid & 63, w = tid >> 6;
    const int mbase = (w & 1) * 32, nbase = (w >> 1) * 32;
    const int lrow = l & 15, kq = (l >> 4) << 3;

    frag_cd acc[2][2];
    #pragma unroll
    for (int i = 0; i < 2; ++i)
        #pragma unroll
        for (int j = 0; j < 2; ++j)
            #pragma unroll
            for (int r = 0; r < 4; ++r) acc[i][j][r] = 0.0f;

    auto STAGE = [&](int buf, int k0) {
        #pragma unroll
        for (int half = 0; half < 4; ++half) {
            const int c   = tid + half * 256;
            const int ks  = c >> 8;
            const int row = (c >> 2) & 63;
            const int ko  = ks * 32 + (c & 3) * 8;
            const size_t ga = (size_t)(bm + row) * K + k0 + ko;
            const size_t gb = (size_t)(bn + row) * K + k0 + ko;
            gl_lds16(Ah + ga, &sAh[0][0][0][0] + buf * 8192 + (c << 3));
            gl_lds16(Al + ga, &sAl[0][0][0][0] + buf * 8192 + (c << 3));
            gl_lds16(Bh + gb, &sBh[0][0][0][0] + buf * 8192 + (c << 3));
            gl_lds16(Bl + gb, &sBl[0][0][0][0] + buf * 8192 + (c << 3));
        }
    };

    STAGE(0, 0);
    __syncthreads();
    const int NT = K >> 7;   // 8
    int cur = 0;
    for (int t = 0; t < NT; ++t) {
        if (t + 1 < NT) STAGE(cur ^ 1, (t + 1) << 7);
        #pragma unroll
        for (int ks = 0; ks < 4; ++ks) {
            frag_ab ah[2], al2[2], bh[2], bl2[2];
            #pragma unroll
            for (int i = 0; i < 2; ++i) {
                const int ro = mbase + 16 * i + lrow;
                ah[i]  = *(const frag_ab*)&sAh[cur][ks][ro][kq];
                al2[i] = *(const frag_ab*)&sAl[cur][ks][ro][kq];
            }
            #pragma unroll
            for (int j = 0; j < 2; ++j) {
                const int ro = nbase + 16 * j + lrow;
                bh[j]  = *(const frag_ab*)&sBh[cur][ks][ro][kq];
                bl2[j] = *(const frag_ab*)&sBl[cur][ks][ro][kq];
            }
            #pragma unroll
            for (int i = 0; i < 2; ++i)
                #pragma unroll
                for (int j = 0; j < 2; ++j) {
                    acc[i][j] = __builtin_amdgcn_mfma_f32_16x16x32_bf16(
                        ah[i], bh[j], acc[i][j], 0, 0, 0);
                    acc[i][j] = __builtin_amdgcn_mfma_f32_16x16x32_bf16(
                        al2[i], bh[j], acc[i][j], 0, 0, 0);
                    acc[i][j] = __builtin_amdgcn_mfma_f32_16x16x32_bf16(
                        ah[i], bl2[j], acc[i][j], 0, 0, 0);
                    acc[i][j] = __builtin_amdgcn_mfma_f32_16x16x32_bf16(
                        al2[i], bl2[j], acc[i][j], 0, 0, 0);
                }
        }
        __syncthreads();
        cur ^= 1;
    }

    // epilogue (after final K-loop barrier: staging LDS is dead, reusable)
    const int quad = l >> 4;
    u16* tileH = &sAh[0][0][0][0];   // 64*68 u16 = 8.5 KB, fits in sAh
    u16* tileL = &sAl[0][0][0][0];
    #pragma unroll
    for (int i = 0; i < 2; ++i) {
        #pragma unroll
        for (int j = 0; j < 2; ++j) {
            const int coln = bn + nbase + 16 * j + lrow;
            #pragma unroll
            for (int r = 0; r < 4; ++r) {
                const int rowm = bm + mbase + 16 * i + quad * 4 + r;
                const size_t idx = (size_t)rowm * N + coln;
                float v = beta * acc[i][j][r];
                if (D)  v += alpha  * D[idx];
                if (D2) v += alpha2 * D2[idx];
                if (Cf) Cf[idx] = v;
                u16 hi, lo; split2(v, hi, lo);
                if (Ch) { Ch[idx] = hi; Cl[idx] = lo; }
                if (Th) {
                    const int rl = mbase + 16 * i + quad * 4 + r;   // local row
                    const int cl = nbase + 16 * j + lrow;           // local col
                    tileH[rl * 68 + cl] = hi;
                    tileL[rl * 68 + cl] = lo;
                }
            }
        }
    }
    if (Th) {
        __syncthreads();
        // transposed coalesced write: T[(bn+jj)*N + bm+ii] = tile[ii][jj]
        const int jj  = tid >> 2;          // 0..63
        const int ii0 = (tid & 3) << 4;    // 0,16,32,48
        u16x8 ph0, ph1, pl0, pl1;
        #pragma unroll
        for (int e = 0; e < 8; ++e) {
            ph0[e] = tileH[(ii0 + e) * 68 + jj];
            pl0[e] = tileL[(ii0 + e) * 68 + jj];
            ph1[e] = tileH[(ii0 + 8 + e) * 68 + jj];
            pl1[e] = tileL[(ii0 + 8 + e) * 68 + jj];
        }
        const size_t tb = (size_t)(bn + jj) * N + bm + ii0;
        *(u16x8*)&Th[tb]     = ph0;
        *(u16x8*)&Th[tb + 8] = ph1;
        *(u16x8*)&Tl[tb]     = pl0;
        *(u16x8*)&Tl[tb + 8] = pl1;
    }
}

// ---------------------------------------------------------------------------
// Scan split-bf16 MFMA GEMM: C[m,n] = sum_k A[m,k]*B[n,k], 3-term (bit-identical
// arithmetic to round-1 gemm_split). 128x128 tile, BK=32, double-buffered
// 2-phase prefetch (one barrier/k-step), XCD-swizzled blocks.
// ---------------------------------------------------------------------------
__global__ __launch_bounds__(256) void gemm_split(
    const u16* __restrict__ Ah, const u16* __restrict__ Al,
    const u16* __restrict__ Bh, const u16* __restrict__ Bl,
    float* __restrict__ Cf, u16* __restrict__ Ch, u16* __restrict__ Cl,
    int M, int N, int K)
{
    __shared__ u16 sAh[2][128][32];   // 16 KB each, 64 KB total
    __shared__ u16 sAl[2][128][32];
    __shared__ u16 sBh[2][128][32];
    __shared__ u16 sBl[2][128][32];

    int bx, by; swizzle_block(bx, by);
    const int bm = by * 128, bn = bx * 128;
    const int tid = threadIdx.x;
    const int l = tid & 63, w = tid >> 6;
    const int mbase = (w & 1) * 64, nbase = (w >> 1) * 64;
    const int lrow = l & 15, kq = (l >> 4) << 3;

    frag_cd acc[4][4];
    #pragma unroll
    for (int i = 0; i < 4; ++i)
        #pragma unroll
        for (int j = 0; j < 4; ++j)
            #pragma unroll
            for (int r = 0; r < 4; ++r) acc[i][j][r] = 0.0f;

    auto STAGE = [&](int buf, int k0) {
        #pragma unroll
        for (int half = 0; half < 2; ++half) {
            const int c   = tid + half * 256;
            const int row = c >> 2;
            const int ko  = (c & 3) << 3;
            const size_t ga = (size_t)(bm + row) * K + k0 + ko;
            const size_t gb = (size_t)(bn + row) * K + k0 + ko;
            gl_lds16(Ah + ga, &sAh[buf][0][0] + (c << 3));
            gl_lds16(Al + ga, &sAl[buf][0][0] + (c << 3));
            gl_lds16(Bh + gb, &sBh[buf][0][0] + (c << 3));
            gl_lds16(Bl + gb, &sBl[buf][0][0] + (c << 3));
        }
    };

    STAGE(0, 0);
    __syncthreads();
    const int NT = K >> 5;
    int cur = 0;
    for (int t = 0; t < NT; ++t) {
        if (t + 1 < NT) STAGE(cur ^ 1, (t + 1) << 5);
        frag_ab ah[4], al4[4], bh[4], bl4[4];
        #pragma unroll
        for (int i = 0; i < 4; ++i) {
            const int ro = mbase + 16 * i + lrow;
            ah[i]  = *(const frag_ab*)&sAh[cur][ro][kq];
            al4[i] = *(const frag_ab*)&sAl[cur][ro][kq];
        }
        #pragma unroll
        for (int j = 0; j < 4; ++j) {
            const int ro = nbase + 16 * j + lrow;
            bh[j]  = *(const frag_ab*)&sBh[cur][ro][kq];
            bl4[j] = *(const frag_ab*)&sBl[cur][ro][kq];
        }
        #pragma unroll
        for (int i = 0; i < 4; ++i)
            #pragma unroll
            for (int j = 0; j < 4; ++j) {
                acc[i][j] = __builtin_amdgcn_mfma_f32_16x16x32_bf16(
                    ah[i], bh[j], acc[i][j], 0, 0, 0);
                acc[i][j] = __builtin_amdgcn_mfma_f32_16x16x32_bf16(
                    al4[i], bh[j], acc[i][j], 0, 0, 0);
                acc[i][j] = __builtin_amdgcn_mfma_f32_16x16x32_bf16(
                    ah[i], bl4[j], acc[i][j], 0, 0, 0);
            }
        __syncthreads();
        cur ^= 1;
    }

    const int quad = l >> 4;
    #pragma unroll
    for (int i = 0; i < 4; ++i) {
        #pragma unroll
        for (int j = 0; j < 4; ++j) {
            const int coln = bn + nbase + 16 * j + lrow;
            #pragma unroll
            for (int r = 0; r < 4; ++r) {
                const int rowm = bm + mbase + 16 * i + quad * 4 + r;
                const size_t idx = (size_t)rowm * N + coln;
                float v = acc[i][j][r];
                if (Cf) Cf[idx] = v;
                if (Ch) { u16 hi, lo; split2(v, hi, lo); Ch[idx] = hi; Cl[idx] = lo; }
            }
        }
    }
}

// ---------------------------------------------------------------------------
// Plain bf16 MFMA GEMM (v, Y): C[m,n] = sum_k A[m,k]*B[n,k], A/B pre-converted
// u16 bf16 (pure global_load_lds staging). 128x128, BK=64 panel layout,
// double-buffered 2-phase, XCD swizzle.
// ---------------------------------------------------------------------------
__global__ __launch_bounds__(256) void gemm_bf16(
    const u16* __restrict__ Ab, const u16* __restrict__ Bb,
    void* __restrict__ Cdst, int cmode, const int* __restrict__ flag,
    int M, int N, int K)
{
    __shared__ u16 As[2][2][128][32];   // [dbuf][ks][row][k]  32 KB
    __shared__ u16 Bs[2][2][128][32];   // 64 KB total
    const int cbf = (cmode == 1) ? *flag : 0;

    int bx, by; swizzle_block(bx, by);
    const int bm = by * 128, bn = bx * 128;
    const int tid = threadIdx.x;
    const int l = tid & 63, w = tid >> 6;
    const int mbase = (w & 1) * 64, nbase = (w >> 1) * 64;
    const int lrow = l & 15, kq = (l >> 4) << 3;

    frag_cd acc[4][4];
    #pragma unroll
    for (int i = 0; i < 4; ++i)
        #pragma unroll
        for (int j = 0; j < 4; ++j)
            #pragma unroll
            for (int r = 0; r < 4; ++r) acc[i][j][r] = 0.0f;

    auto STAGE = [&](int buf, int k0) {
        #pragma unroll
        for (int half = 0; half < 4; ++half) {
            const int c   = tid + half * 256;
            const int ks  = c >> 9;
            const int row = (c >> 2) & 127;
            const int ko  = ks * 32 + (c & 3) * 8;
            const size_t ga = (size_t)(bm + row) * K + k0 + ko;
            const size_t gb = (size_t)(bn + row) * K + k0 + ko;
            gl_lds16(Ab + ga, &As[buf][0][0][0] + (c << 3));
            gl_lds16(Bb + gb, &Bs[buf][0][0][0] + (c << 3));
        }
    };

    STAGE(0, 0);
    __syncthreads();
    const int NT = K >> 6;
    int cur = 0;
    for (int t = 0; t < NT; ++t) {
        if (t + 1 < NT) STAGE(cur ^ 1, (t + 1) << 6);
        #pragma unroll
        for (int ks = 0; ks < 2; ++ks) {
            frag_ab a[4], b[4];
            #pragma unroll
            for (int i = 0; i < 4; ++i)
                a[i] = *(const frag_ab*)&As[cur][ks][mbase + 16 * i + lrow][kq];
            #pragma unroll
            for (int j = 0; j < 4; ++j)
                b[j] = *(const frag_ab*)&Bs[cur][ks][nbase + 16 * j + lrow][kq];
            #pragma unroll
            for (int i = 0; i < 4; ++i)
                #pragma unroll
                for (int j = 0; j < 4; ++j)
                    acc[i][j] = __builtin_amdgcn_mfma_f32_16x16x32_bf16(
                        a[i], b[j], acc[i][j], 0, 0, 0);
        }
        __syncthreads();
        cur ^= 1;
    }

    const int quad = l >> 4;
    #pragma unroll
    for (int i = 0; i < 4; ++i) {
        #pragma unroll
        for (int j = 0; j < 4; ++j) {
            const int coln = bn + nbase + 16 * j + lrow;
            #pragma unroll
            for (int r = 0; r < 4; ++r) {
                const int rowm = bm + mbase + 16 * i + quad * 4 + r;
                const size_t idx = (size_t)rowm * N + coln;
                float v = acc[i][j][r];
                if (cbf) ((u16*)Cdst)[idx] = f2bf(v);
                else     ((float*)Cdst)[idx] = v;
            }
        }
    }
}

// ---------------------------------------------------------------------------
// fused conv_split: x -> (Xh,Xl), Wup -> (Wh,Wl). Ranges block-aligned
// (NX/4 = 8192 blocks, NC/4 = 1024 blocks) so no intra-block divergence.
// ---------------------------------------------------------------------------
__global__ __launch_bounds__(256) void prep_q0_k(
    const void* __restrict__ x, const void* __restrict__ wup,
    u16* __restrict__ Xh, u16* __restrict__ Xl,
    u16* __restrict__ Wh, u16* __restrict__ Wl,
    const int* __restrict__ flag)
{
    int i = blockIdx.x * 256 + threadIdx.x;
    const int n4x = (NTOK * C_) / 4;
    const void* src; u16 *H, *L; int idx;
    if (i < n4x) { src = x;   H = Xh; L = Xl; idx = i; }
    else         { src = wup; H = Wh; L = Wl; idx = i - n4x; }
    float f[4];
    if (*flag) {
        u16x4 u = ((const u16x4*)src)[idx];
        f[0] = bf2f(u[0]); f[1] = bf2f(u[1]); f[2] = bf2f(u[2]); f[3] = bf2f(u[3]);
    } else {
        float4 v = ((const float4*)src)[idx];
        f[0] = v.x; f[1] = v.y; f[2] = v.z; f[3] = v.w;
    }
    u16x4 h, lo;
    #pragma unroll
    for (int r = 0; r < 4; ++r) { u16 a, b; split2(f[r], a, b); h[r] = a; lo[r] = b; }
    ((u16x4*)H)[idx] = h; ((u16x4*)L)[idx] = lo;
}

// fused bf16 pre-convert: x -> xb, Wv -> wvb, Wproj -> wpb (block-aligned ranges)
__global__ __launch_bounds__(256) void prep_vy_k(
    const void* __restrict__ x, const void* __restrict__ wv,
    const void* __restrict__ wp,
    u16* __restrict__ xb, u16* __restrict__ wvb, u16* __restrict__ wpb,
    const int* __restrict__ flag)
{
    int i = blockIdx.x * 256 + threadIdx.x;
    const int n4x = (NTOK * C_) / 4;
    const int n4c = (C_ * C_) / 4;
    const void* src; u16* out; int idx;
    if (i < n4x)            { src = x;  out = xb;  idx = i; }
    else if (i < n4x + n4c) { src = wv; out = wvb; idx = i - n4x; }
    else                    { src = wp; out = wpb; idx = i - n4x - n4c; }
    u16x4 o;
    if (*flag) {
        o = ((const u16x4*)src)[idx];
    } else {
        float4 v = ((const float4*)src)[idx];
        o[0] = f2bf(v.x); o[1] = f2bf(v.y); o[2] = f2bf(v.z); o[3] = f2bf(v.w);
    }
    ((u16x4*)out)[idx] = o;
}

// fused qv + q-store: qvout = bf16(recon(q)*v); d_out[NX + i] = recon(q)
// (reads q-split once for both jobs; bit-identical to qvb_k + store_split_k)
__global__ __launch_bounds__(256) void qv_store_k(
    const u16* __restrict__ qh, const u16* __restrict__ ql,
    const float* __restrict__ V, u16* __restrict__ qvout,
    void* __restrict__ out, const int* __restrict__ flag)
{
    int i = blockIdx.x * 256 + threadIdx.x;
    u16x4 h = ((const u16x4*)qh)[i], lo = ((const u16x4*)ql)[i];
    float4 v = ((const float4*)V)[i];
    float r0 = bf2f(h[0]) + bf2f(lo[0]);
    float r1 = bf2f(h[1]) + bf2f(lo[1]);
    float r2 = bf2f(h[2]) + bf2f(lo[2]);
    float r3 = bf2f(h[3]) + bf2f(lo[3]);
    u16x4 o;
    o[0] = f2bf(r0 * v.x); o[1] = f2bf(r1 * v.y);
    o[2] = f2bf(r2 * v.z); o[3] = f2bf(r3 * v.w);
    ((u16x4*)qvout)[i] = o;
    const size_t off4 = (size_t)(NTOK * C_) / 4;
    if (*flag) {
        u16x4 q; q[0] = f2bf(r0); q[1] = f2bf(r1); q[2] = f2bf(r2); q[3] = f2bf(r3);
        ((u16x4*)out)[off4 + i] = q;
    } else {
        float4 f; f.x = r0; f.y = r1; f.z = r2; f.w = r3;
        ((float4*)out)[off4 + i] = f;
    }
}

// idW[j] = sum_i identf[i] * W[i,j] — 64 blocks x 16 rows, atomic combine
__global__ __launch_bounds__(256) void idw2_k(
    const float* __restrict__ identf, const float* __restrict__ W,
    float* __restrict__ idW)
{
    const int b = blockIdx.x;
    const int j = threadIdx.x;
    float a0 = 0, a1 = 0, a2 = 0, a3 = 0;
    #pragma unroll
    for (int ii = 0; ii < 16; ++ii) {
        const int i = b * 16 + ii;
        const float s = identf[i];
        const float* row = W + (size_t)i * C_;
        a0 += s * row[j];
        a1 += s * row[j + 256];
        a2 += s * row[j + 512];
        a3 += s * row[j + 768];
    }
    atomicAdd(idW + j, a0);       atomicAdd(idW + j + 256, a1);
    atomicAdd(idW + j + 512, a2); atomicAdd(idW + j + 768, a3);
}

// ---------------------------------------------------------------------------
// scan combine, 2-barrier version. Math BIT-IDENTICAL to proven combine3:
// softmax recomputed per-thread from the same red[16] values (same FP ops);
// rms broadcast via __shfl(.,0) instead of LDS+barrier. vs/ks written before
// barrier 1 and never modified -> safe to read after barrier 2.
// ---------------------------------------------------------------------------
__global__ __launch_bounds__(256) void combine4_k(
    const u16* __restrict__ curh, const u16* __restrict__ curl,
    const float* __restrict__ xW,
    const float* __restrict__ idW, const float* __restrict__ identf,
    u16* __restrict__ nxth, u16* __restrict__ nxtl, int d)
{
    const int token = blockIdx.x;
    const int t = token & (T_ - 1);
    const int tid = threadIdx.x;
    const bool hl = (t >= d);
    const size_t rbase = (size_t)token * C_;
    const size_t lbase = hl ? (size_t)(token - d) * C_ : 0;
    const float* leftW  = hl ? xW + lbase : idW;
    const float* rightW = xW + rbase;

    const int e0   = tid << 2;          // element base (4 consecutive)
    const int a    = tid >> 6;          // SDPA lane owned by this wave
    const int dd   = (tid & 63) << 2;   // within-lane element offset
    const int lane = tid & 63;

    float q4[4], k4[4], v4[4];
    {
        u16x4 kh = *(const u16x4*)&curh[rbase + e0];
        u16x4 kl = *(const u16x4*)&curl[rbase + e0];
        #pragma unroll
        for (int e = 0; e < 4; ++e) k4[e] = bf2f(kh[e]) + bf2f(kl[e]);
        if (hl) {
            u16x4 qh = *(const u16x4*)&curh[lbase + e0];
            u16x4 ql = *(const u16x4*)&curl[lbase + e0];
            #pragma unroll
            for (int e = 0; e < 4; ++e) q4[e] = bf2f(qh[e]) + bf2f(ql[e]);
        } else {
            float4 iv = *(const float4*)&identf[e0];
            q4[0] = iv.x; q4[1] = iv.y; q4[2] = iv.z; q4[3] = iv.w;
        }
        float4 lw = *(const float4*)&leftW[e0];
        float4 rw = *(const float4*)&rightW[e0];
        v4[0] = lw.x + rw.x; v4[1] = lw.y + rw.y;
        v4[2] = lw.z + rw.z; v4[3] = lw.w + rw.w;
    }

    __shared__ float ks[4][256];
    __shared__ float vs[4][256];
    __shared__ float red[16];
    {
        float4 kv = { k4[0], k4[1], k4[2], k4[3] };
        float4 vv = { v4[0], v4[1], v4[2], v4[3] };
        *(float4*)&ks[a][dd] = kv;
        *(float4*)&vs[a][dd] = vv;
    }
    __syncthreads();

    // wave a computes scores S[a][b] = (1/16) * sum_d q[a][d] k[b][d]
    #pragma unroll
    for (int b = 0; b < 4; ++b) {
        float4 kk = *(const float4*)&ks[b][dd];
        float pp = q4[0] * kk.x + q4[1] * kk.y + q4[2] * kk.z + q4[3] * kk.w;
        float sb = wave_reduce(pp);
        if (lane == 0) red[a * 4 + b] = sb * 0.0625f;
    }
    __syncthreads();

    // per-thread softmax of row a (same values as the old tid<4 section)
    float s0 = red[a * 4 + 0], s1 = red[a * 4 + 1];
    float s2 = red[a * 4 + 2], s3 = red[a * 4 + 3];
    float mx = fmaxf(fmaxf(s0, s1), fmaxf(s2, s3));
    float x0 = __expf(s0 - mx), x1 = __expf(s1 - mx);
    float x2 = __expf(s2 - mx), x3 = __expf(s3 - mx);
    float inv = 1.0f / (x0 + x1 + x2 + x3);
    const float a0 = x0 * inv, a1 = x1 * inv, a2 = x2 * inv, a3 = x3 * inv;

    // z[a][d] = sum_b att[a][b] v[b][d]
    float4 v0 = *(const float4*)&vs[0][dd];
    float4 v1 = *(const float4*)&vs[1][dd];
    float4 v2 = *(const float4*)&vs[2][dd];
    float4 v3 = *(const float4*)&vs[3][dd];
    float z4[4];
    z4[0] = a0 * v0.x + a1 * v1.x + a2 * v2.x + a3 * v3.x;
    z4[1] = a0 * v0.y + a1 * v1.y + a2 * v2.y + a3 * v3.y;
    z4[2] = a0 * v0.z + a1 * v1.z + a2 * v2.z + a3 * v3.z;
    z4[3] = a0 * v0.w + a1 * v1.w + a2 * v2.w + a3 * v3.w;

    // rms over lane a's 256 elements; lane-0 total broadcast via shfl
    float ssp = z4[0] * z4[0] + z4[1] * z4[1] + z4[2] * z4[2] + z4[3] * z4[3];
    float ss = wave_reduce(ssp);
    ss = __shfl(ss, 0, 64);
    const float rs = rsqrtf(ss * (1.0f / HD) + 1e-8f) * (1.0f / (float)(a + 1));

    u16x4 oh, ol;
    #pragma unroll
    for (int e = 0; e < 4; ++e) {
        float out = q4[e] + z4[e] * rs;
        u16 hi, lo; split2(out, hi, lo);
        oh[e] = hi; ol[e] = lo;
    }
    *(u16x4*)&nxth[rbase + e0] = oh;
    *(u16x4*)&nxtl[rbase + e0] = ol;
}

// ---------------------------------------------------------------------------
extern "C" void kernel_launch(void* const* d_in, const int* in_sizes, int n_in,
                              void* d_out, int out_size, void* d_ws, size_t ws_size,
                              hipStream_t stream)
{
    const void* x     = d_in[0];
    const void* Wup   = d_in[1];
    const void* Wv    = d_in[2];
    const void* Wproj = d_in[3];
    const void* ident = d_in[4];
    const void* Wraw  = d_in[5];

    float* ws = (float*)d_ws;
    int*   flagp  = (int*)ws;                    // meta[0]
    float* sumsqp = ws + 1;                      // meta[1]
    float* W0     = ws + 256;                    // 1M f32
    float* W1     = W0 + (1 << 20);              // 1M f32
    float* identf = W1 + (1 << 20);              // 1024
    float* idW    = identf + 1024;               // 1024
    float* F1     = idW + 1024;                  // 8M f32 (xW / v / NS Hf)
    u16*   WTh    = (u16*)(F1 + (size_t)NTOK * C_);  // W^T split hi (1M u16)
    u16*   WTl    = WTh + (1 << 20);
    u16*   WUh    = WTl + (1 << 20);             // Wup split / NS G / WVb
    u16*   WUl    = WUh + (1 << 20);             //            …       / WPb
    u16*   Q0h    = WUl + (1 << 20);             // q split dbuf A (8M u16 ea)
    u16*   Q0l    = Q0h + (size_t)NTOK * C_;
    u16*   Q1h    = Q0l + (size_t)NTOK * C_;     // q split dbuf B
    u16*   Q1l    = Q1h + (size_t)NTOK * C_;

    const int NC = C_ * C_;          // 1M
    const int NX = NTOK * C_;        // 8M

    // ---- dtype detection ----
    detect_k<<<1, 256, 0, stream>>>((const u16*)Wup, flagp);

    // ---- polar(W_raw): quintic-ramp Newton-Schulz, split-bf16 MFMA ----
    hipMemsetAsync(sumsqp, 0, sizeof(float), stream);
    conv_sumsq_k<<<NC / 256, 256, 0, stream>>>(Wraw, W0, flagp, sumsqp);

    // NS split scratch aliases (Q0 region dead until q0; WU* dead until q0)
    u16* Gh = WUh;  u16* Gl = WUl;
    u16* Xh2[2] = { Q0h,             Q0h + 2 * (1 << 20) };
    u16* Xl2[2] = { Q0h + (1 << 20), Q0h + 3 * (1 << 20) };
    u16* Hh = Q0h + 4 * (1 << 20);
    u16* Hl = Q0h + 5 * (1 << 20);
    float* Hf = F1;                               // F1 dead until the scan

    scale_split_k<<<NC / 256, 256, 0, stream>>>(W0, sumsqp, Xh2[0], Xl2[0]);
    transpose_split_k<<<dim3(32, 32), 256, 0, stream>>>(W0, WTh, WTl);

    float* Xf = W0; float* Yf = W1; int cur = 0;
    const dim3 gNS(16, 16);
    // quintic ramp: p(x) = aQ x + bQ x^3 + cQ x^5 (no positive roots; band
    // [0,1.202] invariant; growth 3.44x/iter lifts sigma_min >= 3e-6 in 10)
    const float aQ = 3.4445f, bQ = -4.7750f, cQ = 2.0315f;
    for (int it = 0; it < 10; ++it) {
        // G = X^T X
        gemm_split64<<<gNS, 256, 0, stream>>>(WTh, WTl, WTh, WTl,
                                              nullptr, Gh, Gl,
                                              nullptr, 0.0f, nullptr, 0.0f, 1.0f,
                                              C_, C_, C_, nullptr, nullptr);
        // H = X G  (G symmetric -> B = G row-major)
        gemm_split64<<<gNS, 256, 0, stream>>>(Xh2[cur], Xl2[cur], Gh, Gl,
                                              Hf, Hh, Hl,
                                              nullptr, 0.0f, nullptr, 0.0f, 1.0f,
                                              C_, C_, C_, nullptr, nullptr);
        // Y = cQ*(H G) + aQ*X + bQ*H   -> f32 + row split + fused W^T split
        gemm_split64<<<gNS, 256, 0, stream>>>(Hh, Hl, Gh, Gl,
                                              Yf, Xh2[cur ^ 1], Xl2[cur ^ 1],
                                              Xf, aQ, Hf, bQ, cQ,
                                              C_, C_, C_, WTh, WTl);
        float* tmp = Xf; Xf = Yf; Yf = tmp; cur ^= 1;
    }
    // cubic polish: x -> 1.5x - 0.5x^3 (quadratic convergence at 1)
    for (int it = 0; it < 5; ++it) {
        gemm_split64<<<gNS, 256, 0, stream>>>(WTh, WTl, WTh, WTl,
                                              nullptr, Gh, Gl,
                                              nullptr, 0.0f, nullptr, 0.0f, 1.0f,
                                              C_, C_, C_, nullptr, nullptr);
        gemm_split64<<<gNS, 256, 0, stream>>>(Xh2[cur], Xl2[cur], Gh, Gl,
                                              Yf, Xh2[cur ^ 1], Xl2[cur ^ 1],
                                              Xf, 1.5f, nullptr, 0.0f, -0.5f,
                                              C_, C_, C_, WTh, WTl);
        float* tmp = Xf; Xf = Yf; Yf = tmp; cur ^= 1;
    }
    // Xf = polar(W_raw) f32 ; WTh/WTl = W^T split, ready for the scan

    ident_init_k<<<4, 256, 0, stream>>>(ident, identf, idW, flagp);
    idw2_k<<<64, 256, 0, stream>>>(identf, Xf, idW);

    const dim3 g128(C_ / 128, NTOK / 128);   // (8, 64)

    // ---- q0 = x @ Wup^T  (split-bf16 MFMA) ----
    prep_q0_k<<<(NX + NC) / 1024, 256, 0, stream>>>(x, Wup, Q1h, Q1l,
                                                    WUh, WUl, flagp);
    gemm_split<<<g128, 256, 0, stream>>>(Q1h, Q1l, WUh, WUl,
                                         nullptr, Q0h, Q0l, NTOK, C_, C_);

    // ---- scan: 11 Hillis-Steele steps, q carried as split bf16 pairs ----
    u16 *ch = Q0h, *cl = Q0l, *nh = Q1h, *nl = Q1l;
    for (int d = 1; d < T_; d <<= 1) {
        gemm_split<<<g128, 256, 0, stream>>>(ch, cl, WTh, WTl,
                                             F1, nullptr, nullptr, NTOK, C_, C_);
        combine4_k<<<NTOK, 256, 0, stream>>>(ch, cl, F1, idW, identf, nh, nl, d);
        u16* t1 = ch; ch = nh; nh = t1;
        u16* t2 = cl; cl = nl; nl = t2;
    }
    // 11 steps (odd) -> ch/cl = Q1h/Q1l hold q; Q0*, F1, WU* free

    // ---- pre-convert x / weights to bf16 (one fused dispatch) ----
    prep_vy_k<<<(NX + 2 * NC) / 1024, 256, 0, stream>>>(x, Wv, Wproj,
                                                        Q0h, WUh, WUl, flagp);

    // ---- v = x @ Wv^T  (pure bf16 MFMA) -> F1 f32 ----
    gemm_bf16<<<g128, 256, 0, stream>>>(Q0h, WUh, F1, 0, flagp, NTOK, C_, C_);

    // ---- qv = q.*v (A for Y GEMM) + second output q -> d_out[NX:2NX] ----
    qv_store_k<<<NX / 1024, 256, 0, stream>>>(ch, cl, F1, Q0l, d_out, flagp);

    // ---- Y = (q .* v) @ Wproj^T -> d_out[0:NX] ----
    gemm_bf16<<<g128, 256, 0, stream>>>(Q0l, WUl, d_out, 1, flagp, NTOK, C_, C_);
}

// Round 9
// 1808.806 us; speedup vs baseline: 2.8080x; 1.0455x over previous
//
#include <hip/hip_runtime.h>
#include <hip/hip_bf16.h>

#define DEVINL __device__ __forceinline__

constexpr int B_   = 4;
constexpr int T_   = 2048;
constexpr int C_   = 1024;
constexpr int NTOK = B_ * T_;      // 8192
constexpr int HD   = 256;          // C_/4

typedef unsigned short u16;
typedef __attribute__((ext_vector_type(8))) short  frag_ab;  // 8 bf16 (4 VGPRs)
typedef __attribute__((ext_vector_type(4))) float  frag_cd;  // 4 fp32
typedef __attribute__((ext_vector_type(8))) u16    u16x8;
typedef __attribute__((ext_vector_type(4))) u16    u16x4;

DEVINL float bf2f(u16 u) {
    unsigned int x = ((unsigned int)u) << 16;
    return __uint_as_float(x);
}
DEVINL u16 f2bf(float f) {
    unsigned int x = __float_as_uint(f);
    unsigned int r = (x + 0x7fffu + ((x >> 16) & 1u)) >> 16;
    return (u16)r;
}
// f == bf2f(h) + bf2f(l) + O(2^-18 |f|); residual subtraction exact (Sterbenz).
DEVINL void split2(float f, u16& h, u16& l) {
    h = f2bf(f);
    l = f2bf(f - bf2f(h));
}
DEVINL float wave_reduce(float v) {
    #pragma unroll
    for (int off = 32; off > 0; off >>= 1) v += __shfl_down(v, off, 64);
    return v;
}
DEVINL void gl_lds16(const void* g, void* l) {
    __builtin_amdgcn_global_load_lds(
        (const __attribute__((address_space(1))) unsigned int*)g,
        (__attribute__((address_space(3))) unsigned int*)l, 16, 0, 0);
}

// XCD-aware remap for (8,64) grids: hw%8 = XCD (round-robin); give each XCD
// 8 M-panels x 8 N-cols so its A footprint (4MB split / 2MB bf16) is L2-resident
// and each A panel is fetched by exactly one XCD (was 8x over-fetch).
DEVINL void swizzle_block(int& bx, int& by) {
    const int hw = (int)(blockIdx.x + gridDim.x * blockIdx.y);
    if (gridDim.x == 8 && gridDim.y == 64) {
        const int xcd = hw & 7, idx = hw >> 3;
        by = xcd * 8 + (idx & 7);
        bx = idx >> 3;
    } else { bx = blockIdx.x; by = blockIdx.y; }
}

// ---------------------------------------------------------------------------
// dtype auto-detect (flag: 1 = bf16 inputs, 0 = f32 inputs)
// ---------------------------------------------------------------------------
__global__ __launch_bounds__(256) void detect_k(const u16* __restrict__ w,
                                                int* __restrict__ flag)
{
    int tid = threadIdx.x;
    int cnt = 0;
    for (int i = tid; i < 4096; i += 256) {
        u16 u = w[2 * i];
        int e = (u >> 7) & 0xFF;
        if (u == 0 || (e >= 96 && e <= 134)) cnt++;
    }
    __shared__ int sh[256];
    sh[tid] = cnt; __syncthreads();
    for (int s = 128; s > 0; s >>= 1) {
        if (tid < s) sh[tid] += sh[tid + s];
        __syncthreads();
    }
    if (tid == 0) *flag = (sh[0] > 2048) ? 1 : 0;
}

// Wraw conversion + Frobenius sumsq in one pass (bit-identical to conv+sumsq)
__global__ __launch_bounds__(256) void conv_sumsq_k(const void* __restrict__ src,
                                                    float* __restrict__ dst,
                                                    const int* __restrict__ flag,
                                                    float* __restrict__ sumsq)
{
    int i = blockIdx.x * 256 + threadIdx.x;
    float f = (*flag) ? bf2f(((const u16*)src)[i]) : ((const float*)src)[i];
    dst[i] = f;
    float p = wave_reduce(f * f);
    __shared__ float r[4];
    int lane = threadIdx.x & 63, w = threadIdx.x >> 6;
    if (lane == 0) r[w] = p;
    __syncthreads();
    if (threadIdx.x == 0) atomicAdd(sumsq, r[0] + r[1] + r[2] + r[3]);
}

// scale X in place + write row-major split (bit-identical to scale+split)
__global__ __launch_bounds__(256) void scale_split_k(float* __restrict__ X,
                                                     const float* __restrict__ sumsq,
                                                     u16* __restrict__ H,
                                                     u16* __restrict__ L)
{
    int i = blockIdx.x * 256 + threadIdx.x;
    float F = sqrtf(*sumsq);
    float s = 16.0f / (1.1f * F);   // Gaussian: sigma_max ~= F/16; 10% margin
    float f = X[i] * s;
    X[i] = f;
    u16 hi, lo; split2(f, hi, lo);
    H[i] = hi; L[i] = lo;
}

// identf conversion + idW zeroing (grid 4 x 256)
__global__ __launch_bounds__(256) void ident_init_k(const void* __restrict__ ident,
                                                    float* __restrict__ identf,
                                                    float* __restrict__ idW,
                                                    const int* __restrict__ flag)
{
    int j = blockIdx.x * 256 + threadIdx.x;
    identf[j] = (*flag) ? bf2f(((const u16*)ident)[j]) : ((const float*)ident)[j];
    idW[j] = 0.0f;
}

// Th/Tl[n*C_+k] = split(W[k*C_+n])  — LDS 32x32 tile transpose (initial only)
__global__ __launch_bounds__(256) void transpose_split_k(
    const float* __restrict__ W, u16* __restrict__ Th, u16* __restrict__ Tl)
{
    __shared__ float tile[32][33];
    const int k0 = blockIdx.y * 32;
    const int n0 = blockIdx.x * 32;
    const int tx = threadIdx.x & 31, ty = threadIdx.x >> 5;   // 32 x 8
    #pragma unroll
    for (int r = 0; r < 32; r += 8)
        tile[ty + r][tx] = W[(size_t)(k0 + ty + r) * C_ + n0 + tx];
    __syncthreads();
    #pragma unroll
    for (int r = 0; r < 32; r += 8) {
        float f = tile[tx][ty + r];                 // = W[k0+tx][n0+ty+r]
        size_t idx = (size_t)(n0 + ty + r) * C_ + k0 + tx;
        u16 hi, lo; split2(f, hi, lo);
        Th[idx] = hi; Tl[idx] = lo;
    }
}

// ---------------------------------------------------------------------------
// NS split-bf16 MFMA GEMM:
//   C[m,n] = beta*sum_k A[m,k]*B[n,k] + alpha*recon(D) + alpha2*recon(D2)
// where D/D2 are (hi,lo) split pairs (recon err ~2^-18 — consistent with the
// 4-term MFMA precision; drops the f32 X/H ping-pong arrays entirely).
// 64x64 tile, BK=128, 4-term (hh+lh+hl+ll), double-buffered 2-phase prefetch,
// 128 KB LDS. Optional epilogue outputs: f32 (Cf, final iter only), row-major
// split (Ch/Cl), LDS-transposed split (Th/Tl) (fold proven rounds 4-8).
// ---------------------------------------------------------------------------
__global__ __launch_bounds__(256) void gemm_split64(
    const u16* __restrict__ Ah, const u16* __restrict__ Al,
    const u16* __restrict__ Bh, const u16* __restrict__ Bl,
    float* __restrict__ Cf, u16* __restrict__ Ch, u16* __restrict__ Cl,
    const u16* __restrict__ Dh, const u16* __restrict__ Dl, float alpha,
    const u16* __restrict__ D2h, const u16* __restrict__ D2l, float alpha2,
    float beta, int M, int N, int K,
    u16* __restrict__ Th, u16* __restrict__ Tl)
{
    __shared__ u16 sAh[2][4][64][32];   // [dbuf][ks][row][k]  32 KB
    __shared__ u16 sAl[2][4][64][32];
    __shared__ u16 sBh[2][4][64][32];
    __shared__ u16 sBl[2][4][64][32];   // total 128 KB (1 block/CU)

    const int bm = blockIdx.y * 64, bn = blockIdx.x * 64;
    const int tid = threadIdx.x;
    const int l = tid & 63, w = tid >> 6;
    const int mbase = (w & 1) * 32, nbase = (w >> 1) * 32;
    const int lrow = l & 15, kq = (l >> 4) << 3;

    frag_cd acc[2][2];
    #pragma unroll
    for (int i = 0; i < 2; ++i)
        #pragma unroll
        for (int j = 0; j < 2; ++j)
            #pragma unroll
            for (int r = 0; r < 4; ++r) acc[i][j][r] = 0.0f;

    auto STAGE = [&](int buf, int k0) {
        #pragma unroll
        for (int half = 0; half < 4; ++half) {
            const int c   = tid + half * 256;
            const int ks  = c >> 8;
            const int row = (c >> 2) & 63;
            const int ko  = ks * 32 + (c & 3) * 8;
            const size_t ga = (size_t)(bm + row) * K + k0 + ko;
            const size_t gb = (size_t)(bn + row) * K + k0 + ko;
            gl_lds16(Ah + ga, &sAh[0][0][0][0] + buf * 8192 + (c << 3));
            gl_lds16(Al + ga, &sAl[0][0][0][0] + buf * 8192 + (c << 3));
            gl_lds16(Bh + gb, &sBh[0][0][0][0] + buf * 8192 + (c << 3));
            gl_lds16(Bl + gb, &sBl[0][0][0][0] + buf * 8192 + (c << 3));
        }
    };

    STAGE(0, 0);
    __syncthreads();
    const int NT = K >> 7;   // 8
    int cur = 0;
    for (int t = 0; t < NT; ++t) {
        if (t + 1 < NT) STAGE(cur ^ 1, (t + 1) << 7);
        #pragma unroll
        for (int ks = 0; ks < 4; ++ks) {
            frag_ab ah[2], al2[2], bh[2], bl2[2];
            #pragma unroll
            for (int i = 0; i < 2; ++i) {
                const int ro = mbase + 16 * i + lrow;
                ah[i]  = *(const frag_ab*)&sAh[cur][ks][ro][kq];
                al2[i] = *(const frag_ab*)&sAl[cur][ks][ro][kq];
            }
            #pragma unroll
            for (int j = 0; j < 2; ++j) {
                const int ro = nbase + 16 * j + lrow;
                bh[j]  = *(const frag_ab*)&sBh[cur][ks][ro][kq];
                bl2[j] = *(const frag_ab*)&sBl[cur][ks][ro][kq];
            }
            #pragma unroll
            for (int i = 0; i < 2; ++i)
                #pragma unroll
                for (int j = 0; j < 2; ++j) {
                    acc[i][j] = __builtin_amdgcn_mfma_f32_16x16x32_bf16(
                        ah[i], bh[j], acc[i][j], 0, 0, 0);
                    acc[i][j] = __builtin_amdgcn_mfma_f32_16x16x32_bf16(
                        al2[i], bh[j], acc[i][j], 0, 0, 0);
                    acc[i][j] = __builtin_amdgcn_mfma_f32_16x16x32_bf16(
                        ah[i], bl2[j], acc[i][j], 0, 0, 0);
                    acc[i][j] = __builtin_amdgcn_mfma_f32_16x16x32_bf16(
                        al2[i], bl2[j], acc[i][j], 0, 0, 0);
                }
        }
        __syncthreads();
        cur ^= 1;
    }

    // epilogue (after final K-loop barrier: staging LDS is dead, reusable)
    const int quad = l >> 4;
    u16* tileH = &sAh[0][0][0][0];   // 64*68 u16 = 8.5 KB, fits in sAh
    u16* tileL = &sAl[0][0][0][0];
    #pragma unroll
    for (int i = 0; i < 2; ++i) {
        #pragma unroll
        for (int j = 0; j < 2; ++j) {
            const int coln = bn + nbase + 16 * j + lrow;
            #pragma unroll
            for (int r = 0; r < 4; ++r) {
                const int rowm = bm + mbase + 16 * i + quad * 4 + r;
                const size_t idx = (size_t)rowm * N + coln;
                float v = beta * acc[i][j][r];
                if (Dh)  v += alpha  * (bf2f(Dh[idx])  + bf2f(Dl[idx]));
                if (D2h) v += alpha2 * (bf2f(D2h[idx]) + bf2f(D2l[idx]));
                if (Cf) Cf[idx] = v;
                u16 hi, lo; split2(v, hi, lo);
                if (Ch) { Ch[idx] = hi; Cl[idx] = lo; }
                if (Th) {
                    const int rl = mbase + 16 * i + quad * 4 + r;   // local row
                    const int cl = nbase + 16 * j + lrow;           // local col
                    tileH[rl * 68 + cl] = hi;
                    tileL[rl * 68 + cl] = lo;
                }
            }
        }
    }
    if (Th) {
        __syncthreads();
        // transposed coalesced write: T[(bn+jj)*N + bm+ii] = tile[ii][jj]
        const int jj  = tid >> 2;          // 0..63
        const int ii0 = (tid & 3) << 4;    // 0,16,32,48
        u16x8 ph0, ph1, pl0, pl1;
        #pragma unroll
        for (int e = 0; e < 8; ++e) {
            ph0[e] = tileH[(ii0 + e) * 68 + jj];
            pl0[e] = tileL[(ii0 + e) * 68 + jj];
            ph1[e] = tileH[(ii0 + 8 + e) * 68 + jj];
            pl1[e] = tileL[(ii0 + 8 + e) * 68 + jj];
        }
        const size_t tb = (size_t)(bn + jj) * N + bm + ii0;
        *(u16x8*)&Th[tb]     = ph0;
        *(u16x8*)&Th[tb + 8] = ph1;
        *(u16x8*)&Tl[tb]     = pl0;
        *(u16x8*)&Tl[tb + 8] = pl1;
    }
}

// ---------------------------------------------------------------------------
// Scan split-bf16 MFMA GEMM: C[m,n] = sum_k A[m,k]*B[n,k], 3-term (bit-identical
// arithmetic to round-1 gemm_split). 128x128 tile, BK=32, double-buffered
// 2-phase prefetch (one barrier/k-step), XCD-swizzled blocks.
// ---------------------------------------------------------------------------
__global__ __launch_bounds__(256) void gemm_split(
    const u16* __restrict__ Ah, const u16* __restrict__ Al,
    const u16* __restrict__ Bh, const u16* __restrict__ Bl,
    float* __restrict__ Cf, u16* __restrict__ Ch, u16* __restrict__ Cl,
    int M, int N, int K)
{
    __shared__ u16 sAh[2][128][32];   // 16 KB each, 64 KB total
    __shared__ u16 sAl[2][128][32];
    __shared__ u16 sBh[2][128][32];
    __shared__ u16 sBl[2][128][32];

    int bx, by; swizzle_block(bx, by);
    const int bm = by * 128, bn = bx * 128;
    const int tid = threadIdx.x;
    const int l = tid & 63, w = tid >> 6;
    const int mbase = (w & 1) * 64, nbase = (w >> 1) * 64;
    const int lrow = l & 15, kq = (l >> 4) << 3;

    frag_cd acc[4][4];
    #pragma unroll
    for (int i = 0; i < 4; ++i)
        #pragma unroll
        for (int j = 0; j < 4; ++j)
            #pragma unroll
            for (int r = 0; r < 4; ++r) acc[i][j][r] = 0.0f;

    auto STAGE = [&](int buf, int k0) {
        #pragma unroll
        for (int half = 0; half < 2; ++half) {
            const int c   = tid + half * 256;
            const int row = c >> 2;
            const int ko  = (c & 3) << 3;
            const size_t ga = (size_t)(bm + row) * K + k0 + ko;
            const size_t gb = (size_t)(bn + row) * K + k0 + ko;
            gl_lds16(Ah + ga, &sAh[buf][0][0] + (c << 3));
            gl_lds16(Al + ga, &sAl[buf][0][0] + (c << 3));
            gl_lds16(Bh + gb, &sBh[buf][0][0] + (c << 3));
            gl_lds16(Bl + gb, &sBl[buf][0][0] + (c << 3));
        }
    };

    STAGE(0, 0);
    __syncthreads();
    const int NT = K >> 5;
    int cur = 0;
    for (int t = 0; t < NT; ++t) {
        if (t + 1 < NT) STAGE(cur ^ 1, (t + 1) << 5);
        frag_ab ah[4], al4[4], bh[4], bl4[4];
        #pragma unroll
        for (int i = 0; i < 4; ++i) {
            const int ro = mbase + 16 * i + lrow;
            ah[i]  = *(const frag_ab*)&sAh[cur][ro][kq];
            al4[i] = *(const frag_ab*)&sAl[cur][ro][kq];
        }
        #pragma unroll
        for (int j = 0; j < 4; ++j) {
            const int ro = nbase + 16 * j + lrow;
            bh[j]  = *(const frag_ab*)&sBh[cur][ro][kq];
            bl4[j] = *(const frag_ab*)&sBl[cur][ro][kq];
        }
        #pragma unroll
        for (int i = 0; i < 4; ++i)
            #pragma unroll
            for (int j = 0; j < 4; ++j) {
                acc[i][j] = __builtin_amdgcn_mfma_f32_16x16x32_bf16(
                    ah[i], bh[j], acc[i][j], 0, 0, 0);
                acc[i][j] = __builtin_amdgcn_mfma_f32_16x16x32_bf16(
                    al4[i], bh[j], acc[i][j], 0, 0, 0);
                acc[i][j] = __builtin_amdgcn_mfma_f32_16x16x32_bf16(
                    ah[i], bl4[j], acc[i][j], 0, 0, 0);
            }
        __syncthreads();
        cur ^= 1;
    }

    const int quad = l >> 4;
    #pragma unroll
    for (int i = 0; i < 4; ++i) {
        #pragma unroll
        for (int j = 0; j < 4; ++j) {
            const int coln = bn + nbase + 16 * j + lrow;
            #pragma unroll
            for (int r = 0; r < 4; ++r) {
                const int rowm = bm + mbase + 16 * i + quad * 4 + r;
                const size_t idx = (size_t)rowm * N + coln;
                float v = acc[i][j][r];
                if (Cf) Cf[idx] = v;
                if (Ch) { u16 hi, lo; split2(v, hi, lo); Ch[idx] = hi; Cl[idx] = lo; }
            }
        }
    }
}

// ---------------------------------------------------------------------------
// Plain bf16 MFMA GEMM (v, Y): C[m,n] = sum_k A[m,k]*B[n,k], A/B pre-converted
// u16 bf16 (pure global_load_lds staging). 128x128, BK=64 panel layout,
// double-buffered 2-phase, XCD swizzle.
// ---------------------------------------------------------------------------
__global__ __launch_bounds__(256) void gemm_bf16(
    const u16* __restrict__ Ab, const u16* __restrict__ Bb,
    void* __restrict__ Cdst, int cmode, const int* __restrict__ flag,
    int M, int N, int K)
{
    __shared__ u16 As[2][2][128][32];   // [dbuf][ks][row][k]  32 KB
    __shared__ u16 Bs[2][2][128][32];   // 64 KB total
    const int cbf = (cmode == 1) ? *flag : 0;

    int bx, by; swizzle_block(bx, by);
    const int bm = by * 128, bn = bx * 128;
    const int tid = threadIdx.x;
    const int l = tid & 63, w = tid >> 6;
    const int mbase = (w & 1) * 64, nbase = (w >> 1) * 64;
    const int lrow = l & 15, kq = (l >> 4) << 3;

    frag_cd acc[4][4];
    #pragma unroll
    for (int i = 0; i < 4; ++i)
        #pragma unroll
        for (int j = 0; j < 4; ++j)
            #pragma unroll
            for (int r = 0; r < 4; ++r) acc[i][j][r] = 0.0f;

    auto STAGE = [&](int buf, int k0) {
        #pragma unroll
        for (int half = 0; half < 4; ++half) {
            const int c   = tid + half * 256;
            const int ks  = c >> 9;
            const int row = (c >> 2) & 127;
            const int ko  = ks * 32 + (c & 3) * 8;
            const size_t ga = (size_t)(bm + row) * K + k0 + ko;
            const size_t gb = (size_t)(bn + row) * K + k0 + ko;
            gl_lds16(Ab + ga, &As[buf][0][0][0] + (c << 3));
            gl_lds16(Bb + gb, &Bs[buf][0][0][0] + (c << 3));
        }
    };

    STAGE(0, 0);
    __syncthreads();
    const int NT = K >> 6;
    int cur = 0;
    for (int t = 0; t < NT; ++t) {
        if (t + 1 < NT) STAGE(cur ^ 1, (t + 1) << 6);
        #pragma unroll
        for (int ks = 0; ks < 2; ++ks) {
            frag_ab a[4], b[4];
            #pragma unroll
            for (int i = 0; i < 4; ++i)
                a[i] = *(const frag_ab*)&As[cur][ks][mbase + 16 * i + lrow][kq];
            #pragma unroll
            for (int j = 0; j < 4; ++j)
                b[j] = *(const frag_ab*)&Bs[cur][ks][nbase + 16 * j + lrow][kq];
            #pragma unroll
            for (int i = 0; i < 4; ++i)
                #pragma unroll
                for (int j = 0; j < 4; ++j)
                    acc[i][j] = __builtin_amdgcn_mfma_f32_16x16x32_bf16(
                        a[i], b[j], acc[i][j], 0, 0, 0);
        }
        __syncthreads();
        cur ^= 1;
    }

    const int quad = l >> 4;
    #pragma unroll
    for (int i = 0; i < 4; ++i) {
        #pragma unroll
        for (int j = 0; j < 4; ++j) {
            const int coln = bn + nbase + 16 * j + lrow;
            #pragma unroll
            for (int r = 0; r < 4; ++r) {
                const int rowm = bm + mbase + 16 * i + quad * 4 + r;
                const size_t idx = (size_t)rowm * N + coln;
                float v = acc[i][j][r];
                if (cbf) ((u16*)Cdst)[idx] = f2bf(v);
                else     ((float*)Cdst)[idx] = v;
            }
        }
    }
}

// ---------------------------------------------------------------------------
// fused conv_split: x -> (Xh,Xl), Wup -> (Wh,Wl). Ranges block-aligned
// (NX/4 = 8192 blocks, NC/4 = 1024 blocks) so no intra-block divergence.
// ---------------------------------------------------------------------------
__global__ __launch_bounds__(256) void prep_q0_k(
    const void* __restrict__ x, const void* __restrict__ wup,
    u16* __restrict__ Xh, u16* __restrict__ Xl,
    u16* __restrict__ Wh, u16* __restrict__ Wl,
    const int* __restrict__ flag)
{
    int i = blockIdx.x * 256 + threadIdx.x;
    const int n4x = (NTOK * C_) / 4;
    const void* src; u16 *H, *L; int idx;
    if (i < n4x) { src = x;   H = Xh; L = Xl; idx = i; }
    else         { src = wup; H = Wh; L = Wl; idx = i - n4x; }
    float f[4];
    if (*flag) {
        u16x4 u = ((const u16x4*)src)[idx];
        f[0] = bf2f(u[0]); f[1] = bf2f(u[1]); f[2] = bf2f(u[2]); f[3] = bf2f(u[3]);
    } else {
        float4 v = ((const float4*)src)[idx];
        f[0] = v.x; f[1] = v.y; f[2] = v.z; f[3] = v.w;
    }
    u16x4 h, lo;
    #pragma unroll
    for (int r = 0; r < 4; ++r) { u16 a, b; split2(f[r], a, b); h[r] = a; lo[r] = b; }
    ((u16x4*)H)[idx] = h; ((u16x4*)L)[idx] = lo;
}

// fused bf16 pre-convert: x -> xb, Wv -> wvb, Wproj -> wpb (block-aligned ranges)
__global__ __launch_bounds__(256) void prep_vy_k(
    const void* __restrict__ x, const void* __restrict__ wv,
    const void* __restrict__ wp,
    u16* __restrict__ xb, u16* __restrict__ wvb, u16* __restrict__ wpb,
    const int* __restrict__ flag)
{
    int i = blockIdx.x * 256 + threadIdx.x;
    const int n4x = (NTOK * C_) / 4;
    const int n4c = (C_ * C_) / 4;
    const void* src; u16* out; int idx;
    if (i < n4x)            { src = x;  out = xb;  idx = i; }
    else if (i < n4x + n4c) { src = wv; out = wvb; idx = i - n4x; }
    else                    { src = wp; out = wpb; idx = i - n4x - n4c; }
    u16x4 o;
    if (*flag) {
        o = ((const u16x4*)src)[idx];
    } else {
        float4 v = ((const float4*)src)[idx];
        o[0] = f2bf(v.x); o[1] = f2bf(v.y); o[2] = f2bf(v.z); o[3] = f2bf(v.w);
    }
    ((u16x4*)out)[idx] = o;
}

// fused qv + q-store: qvout = bf16(recon(q)*v); d_out[NX + i] = recon(q)
// (reads q-split once for both jobs; bit-identical to qvb_k + store_split_k)
__global__ __launch_bounds__(256) void qv_store_k(
    const u16* __restrict__ qh, const u16* __restrict__ ql,
    const float* __restrict__ V, u16* __restrict__ qvout,
    void* __restrict__ out, const int* __restrict__ flag)
{
    int i = blockIdx.x * 256 + threadIdx.x;
    u16x4 h = ((const u16x4*)qh)[i], lo = ((const u16x4*)ql)[i];
    float4 v = ((const float4*)V)[i];
    float r0 = bf2f(h[0]) + bf2f(lo[0]);
    float r1 = bf2f(h[1]) + bf2f(lo[1]);
    float r2 = bf2f(h[2]) + bf2f(lo[2]);
    float r3 = bf2f(h[3]) + bf2f(lo[3]);
    u16x4 o;
    o[0] = f2bf(r0 * v.x); o[1] = f2bf(r1 * v.y);
    o[2] = f2bf(r2 * v.z); o[3] = f2bf(r3 * v.w);
    ((u16x4*)qvout)[i] = o;
    const size_t off4 = (size_t)(NTOK * C_) / 4;
    if (*flag) {
        u16x4 q; q[0] = f2bf(r0); q[1] = f2bf(r1); q[2] = f2bf(r2); q[3] = f2bf(r3);
        ((u16x4*)out)[off4 + i] = q;
    } else {
        float4 f; f.x = r0; f.y = r1; f.z = r2; f.w = r3;
        ((float4*)out)[off4 + i] = f;
    }
}

// idW[j] = sum_i identf[i] * W[i,j] — 64 blocks x 16 rows, atomic combine
__global__ __launch_bounds__(256) void idw2_k(
    const float* __restrict__ identf, const float* __restrict__ W,
    float* __restrict__ idW)
{
    const int b = blockIdx.x;
    const int j = threadIdx.x;
    float a0 = 0, a1 = 0, a2 = 0, a3 = 0;
    #pragma unroll
    for (int ii = 0; ii < 16; ++ii) {
        const int i = b * 16 + ii;
        const float s = identf[i];
        const float* row = W + (size_t)i * C_;
        a0 += s * row[j];
        a1 += s * row[j + 256];
        a2 += s * row[j + 512];
        a3 += s * row[j + 768];
    }
    atomicAdd(idW + j, a0);       atomicAdd(idW + j + 256, a1);
    atomicAdd(idW + j + 512, a2); atomicAdd(idW + j + 768, a3);
}

// ---------------------------------------------------------------------------
// scan combine, 2-barrier version (proven round 8). Thread t owns elements
// [4t,4t+4); wave a owns SDPA lane a; k/v staged in LDS; softmax recomputed
// per-thread from shared red[16]; rms broadcast via shfl.
// ---------------------------------------------------------------------------
__global__ __launch_bounds__(256) void combine4_k(
    const u16* __restrict__ curh, const u16* __restrict__ curl,
    const float* __restrict__ xW,
    const float* __restrict__ idW, const float* __restrict__ identf,
    u16* __restrict__ nxth, u16* __restrict__ nxtl, int d)
{
    const int token = blockIdx.x;
    const int t = token & (T_ - 1);
    const int tid = threadIdx.x;
    const bool hl = (t >= d);
    const size_t rbase = (size_t)token * C_;
    const size_t lbase = hl ? (size_t)(token - d) * C_ : 0;
    const float* leftW  = hl ? xW + lbase : idW;
    const float* rightW = xW + rbase;

    const int e0   = tid << 2;          // element base (4 consecutive)
    const int a    = tid >> 6;          // SDPA lane owned by this wave
    const int dd   = (tid & 63) << 2;   // within-lane element offset
    const int lane = tid & 63;

    float q4[4], k4[4], v4[4];
    {
        u16x4 kh = *(const u16x4*)&curh[rbase + e0];
        u16x4 kl = *(const u16x4*)&curl[rbase + e0];
        #pragma unroll
        for (int e = 0; e < 4; ++e) k4[e] = bf2f(kh[e]) + bf2f(kl[e]);
        if (hl) {
            u16x4 qh = *(const u16x4*)&curh[lbase + e0];
            u16x4 ql = *(const u16x4*)&curl[lbase + e0];
            #pragma unroll
            for (int e = 0; e < 4; ++e) q4[e] = bf2f(qh[e]) + bf2f(ql[e]);
        } else {
            float4 iv = *(const float4*)&identf[e0];
            q4[0] = iv.x; q4[1] = iv.y; q4[2] = iv.z; q4[3] = iv.w;
        }
        float4 lw = *(const float4*)&leftW[e0];
        float4 rw = *(const float4*)&rightW[e0];
        v4[0] = lw.x + rw.x; v4[1] = lw.y + rw.y;
        v4[2] = lw.z + rw.z; v4[3] = lw.w + rw.w;
    }

    __shared__ float ks[4][256];
    __shared__ float vs[4][256];
    __shared__ float red[16];
    {
        float4 kv = { k4[0], k4[1], k4[2], k4[3] };
        float4 vv = { v4[0], v4[1], v4[2], v4[3] };
        *(float4*)&ks[a][dd] = kv;
        *(float4*)&vs[a][dd] = vv;
    }
    __syncthreads();

    // wave a computes scores S[a][b] = (1/16) * sum_d q[a][d] k[b][d]
    #pragma unroll
    for (int b = 0; b < 4; ++b) {
        float4 kk = *(const float4*)&ks[b][dd];
        float pp = q4[0] * kk.x + q4[1] * kk.y + q4[2] * kk.z + q4[3] * kk.w;
        float sb = wave_reduce(pp);
        if (lane == 0) red[a * 4 + b] = sb * 0.0625f;
    }
    __syncthreads();

    // per-thread softmax of row a
    float s0 = red[a * 4 + 0], s1 = red[a * 4 + 1];
    float s2 = red[a * 4 + 2], s3 = red[a * 4 + 3];
    float mx = fmaxf(fmaxf(s0, s1), fmaxf(s2, s3));
    float x0 = __expf(s0 - mx), x1 = __expf(s1 - mx);
    float x2 = __expf(s2 - mx), x3 = __expf(s3 - mx);
    float inv = 1.0f / (x0 + x1 + x2 + x3);
    const float a0 = x0 * inv, a1 = x1 * inv, a2 = x2 * inv, a3 = x3 * inv;

    // z[a][d] = sum_b att[a][b] v[b][d]
    float4 v0 = *(const float4*)&vs[0][dd];
    float4 v1 = *(const float4*)&vs[1][dd];
    float4 v2 = *(const float4*)&vs[2][dd];
    float4 v3 = *(const float4*)&vs[3][dd];
    float z4[4];
    z4[0] = a0 * v0.x + a1 * v1.x + a2 * v2.x + a3 * v3.x;
    z4[1] = a0 * v0.y + a1 * v1.y + a2 * v2.y + a3 * v3.y;
    z4[2] = a0 * v0.z + a1 * v1.z + a2 * v2.z + a3 * v3.z;
    z4[3] = a0 * v0.w + a1 * v1.w + a2 * v2.w + a3 * v3.w;

    // rms over lane a's 256 elements; lane-0 total broadcast via shfl
    float ssp = z4[0] * z4[0] + z4[1] * z4[1] + z4[2] * z4[2] + z4[3] * z4[3];
    float ss = wave_reduce(ssp);
    ss = __shfl(ss, 0, 64);
    const float rs = rsqrtf(ss * (1.0f / HD) + 1e-8f) * (1.0f / (float)(a + 1));

    u16x4 oh, ol;
    #pragma unroll
    for (int e = 0; e < 4; ++e) {
        float out = q4[e] + z4[e] * rs;
        u16 hi, lo; split2(out, hi, lo);
        oh[e] = hi; ol[e] = lo;
    }
    *(u16x4*)&nxth[rbase + e0] = oh;
    *(u16x4*)&nxtl[rbase + e0] = ol;
}

// ---------------------------------------------------------------------------
extern "C" void kernel_launch(void* const* d_in, const int* in_sizes, int n_in,
                              void* d_out, int out_size, void* d_ws, size_t ws_size,
                              hipStream_t stream)
{
    const void* x     = d_in[0];
    const void* Wup   = d_in[1];
    const void* Wv    = d_in[2];
    const void* Wproj = d_in[3];
    const void* ident = d_in[4];
    const void* Wraw  = d_in[5];

    float* ws = (float*)d_ws;
    int*   flagp  = (int*)ws;                    // meta[0]
    float* sumsqp = ws + 1;                      // meta[1]
    float* W0     = ws + 256;                    // 1M f32 (scaled W_raw)
    float* W1     = W0 + (1 << 20);              // 1M f32 (final polar X)
    float* identf = W1 + (1 << 20);              // 1024
    float* idW    = identf + 1024;               // 1024
    float* F1     = idW + 1024;                  // 8M f32 (xW / v scratch)
    u16*   WTh    = (u16*)(F1 + (size_t)NTOK * C_);  // W^T split hi (1M u16)
    u16*   WTl    = WTh + (1 << 20);
    u16*   WUh    = WTl + (1 << 20);             // Wup split / NS G / WVb
    u16*   WUl    = WUh + (1 << 20);             //            …       / WPb
    u16*   Q0h    = WUl + (1 << 20);             // q split dbuf A (8M u16 ea)
    u16*   Q0l    = Q0h + (size_t)NTOK * C_;
    u16*   Q1h    = Q0l + (size_t)NTOK * C_;     // q split dbuf B
    u16*   Q1l    = Q1h + (size_t)NTOK * C_;

    const int NC = C_ * C_;          // 1M
    const int NX = NTOK * C_;        // 8M

    // ---- dtype detection ----
    detect_k<<<1, 256, 0, stream>>>((const u16*)Wup, flagp);

    // ---- polar(W_raw): quintic-ramp Newton-Schulz, split-bf16 MFMA ----
    hipMemsetAsync(sumsqp, 0, sizeof(float), stream);
    conv_sumsq_k<<<NC / 256, 256, 0, stream>>>(Wraw, W0, flagp, sumsqp);

    // NS split scratch aliases (Q0 region dead until q0; WU* dead until q0)
    u16* Gh = WUh;  u16* Gl = WUl;
    u16* Xh2[2] = { Q0h,             Q0h + 2 * (1 << 20) };
    u16* Xl2[2] = { Q0h + (1 << 20), Q0h + 3 * (1 << 20) };
    u16* Hh = Q0h + 4 * (1 << 20);
    u16* Hl = Q0h + 5 * (1 << 20);

    scale_split_k<<<NC / 256, 256, 0, stream>>>(W0, sumsqp, Xh2[0], Xl2[0]);
    transpose_split_k<<<dim3(32, 32), 256, 0, stream>>>(W0, WTh, WTl);

    int cur = 0;
    const dim3 gNS(16, 16);
    // quintic ramp: p(x) = aQ x + bQ x^3 + cQ x^5 (no positive roots; band
    // [0,1.202] invariant; growth 3.44x/iter lifts sigma_min >= 3e-6 in 10)
    const float aQ = 3.4445f, bQ = -4.7750f, cQ = 2.0315f;
    for (int it = 0; it < 10; ++it) {
        // G = X^T X
        gemm_split64<<<gNS, 256, 0, stream>>>(WTh, WTl, WTh, WTl,
                                              nullptr, Gh, Gl,
                                              nullptr, nullptr, 0.0f,
                                              nullptr, nullptr, 0.0f, 1.0f,
                                              C_, C_, C_, nullptr, nullptr);
        // H = X G  (G symmetric -> B = G row-major); split output only
        gemm_split64<<<gNS, 256, 0, stream>>>(Xh2[cur], Xl2[cur], Gh, Gl,
                                              nullptr, Hh, Hl,
                                              nullptr, nullptr, 0.0f,
                                              nullptr, nullptr, 0.0f, 1.0f,
                                              C_, C_, C_, nullptr, nullptr);
        // Y = cQ*(H G) + aQ*recon(X) + bQ*recon(H) -> row split + fused W^T
        gemm_split64<<<gNS, 256, 0, stream>>>(Hh, Hl, Gh, Gl,
                                              nullptr, Xh2[cur ^ 1], Xl2[cur ^ 1],
                                              Xh2[cur], Xl2[cur], aQ,
                                              Hh, Hl, bQ, cQ,
                                              C_, C_, C_, WTh, WTl);
        cur ^= 1;
    }
    // cubic polish: x -> 1.5x - 0.5x^3 (4 iters: band-min 0.68 -> 1 - 2e-6).
    // Final iter writes f32 X (for idw2) and skips the dead row-split.
    for (int it = 0; it < 4; ++it) {
        const bool last = (it == 3);
        gemm_split64<<<gNS, 256, 0, stream>>>(WTh, WTl, WTh, WTl,
                                              nullptr, Gh, Gl,
                                              nullptr, nullptr, 0.0f,
                                              nullptr, nullptr, 0.0f, 1.0f,
                                              C_, C_, C_, nullptr, nullptr);
        gemm_split64<<<gNS, 256, 0, stream>>>(Xh2[cur], Xl2[cur], Gh, Gl,
                                              last ? W1 : nullptr,
                                              last ? nullptr : Xh2[cur ^ 1],
                                              last ? nullptr : Xl2[cur ^ 1],
                                              Xh2[cur], Xl2[cur], 1.5f,
                                              nullptr, nullptr, 0.0f, -0.5f,
                                              C_, C_, C_, WTh, WTl);
        cur ^= 1;
    }
    // W1 = polar(W_raw) f32 ; WTh/WTl = W^T split, ready for the scan

    ident_init_k<<<4, 256, 0, stream>>>(ident, identf, idW, flagp);
    idw2_k<<<64, 256, 0, stream>>>(identf, W1, idW);

    const dim3 g128(C_ / 128, NTOK / 128);   // (8, 64)

    // ---- q0 = x @ Wup^T  (split-bf16 MFMA) ----
    prep_q0_k<<<(NX + NC) / 1024, 256, 0, stream>>>(x, Wup, Q1h, Q1l,
                                                    WUh, WUl, flagp);
    gemm_split<<<g128, 256, 0, stream>>>(Q1h, Q1l, WUh, WUl,
                                         nullptr, Q0h, Q0l, NTOK, C_, C_);

    // ---- scan: 11 Hillis-Steele steps, q carried as split bf16 pairs ----
    u16 *ch = Q0h, *cl = Q0l, *nh = Q1h, *nl = Q1l;
    for (int d = 1; d < T_; d <<= 1) {
        gemm_split<<<g128, 256, 0, stream>>>(ch, cl, WTh, WTl,
                                             F1, nullptr, nullptr, NTOK, C_, C_);
        combine4_k<<<NTOK, 256, 0, stream>>>(ch, cl, F1, idW, identf, nh, nl, d);
        u16* t1 = ch; ch = nh; nh = t1;
        u16* t2 = cl; cl = nl; nl = t2;
    }
    // 11 steps (odd) -> ch/cl = Q1h/Q1l hold q; Q0*, F1, WU* free

    // ---- pre-convert x / weights to bf16 (one fused dispatch) ----
    prep_vy_k<<<(NX + 2 * NC) / 1024, 256, 0, stream>>>(x, Wv, Wproj,
                                                        Q0h, WUh, WUl, flagp);

    // ---- v = x @ Wv^T  (pure bf16 MFMA) -> F1 f32 ----
    gemm_bf16<<<g128, 256, 0, stream>>>(Q0h, WUh, F1, 0, flagp, NTOK, C_, C_);

    // ---- qv = q.*v (A for Y GEMM) + second output q -> d_out[NX:2NX] ----
    qv_store_k<<<NX / 1024, 256, 0, stream>>>(ch, cl, F1, Q0l, d_out, flagp);

    // ---- Y = (q .* v) @ Wproj^T -> d_out[0:NX] ----
    gemm_bf16<<<g128, 256, 0, stream>>>(Q0l, WUl, d_out, 1, flagp, NTOK, C_, C_);
}

// Round 10
// 1803.925 us; speedup vs baseline: 2.8156x; 1.0027x over previous
//
#include <hip/hip_runtime.h>
#include <hip/hip_bf16.h>

#define DEVINL __device__ __forceinline__

constexpr int B_   = 4;
constexpr int T_   = 2048;
constexpr int C_   = 1024;
constexpr int NTOK = B_ * T_;      // 8192
constexpr int HD   = 256;          // C_/4

typedef unsigned short u16;
typedef __attribute__((ext_vector_type(8))) short  frag_ab;  // 8 bf16 (4 VGPRs)
typedef __attribute__((ext_vector_type(4))) float  frag_cd;  // 4 fp32
typedef __attribute__((ext_vector_type(8))) u16    u16x8;
typedef __attribute__((ext_vector_type(4))) u16    u16x4;

DEVINL float bf2f(u16 u) {
    unsigned int x = ((unsigned int)u) << 16;
    return __uint_as_float(x);
}
DEVINL u16 f2bf(float f) {
    unsigned int x = __float_as_uint(f);
    unsigned int r = (x + 0x7fffu + ((x >> 16) & 1u)) >> 16;
    return (u16)r;
}
// f == bf2f(h) + bf2f(l) + O(2^-18 |f|); residual subtraction exact (Sterbenz).
DEVINL void split2(float f, u16& h, u16& l) {
    h = f2bf(f);
    l = f2bf(f - bf2f(h));
}
DEVINL float wave_reduce(float v) {
    #pragma unroll
    for (int off = 32; off > 0; off >>= 1) v += __shfl_down(v, off, 64);
    return v;
}
DEVINL void gl_lds16(const void* g, void* l) {
    __builtin_amdgcn_global_load_lds(
        (const __attribute__((address_space(1))) unsigned int*)g,
        (__attribute__((address_space(3))) unsigned int*)l, 16, 0, 0);
}

// XCD-aware remap for (8,64) grids: hw%8 = XCD (round-robin); give each XCD
// 8 M-panels x 8 N-cols so its A footprint (4MB split / 2MB bf16) is L2-resident
// and each A panel is fetched by exactly one XCD (was 8x over-fetch).
DEVINL void swizzle_block(int& bx, int& by) {
    const int hw = (int)(blockIdx.x + gridDim.x * blockIdx.y);
    if (gridDim.x == 8 && gridDim.y == 64) {
        const int xcd = hw & 7, idx = hw >> 3;
        by = xcd * 8 + (idx & 7);
        bx = idx >> 3;
    } else { bx = blockIdx.x; by = blockIdx.y; }
}

// ---------------------------------------------------------------------------
// dtype auto-detect (flag: 1 = bf16 inputs, 0 = f32 inputs)
// ---------------------------------------------------------------------------
__global__ __launch_bounds__(256) void detect_k(const u16* __restrict__ w,
                                                int* __restrict__ flag)
{
    int tid = threadIdx.x;
    int cnt = 0;
    for (int i = tid; i < 4096; i += 256) {
        u16 u = w[2 * i];
        int e = (u >> 7) & 0xFF;
        if (u == 0 || (e >= 96 && e <= 134)) cnt++;
    }
    __shared__ int sh[256];
    sh[tid] = cnt; __syncthreads();
    for (int s = 128; s > 0; s >>= 1) {
        if (tid < s) sh[tid] += sh[tid + s];
        __syncthreads();
    }
    if (tid == 0) *flag = (sh[0] > 2048) ? 1 : 0;
}

// Wraw conversion + Frobenius sumsq in one pass (bit-identical to conv+sumsq)
__global__ __launch_bounds__(256) void conv_sumsq_k(const void* __restrict__ src,
                                                    float* __restrict__ dst,
                                                    const int* __restrict__ flag,
                                                    float* __restrict__ sumsq)
{
    int i = blockIdx.x * 256 + threadIdx.x;
    float f = (*flag) ? bf2f(((const u16*)src)[i]) : ((const float*)src)[i];
    dst[i] = f;
    float p = wave_reduce(f * f);
    __shared__ float r[4];
    int lane = threadIdx.x & 63, w = threadIdx.x >> 6;
    if (lane == 0) r[w] = p;
    __syncthreads();
    if (threadIdx.x == 0) atomicAdd(sumsq, r[0] + r[1] + r[2] + r[3]);
}

// scale X in place + write row-major split (bit-identical to scale+split)
__global__ __launch_bounds__(256) void scale_split_k(float* __restrict__ X,
                                                     const float* __restrict__ sumsq,
                                                     u16* __restrict__ H,
                                                     u16* __restrict__ L)
{
    int i = blockIdx.x * 256 + threadIdx.x;
    float F = sqrtf(*sumsq);
    float s = 16.0f / (1.1f * F);   // Gaussian: sigma_max ~= F/16; 10% margin
    float f = X[i] * s;
    X[i] = f;
    u16 hi, lo; split2(f, hi, lo);
    H[i] = hi; L[i] = lo;
}

// identf conversion + idW zeroing (grid 4 x 256)
__global__ __launch_bounds__(256) void ident_init_k(const void* __restrict__ ident,
                                                    float* __restrict__ identf,
                                                    float* __restrict__ idW,
                                                    const int* __restrict__ flag)
{
    int j = blockIdx.x * 256 + threadIdx.x;
    identf[j] = (*flag) ? bf2f(((const u16*)ident)[j]) : ((const float*)ident)[j];
    idW[j] = 0.0f;
}

// Th/Tl[n*C_+k] = split(W[k*C_+n])  — LDS 32x32 tile transpose (initial only)
__global__ __launch_bounds__(256) void transpose_split_k(
    const float* __restrict__ W, u16* __restrict__ Th, u16* __restrict__ Tl)
{
    __shared__ float tile[32][33];
    const int k0 = blockIdx.y * 32;
    const int n0 = blockIdx.x * 32;
    const int tx = threadIdx.x & 31, ty = threadIdx.x >> 5;   // 32 x 8
    #pragma unroll
    for (int r = 0; r < 32; r += 8)
        tile[ty + r][tx] = W[(size_t)(k0 + ty + r) * C_ + n0 + tx];
    __syncthreads();
    #pragma unroll
    for (int r = 0; r < 32; r += 8) {
        float f = tile[tx][ty + r];                 // = W[k0+tx][n0+ty+r]
        size_t idx = (size_t)(n0 + ty + r) * C_ + k0 + tx;
        u16 hi, lo; split2(f, hi, lo);
        Th[idx] = hi; Tl[idx] = lo;
    }
}

// ---------------------------------------------------------------------------
// NS split-bf16 MFMA GEMM:
//   C[m,n] = beta*sum_k A[m,k]*B[n,k] + alpha*recon(D) + alpha2*recon(D2)
// where D/D2 are (hi,lo) split pairs (recon err ~2^-18 — consistent with the
// 4-term MFMA precision). 64x64 tile, BK=128, 4-term (hh+lh+hl+ll),
// double-buffered 2-phase prefetch, 128 KB LDS. Optional epilogue outputs:
// f32 (Cf, final iter only), row-major split (Ch/Cl), LDS-transposed split
// (Th/Tl) (fold proven rounds 4-9).
// ---------------------------------------------------------------------------
__global__ __launch_bounds__(256) void gemm_split64(
    const u16* __restrict__ Ah, const u16* __restrict__ Al,
    const u16* __restrict__ Bh, const u16* __restrict__ Bl,
    float* __restrict__ Cf, u16* __restrict__ Ch, u16* __restrict__ Cl,
    const u16* __restrict__ Dh, const u16* __restrict__ Dl, float alpha,
    const u16* __restrict__ D2h, const u16* __restrict__ D2l, float alpha2,
    float beta, int M, int N, int K,
    u16* __restrict__ Th, u16* __restrict__ Tl)
{
    __shared__ u16 sAh[2][4][64][32];   // [dbuf][ks][row][k]  32 KB
    __shared__ u16 sAl[2][4][64][32];
    __shared__ u16 sBh[2][4][64][32];
    __shared__ u16 sBl[2][4][64][32];   // total 128 KB (1 block/CU)

    const int bm = blockIdx.y * 64, bn = blockIdx.x * 64;
    const int tid = threadIdx.x;
    const int l = tid & 63, w = tid >> 6;
    const int mbase = (w & 1) * 32, nbase = (w >> 1) * 32;
    const int lrow = l & 15, kq = (l >> 4) << 3;

    frag_cd acc[2][2];
    #pragma unroll
    for (int i = 0; i < 2; ++i)
        #pragma unroll
        for (int j = 0; j < 2; ++j)
            #pragma unroll
            for (int r = 0; r < 4; ++r) acc[i][j][r] = 0.0f;

    auto STAGE = [&](int buf, int k0) {
        #pragma unroll
        for (int half = 0; half < 4; ++half) {
            const int c   = tid + half * 256;
            const int ks  = c >> 8;
            const int row = (c >> 2) & 63;
            const int ko  = ks * 32 + (c & 3) * 8;
            const size_t ga = (size_t)(bm + row) * K + k0 + ko;
            const size_t gb = (size_t)(bn + row) * K + k0 + ko;
            gl_lds16(Ah + ga, &sAh[0][0][0][0] + buf * 8192 + (c << 3));
            gl_lds16(Al + ga, &sAl[0][0][0][0] + buf * 8192 + (c << 3));
            gl_lds16(Bh + gb, &sBh[0][0][0][0] + buf * 8192 + (c << 3));
            gl_lds16(Bl + gb, &sBl[0][0][0][0] + buf * 8192 + (c << 3));
        }
    };

    STAGE(0, 0);
    __syncthreads();
    const int NT = K >> 7;   // 8
    int cur = 0;
    for (int t = 0; t < NT; ++t) {
        if (t + 1 < NT) STAGE(cur ^ 1, (t + 1) << 7);
        #pragma unroll
        for (int ks = 0; ks < 4; ++ks) {
            frag_ab ah[2], al2[2], bh[2], bl2[2];
            #pragma unroll
            for (int i = 0; i < 2; ++i) {
                const int ro = mbase + 16 * i + lrow;
                ah[i]  = *(const frag_ab*)&sAh[cur][ks][ro][kq];
                al2[i] = *(const frag_ab*)&sAl[cur][ks][ro][kq];
            }
            #pragma unroll
            for (int j = 0; j < 2; ++j) {
                const int ro = nbase + 16 * j + lrow;
                bh[j]  = *(const frag_ab*)&sBh[cur][ks][ro][kq];
                bl2[j] = *(const frag_ab*)&sBl[cur][ks][ro][kq];
            }
            #pragma unroll
            for (int i = 0; i < 2; ++i)
                #pragma unroll
                for (int j = 0; j < 2; ++j) {
                    acc[i][j] = __builtin_amdgcn_mfma_f32_16x16x32_bf16(
                        ah[i], bh[j], acc[i][j], 0, 0, 0);
                    acc[i][j] = __builtin_amdgcn_mfma_f32_16x16x32_bf16(
                        al2[i], bh[j], acc[i][j], 0, 0, 0);
                    acc[i][j] = __builtin_amdgcn_mfma_f32_16x16x32_bf16(
                        ah[i], bl2[j], acc[i][j], 0, 0, 0);
                    acc[i][j] = __builtin_amdgcn_mfma_f32_16x16x32_bf16(
                        al2[i], bl2[j], acc[i][j], 0, 0, 0);
                }
        }
        __syncthreads();
        cur ^= 1;
    }

    // epilogue (after final K-loop barrier: staging LDS is dead, reusable)
    const int quad = l >> 4;
    u16* tileH = &sAh[0][0][0][0];   // 64*68 u16 = 8.5 KB, fits in sAh
    u16* tileL = &sAl[0][0][0][0];
    #pragma unroll
    for (int i = 0; i < 2; ++i) {
        #pragma unroll
        for (int j = 0; j < 2; ++j) {
            const int coln = bn + nbase + 16 * j + lrow;
            #pragma unroll
            for (int r = 0; r < 4; ++r) {
                const int rowm = bm + mbase + 16 * i + quad * 4 + r;
                const size_t idx = (size_t)rowm * N + coln;
                float v = beta * acc[i][j][r];
                if (Dh)  v += alpha  * (bf2f(Dh[idx])  + bf2f(Dl[idx]));
                if (D2h) v += alpha2 * (bf2f(D2h[idx]) + bf2f(D2l[idx]));
                if (Cf) Cf[idx] = v;
                u16 hi, lo; split2(v, hi, lo);
                if (Ch) { Ch[idx] = hi; Cl[idx] = lo; }
                if (Th) {
                    const int rl = mbase + 16 * i + quad * 4 + r;   // local row
                    const int cl = nbase + 16 * j + lrow;           // local col
                    tileH[rl * 68 + cl] = hi;
                    tileL[rl * 68 + cl] = lo;
                }
            }
        }
    }
    if (Th) {
        __syncthreads();
        // transposed coalesced write: T[(bn+jj)*N + bm+ii] = tile[ii][jj]
        const int jj  = tid >> 2;          // 0..63
        const int ii0 = (tid & 3) << 4;    // 0,16,32,48
        u16x8 ph0, ph1, pl0, pl1;
        #pragma unroll
        for (int e = 0; e < 8; ++e) {
            ph0[e] = tileH[(ii0 + e) * 68 + jj];
            pl0[e] = tileL[(ii0 + e) * 68 + jj];
            ph1[e] = tileH[(ii0 + 8 + e) * 68 + jj];
            pl1[e] = tileL[(ii0 + 8 + e) * 68 + jj];
        }
        const size_t tb = (size_t)(bn + jj) * N + bm + ii0;
        *(u16x8*)&Th[tb]     = ph0;
        *(u16x8*)&Th[tb + 8] = ph1;
        *(u16x8*)&Tl[tb]     = pl0;
        *(u16x8*)&Tl[tb + 8] = pl1;
    }
}

// ---------------------------------------------------------------------------
// Scan split-bf16 MFMA GEMM: C[m,n] = sum_k A[m,k]*B[n,k], 3-term (bit-identical
// arithmetic to round-1 gemm_split). 128x128 tile, BK=32, double-buffered
// 2-phase prefetch (one barrier/k-step), XCD-swizzled blocks.
// ---------------------------------------------------------------------------
__global__ __launch_bounds__(256) void gemm_split(
    const u16* __restrict__ Ah, const u16* __restrict__ Al,
    const u16* __restrict__ Bh, const u16* __restrict__ Bl,
    float* __restrict__ Cf, u16* __restrict__ Ch, u16* __restrict__ Cl,
    int M, int N, int K)
{
    __shared__ u16 sAh[2][128][32];   // 16 KB each, 64 KB total
    __shared__ u16 sAl[2][128][32];
    __shared__ u16 sBh[2][128][32];
    __shared__ u16 sBl[2][128][32];

    int bx, by; swizzle_block(bx, by);
    const int bm = by * 128, bn = bx * 128;
    const int tid = threadIdx.x;
    const int l = tid & 63, w = tid >> 6;
    const int mbase = (w & 1) * 64, nbase = (w >> 1) * 64;
    const int lrow = l & 15, kq = (l >> 4) << 3;

    frag_cd acc[4][4];
    #pragma unroll
    for (int i = 0; i < 4; ++i)
        #pragma unroll
        for (int j = 0; j < 4; ++j)
            #pragma unroll
            for (int r = 0; r < 4; ++r) acc[i][j][r] = 0.0f;

    auto STAGE = [&](int buf, int k0) {
        #pragma unroll
        for (int half = 0; half < 2; ++half) {
            const int c   = tid + half * 256;
            const int row = c >> 2;
            const int ko  = (c & 3) << 3;
            const size_t ga = (size_t)(bm + row) * K + k0 + ko;
            const size_t gb = (size_t)(bn + row) * K + k0 + ko;
            gl_lds16(Ah + ga, &sAh[buf][0][0] + (c << 3));
            gl_lds16(Al + ga, &sAl[buf][0][0] + (c << 3));
            gl_lds16(Bh + gb, &sBh[buf][0][0] + (c << 3));
            gl_lds16(Bl + gb, &sBl[buf][0][0] + (c << 3));
        }
    };

    STAGE(0, 0);
    __syncthreads();
    const int NT = K >> 5;
    int cur = 0;
    for (int t = 0; t < NT; ++t) {
        if (t + 1 < NT) STAGE(cur ^ 1, (t + 1) << 5);
        frag_ab ah[4], al4[4], bh[4], bl4[4];
        #pragma unroll
        for (int i = 0; i < 4; ++i) {
            const int ro = mbase + 16 * i + lrow;
            ah[i]  = *(const frag_ab*)&sAh[cur][ro][kq];
            al4[i] = *(const frag_ab*)&sAl[cur][ro][kq];
        }
        #pragma unroll
        for (int j = 0; j < 4; ++j) {
            const int ro = nbase + 16 * j + lrow;
            bh[j]  = *(const frag_ab*)&sBh[cur][ro][kq];
            bl4[j] = *(const frag_ab*)&sBl[cur][ro][kq];
        }
        #pragma unroll
        for (int i = 0; i < 4; ++i)
            #pragma unroll
            for (int j = 0; j < 4; ++j) {
                acc[i][j] = __builtin_amdgcn_mfma_f32_16x16x32_bf16(
                    ah[i], bh[j], acc[i][j], 0, 0, 0);
                acc[i][j] = __builtin_amdgcn_mfma_f32_16x16x32_bf16(
                    al4[i], bh[j], acc[i][j], 0, 0, 0);
                acc[i][j] = __builtin_amdgcn_mfma_f32_16x16x32_bf16(
                    ah[i], bl4[j], acc[i][j], 0, 0, 0);
            }
        __syncthreads();
        cur ^= 1;
    }

    const int quad = l >> 4;
    #pragma unroll
    for (int i = 0; i < 4; ++i) {
        #pragma unroll
        for (int j = 0; j < 4; ++j) {
            const int coln = bn + nbase + 16 * j + lrow;
            #pragma unroll
            for (int r = 0; r < 4; ++r) {
                const int rowm = bm + mbase + 16 * i + quad * 4 + r;
                const size_t idx = (size_t)rowm * N + coln;
                float v = acc[i][j][r];
                if (Cf) Cf[idx] = v;
                if (Ch) { u16 hi, lo; split2(v, hi, lo); Ch[idx] = hi; Cl[idx] = lo; }
            }
        }
    }
}

// ---------------------------------------------------------------------------
// Plain bf16 MFMA GEMM (v, Y): C[m,n] = sum_k A[m,k]*B[n,k], A/B pre-converted
// u16 bf16 (pure global_load_lds staging). 128x128, BK=64 panel layout,
// double-buffered 2-phase, XCD swizzle.
// ---------------------------------------------------------------------------
__global__ __launch_bounds__(256) void gemm_bf16(
    const u16* __restrict__ Ab, const u16* __restrict__ Bb,
    void* __restrict__ Cdst, int cmode, const int* __restrict__ flag,
    int M, int N, int K)
{
    __shared__ u16 As[2][2][128][32];   // [dbuf][ks][row][k]  32 KB
    __shared__ u16 Bs[2][2][128][32];   // 64 KB total
    const int cbf = (cmode == 1) ? *flag : 0;

    int bx, by; swizzle_block(bx, by);
    const int bm = by * 128, bn = bx * 128;
    const int tid = threadIdx.x;
    const int l = tid & 63, w = tid >> 6;
    const int mbase = (w & 1) * 64, nbase = (w >> 1) * 64;
    const int lrow = l & 15, kq = (l >> 4) << 3;

    frag_cd acc[4][4];
    #pragma unroll
    for (int i = 0; i < 4; ++i)
        #pragma unroll
        for (int j = 0; j < 4; ++j)
            #pragma unroll
            for (int r = 0; r < 4; ++r) acc[i][j][r] = 0.0f;

    auto STAGE = [&](int buf, int k0) {
        #pragma unroll
        for (int half = 0; half < 4; ++half) {
            const int c   = tid + half * 256;
            const int ks  = c >> 9;
            const int row = (c >> 2) & 127;
            const int ko  = ks * 32 + (c & 3) * 8;
            const size_t ga = (size_t)(bm + row) * K + k0 + ko;
            const size_t gb = (size_t)(bn + row) * K + k0 + ko;
            gl_lds16(Ab + ga, &As[buf][0][0][0] + (c << 3));
            gl_lds16(Bb + gb, &Bs[buf][0][0][0] + (c << 3));
        }
    };

    STAGE(0, 0);
    __syncthreads();
    const int NT = K >> 6;
    int cur = 0;
    for (int t = 0; t < NT; ++t) {
        if (t + 1 < NT) STAGE(cur ^ 1, (t + 1) << 6);
        #pragma unroll
        for (int ks = 0; ks < 2; ++ks) {
            frag_ab a[4], b[4];
            #pragma unroll
            for (int i = 0; i < 4; ++i)
                a[i] = *(const frag_ab*)&As[cur][ks][mbase + 16 * i + lrow][kq];
            #pragma unroll
            for (int j = 0; j < 4; ++j)
                b[j] = *(const frag_ab*)&Bs[cur][ks][nbase + 16 * j + lrow][kq];
            #pragma unroll
            for (int i = 0; i < 4; ++i)
                #pragma unroll
                for (int j = 0; j < 4; ++j)
                    acc[i][j] = __builtin_amdgcn_mfma_f32_16x16x32_bf16(
                        a[i], b[j], acc[i][j], 0, 0, 0);
        }
        __syncthreads();
        cur ^= 1;
    }

    const int quad = l >> 4;
    #pragma unroll
    for (int i = 0; i < 4; ++i) {
        #pragma unroll
        for (int j = 0; j < 4; ++j) {
            const int coln = bn + nbase + 16 * j + lrow;
            #pragma unroll
            for (int r = 0; r < 4; ++r) {
                const int rowm = bm + mbase + 16 * i + quad * 4 + r;
                const size_t idx = (size_t)rowm * N + coln;
                float v = acc[i][j][r];
                if (cbf) ((u16*)Cdst)[idx] = f2bf(v);
                else     ((float*)Cdst)[idx] = v;
            }
        }
    }
}

// ---------------------------------------------------------------------------
// fused conv_split: x -> (Xh,Xl), Wup -> (Wh,Wl). Ranges block-aligned
// (NX/4 = 8192 blocks, NC/4 = 1024 blocks) so no intra-block divergence.
// ---------------------------------------------------------------------------
__global__ __launch_bounds__(256) void prep_q0_k(
    const void* __restrict__ x, const void* __restrict__ wup,
    u16* __restrict__ Xh, u16* __restrict__ Xl,
    u16* __restrict__ Wh, u16* __restrict__ Wl,
    const int* __restrict__ flag)
{
    int i = blockIdx.x * 256 + threadIdx.x;
    const int n4x = (NTOK * C_) / 4;
    const void* src; u16 *H, *L; int idx;
    if (i < n4x) { src = x;   H = Xh; L = Xl; idx = i; }
    else         { src = wup; H = Wh; L = Wl; idx = i - n4x; }
    float f[4];
    if (*flag) {
        u16x4 u = ((const u16x4*)src)[idx];
        f[0] = bf2f(u[0]); f[1] = bf2f(u[1]); f[2] = bf2f(u[2]); f[3] = bf2f(u[3]);
    } else {
        float4 v = ((const float4*)src)[idx];
        f[0] = v.x; f[1] = v.y; f[2] = v.z; f[3] = v.w;
    }
    u16x4 h, lo;
    #pragma unroll
    for (int r = 0; r < 4; ++r) { u16 a, b; split2(f[r], a, b); h[r] = a; lo[r] = b; }
    ((u16x4*)H)[idx] = h; ((u16x4*)L)[idx] = lo;
}

// fused bf16 pre-convert: x -> xb, Wv -> wvb, Wproj -> wpb (block-aligned ranges)
__global__ __launch_bounds__(256) void prep_vy_k(
    const void* __restrict__ x, const void* __restrict__ wv,
    const void* __restrict__ wp,
    u16* __restrict__ xb, u16* __restrict__ wvb, u16* __restrict__ wpb,
    const int* __restrict__ flag)
{
    int i = blockIdx.x * 256 + threadIdx.x;
    const int n4x = (NTOK * C_) / 4;
    const int n4c = (C_ * C_) / 4;
    const void* src; u16* out; int idx;
    if (i < n4x)            { src = x;  out = xb;  idx = i; }
    else if (i < n4x + n4c) { src = wv; out = wvb; idx = i - n4x; }
    else                    { src = wp; out = wpb; idx = i - n4x - n4c; }
    u16x4 o;
    if (*flag) {
        o = ((const u16x4*)src)[idx];
    } else {
        float4 v = ((const float4*)src)[idx];
        o[0] = f2bf(v.x); o[1] = f2bf(v.y); o[2] = f2bf(v.z); o[3] = f2bf(v.w);
    }
    ((u16x4*)out)[idx] = o;
}

// fused qv + q-store: qvout = bf16(recon(q)*v); d_out[NX + i] = recon(q)
// (reads q-split once for both jobs; bit-identical to qvb_k + store_split_k)
__global__ __launch_bounds__(256) void qv_store_k(
    const u16* __restrict__ qh, const u16* __restrict__ ql,
    const float* __restrict__ V, u16* __restrict__ qvout,
    void* __restrict__ out, const int* __restrict__ flag)
{
    int i = blockIdx.x * 256 + threadIdx.x;
    u16x4 h = ((const u16x4*)qh)[i], lo = ((const u16x4*)ql)[i];
    float4 v = ((const float4*)V)[i];
    float r0 = bf2f(h[0]) + bf2f(lo[0]);
    float r1 = bf2f(h[1]) + bf2f(lo[1]);
    float r2 = bf2f(h[2]) + bf2f(lo[2]);
    float r3 = bf2f(h[3]) + bf2f(lo[3]);
    u16x4 o;
    o[0] = f2bf(r0 * v.x); o[1] = f2bf(r1 * v.y);
    o[2] = f2bf(r2 * v.z); o[3] = f2bf(r3 * v.w);
    ((u16x4*)qvout)[i] = o;
    const size_t off4 = (size_t)(NTOK * C_) / 4;
    if (*flag) {
        u16x4 q; q[0] = f2bf(r0); q[1] = f2bf(r1); q[2] = f2bf(r2); q[3] = f2bf(r3);
        ((u16x4*)out)[off4 + i] = q;
    } else {
        float4 f; f.x = r0; f.y = r1; f.z = r2; f.w = r3;
        ((float4*)out)[off4 + i] = f;
    }
}

// idW[j] = sum_i identf[i] * W[i,j] — 64 blocks x 16 rows, atomic combine
__global__ __launch_bounds__(256) void idw2_k(
    const float* __restrict__ identf, const float* __restrict__ W,
    float* __restrict__ idW)
{
    const int b = blockIdx.x;
    const int j = threadIdx.x;
    float a0 = 0, a1 = 0, a2 = 0, a3 = 0;
    #pragma unroll
    for (int ii = 0; ii < 16; ++ii) {
        const int i = b * 16 + ii;
        const float s = identf[i];
        const float* row = W + (size_t)i * C_;
        a0 += s * row[j];
        a1 += s * row[j + 256];
        a2 += s * row[j + 512];
        a3 += s * row[j + 768];
    }
    atomicAdd(idW + j, a0);       atomicAdd(idW + j + 256, a1);
    atomicAdd(idW + j + 512, a2); atomicAdd(idW + j + 768, a3);
}

// ---------------------------------------------------------------------------
// scan combine (2-barrier, proven round 8/9 structure); xW now carried as
// split bf16 pairs (recon err 2^-18, same operation proven in the round-9 NS
// split-D epilogue): halves the xW read traffic and the GEMM's C-write.
// idW (boundary left operand) stays f32.
// ---------------------------------------------------------------------------
__global__ __launch_bounds__(256) void combine5_k(
    const u16* __restrict__ curh, const u16* __restrict__ curl,
    const u16* __restrict__ xWh, const u16* __restrict__ xWl,
    const float* __restrict__ idW, const float* __restrict__ identf,
    u16* __restrict__ nxth, u16* __restrict__ nxtl, int d)
{
    const int token = blockIdx.x;
    const int t = token & (T_ - 1);
    const int tid = threadIdx.x;
    const bool hl = (t >= d);
    const size_t rbase = (size_t)token * C_;
    const size_t lbase = hl ? (size_t)(token - d) * C_ : 0;

    const int e0   = tid << 2;          // element base (4 consecutive)
    const int a    = tid >> 6;          // SDPA lane owned by this wave
    const int dd   = (tid & 63) << 2;   // within-lane element offset
    const int lane = tid & 63;

    float q4[4], k4[4], v4[4];
    {
        u16x4 kh = *(const u16x4*)&curh[rbase + e0];
        u16x4 kl = *(const u16x4*)&curl[rbase + e0];
        #pragma unroll
        for (int e = 0; e < 4; ++e) k4[e] = bf2f(kh[e]) + bf2f(kl[e]);
        u16x4 rwh = *(const u16x4*)&xWh[rbase + e0];
        u16x4 rwl = *(const u16x4*)&xWl[rbase + e0];
        float rw[4];
        #pragma unroll
        for (int e = 0; e < 4; ++e) rw[e] = bf2f(rwh[e]) + bf2f(rwl[e]);
        if (hl) {
            u16x4 qh = *(const u16x4*)&curh[lbase + e0];
            u16x4 ql = *(const u16x4*)&curl[lbase + e0];
            #pragma unroll
            for (int e = 0; e < 4; ++e) q4[e] = bf2f(qh[e]) + bf2f(ql[e]);
            u16x4 lwh = *(const u16x4*)&xWh[lbase + e0];
            u16x4 lwl = *(const u16x4*)&xWl[lbase + e0];
            #pragma unroll
            for (int e = 0; e < 4; ++e)
                v4[e] = bf2f(lwh[e]) + bf2f(lwl[e]) + rw[e];
        } else {
            float4 iv = *(const float4*)&identf[e0];
            q4[0] = iv.x; q4[1] = iv.y; q4[2] = iv.z; q4[3] = iv.w;
            float4 lw = *(const float4*)&idW[e0];
            v4[0] = lw.x + rw[0]; v4[1] = lw.y + rw[1];
            v4[2] = lw.z + rw[2]; v4[3] = lw.w + rw[3];
        }
    }

    __shared__ float ks[4][256];
    __shared__ float vs[4][256];
    __shared__ float red[16];
    {
        float4 kv = { k4[0], k4[1], k4[2], k4[3] };
        float4 vv = { v4[0], v4[1], v4[2], v4[3] };
        *(float4*)&ks[a][dd] = kv;
        *(float4*)&vs[a][dd] = vv;
    }
    __syncthreads();

    // wave a computes scores S[a][b] = (1/16) * sum_d q[a][d] k[b][d]
    #pragma unroll
    for (int b = 0; b < 4; ++b) {
        float4 kk = *(const float4*)&ks[b][dd];
        float pp = q4[0] * kk.x + q4[1] * kk.y + q4[2] * kk.z + q4[3] * kk.w;
        float sb = wave_reduce(pp);
        if (lane == 0) red[a * 4 + b] = sb * 0.0625f;
    }
    __syncthreads();

    // per-thread softmax of row a
    float s0 = red[a * 4 + 0], s1 = red[a * 4 + 1];
    float s2 = red[a * 4 + 2], s3 = red[a * 4 + 3];
    float mx = fmaxf(fmaxf(s0, s1), fmaxf(s2, s3));
    float x0 = __expf(s0 - mx), x1 = __expf(s1 - mx);
    float x2 = __expf(s2 - mx), x3 = __expf(s3 - mx);
    float inv = 1.0f / (x0 + x1 + x2 + x3);
    const float a0 = x0 * inv, a1 = x1 * inv, a2 = x2 * inv, a3 = x3 * inv;

    // z[a][d] = sum_b att[a][b] v[b][d]
    float4 v0 = *(const float4*)&vs[0][dd];
    float4 v1 = *(const float4*)&vs[1][dd];
    float4 v2 = *(const float4*)&vs[2][dd];
    float4 v3 = *(const float4*)&vs[3][dd];
    float z4[4];
    z4[0] = a0 * v0.x + a1 * v1.x + a2 * v2.x + a3 * v3.x;
    z4[1] = a0 * v0.y + a1 * v1.y + a2 * v2.y + a3 * v3.y;
    z4[2] = a0 * v0.z + a1 * v1.z + a2 * v2.z + a3 * v3.z;
    z4[3] = a0 * v0.w + a1 * v1.w + a2 * v2.w + a3 * v3.w;

    // rms over lane a's 256 elements; lane-0 total broadcast via shfl
    float ssp = z4[0] * z4[0] + z4[1] * z4[1] + z4[2] * z4[2] + z4[3] * z4[3];
    float ss = wave_reduce(ssp);
    ss = __shfl(ss, 0, 64);
    const float rs = rsqrtf(ss * (1.0f / HD) + 1e-8f) * (1.0f / (float)(a + 1));

    u16x4 oh, ol;
    #pragma unroll
    for (int e = 0; e < 4; ++e) {
        float out = q4[e] + z4[e] * rs;
        u16 hi, lo; split2(out, hi, lo);
        oh[e] = hi; ol[e] = lo;
    }
    *(u16x4*)&nxth[rbase + e0] = oh;
    *(u16x4*)&nxtl[rbase + e0] = ol;
}

// ---------------------------------------------------------------------------
extern "C" void kernel_launch(void* const* d_in, const int* in_sizes, int n_in,
                              void* d_out, int out_size, void* d_ws, size_t ws_size,
                              hipStream_t stream)
{
    const void* x     = d_in[0];
    const void* Wup   = d_in[1];
    const void* Wv    = d_in[2];
    const void* Wproj = d_in[3];
    const void* ident = d_in[4];
    const void* Wraw  = d_in[5];

    float* ws = (float*)d_ws;
    int*   flagp  = (int*)ws;                    // meta[0]
    float* sumsqp = ws + 1;                      // meta[1]
    float* W0     = ws + 256;                    // 1M f32 (scaled W_raw)
    float* W1     = W0 + (1 << 20);              // 1M f32 (final polar X)
    float* identf = W1 + (1 << 20);              // 1024
    float* idW    = identf + 1024;               // 1024
    float* F1     = idW + 1024;                  // 8M f32 (xW split / v scratch)
    u16*   WTh    = (u16*)(F1 + (size_t)NTOK * C_);  // W^T split hi (1M u16)
    u16*   WTl    = WTh + (1 << 20);
    u16*   WUh    = WTl + (1 << 20);             // Wup split / NS G / WVb
    u16*   WUl    = WUh + (1 << 20);             //            …       / WPb
    u16*   Q0h    = WUl + (1 << 20);             // q split dbuf A (8M u16 ea)
    u16*   Q0l    = Q0h + (size_t)NTOK * C_;
    u16*   Q1h    = Q0l + (size_t)NTOK * C_;     // q split dbuf B
    u16*   Q1l    = Q1h + (size_t)NTOK * C_;

    const int NC = C_ * C_;          // 1M
    const int NX = NTOK * C_;        // 8M

    // ---- dtype detection ----
    detect_k<<<1, 256, 0, stream>>>((const u16*)Wup, flagp);

    // ---- polar(W_raw): quintic-ramp Newton-Schulz, split-bf16 MFMA ----
    hipMemsetAsync(sumsqp, 0, sizeof(float), stream);
    conv_sumsq_k<<<NC / 256, 256, 0, stream>>>(Wraw, W0, flagp, sumsqp);

    // NS split scratch aliases (Q0 region dead until q0; WU* dead until q0)
    u16* Gh = WUh;  u16* Gl = WUl;
    u16* Xh2[2] = { Q0h,             Q0h + 2 * (1 << 20) };
    u16* Xl2[2] = { Q0h + (1 << 20), Q0h + 3 * (1 << 20) };
    u16* Hh = Q0h + 4 * (1 << 20);
    u16* Hl = Q0h + 5 * (1 << 20);

    scale_split_k<<<NC / 256, 256, 0, stream>>>(W0, sumsqp, Xh2[0], Xl2[0]);
    transpose_split_k<<<dim3(32, 32), 256, 0, stream>>>(W0, WTh, WTl);

    int cur = 0;
    const dim3 gNS(16, 16);
    // quintic ramp: p(x) = aQ x + bQ x^3 + cQ x^5. 8 iters: evidence bound
    // sigma_min >= ~8e-5 (cubic 18+5 converged in rounds <=3) x 3.4445^8
    // (~2e4) saturates into the invariant band [0,1.202]; 4 cubic polishes
    // then converge to 1 (worst band exit 0.68 -> 1-2e-6).
    const float aQ = 3.4445f, bQ = -4.7750f, cQ = 2.0315f;
    for (int it = 0; it < 8; ++it) {
        // G = X^T X
        gemm_split64<<<gNS, 256, 0, stream>>>(WTh, WTl, WTh, WTl,
                                              nullptr, Gh, Gl,
                                              nullptr, nullptr, 0.0f,
                                              nullptr, nullptr, 0.0f, 1.0f,
                                              C_, C_, C_, nullptr, nullptr);
        // H = X G  (G symmetric -> B = G row-major); split output only
        gemm_split64<<<gNS, 256, 0, stream>>>(Xh2[cur], Xl2[cur], Gh, Gl,
                                              nullptr, Hh, Hl,
                                              nullptr, nullptr, 0.0f,
                                              nullptr, nullptr, 0.0f, 1.0f,
                                              C_, C_, C_, nullptr, nullptr);
        // Y = cQ*(H G) + aQ*recon(X) + bQ*recon(H) -> row split + fused W^T
        gemm_split64<<<gNS, 256, 0, stream>>>(Hh, Hl, Gh, Gl,
                                              nullptr, Xh2[cur ^ 1], Xl2[cur ^ 1],
                                              Xh2[cur], Xl2[cur], aQ,
                                              Hh, Hl, bQ, cQ,
                                              C_, C_, C_, WTh, WTl);
        cur ^= 1;
    }
    // cubic polish: x -> 1.5x - 0.5x^3 (4 iters). Final iter writes f32 X
    // (for idw2) and skips the dead row-split.
    for (int it = 0; it < 4; ++it) {
        const bool last = (it == 3);
        gemm_split64<<<gNS, 256, 0, stream>>>(WTh, WTl, WTh, WTl,
                                              nullptr, Gh, Gl,
                                              nullptr, nullptr, 0.0f,
                                              nullptr, nullptr, 0.0f, 1.0f,
                                              C_, C_, C_, nullptr, nullptr);
        gemm_split64<<<gNS, 256, 0, stream>>>(Xh2[cur], Xl2[cur], Gh, Gl,
                                              last ? W1 : nullptr,
                                              last ? nullptr : Xh2[cur ^ 1],
                                              last ? nullptr : Xl2[cur ^ 1],
                                              Xh2[cur], Xl2[cur], 1.5f,
                                              nullptr, nullptr, 0.0f, -0.5f,
                                              C_, C_, C_, WTh, WTl);
        cur ^= 1;
    }
    // W1 = polar(W_raw) f32 ; WTh/WTl = W^T split, ready for the scan

    ident_init_k<<<4, 256, 0, stream>>>(ident, identf, idW, flagp);
    idw2_k<<<64, 256, 0, stream>>>(identf, W1, idW);

    const dim3 g128(C_ / 128, NTOK / 128);   // (8, 64)

    // ---- q0 = x @ Wup^T  (split-bf16 MFMA) ----
    prep_q0_k<<<(NX + NC) / 1024, 256, 0, stream>>>(x, Wup, Q1h, Q1l,
                                                    WUh, WUl, flagp);
    gemm_split<<<g128, 256, 0, stream>>>(Q1h, Q1l, WUh, WUl,
                                         nullptr, Q0h, Q0l, NTOK, C_, C_);

    // ---- scan: 11 Hillis-Steele steps; q AND xW carried as split pairs ----
    u16* Fh = (u16*)F1;                 // xW split hi (16MB)
    u16* Fl = Fh + (size_t)NX;          // xW split lo (16MB) — fills F1 region
    u16 *ch = Q0h, *cl = Q0l, *nh = Q1h, *nl = Q1l;
    for (int d = 1; d < T_; d <<= 1) {
        gemm_split<<<g128, 256, 0, stream>>>(ch, cl, WTh, WTl,
                                             nullptr, Fh, Fl, NTOK, C_, C_);
        combine5_k<<<NTOK, 256, 0, stream>>>(ch, cl, Fh, Fl, idW, identf,
                                             nh, nl, d);
        u16* t1 = ch; ch = nh; nh = t1;
        u16* t2 = cl; cl = nl; nl = t2;
    }
    // 11 steps (odd) -> ch/cl = Q1h/Q1l hold q; Q0*, F1, WU* free

    // ---- pre-convert x / weights to bf16 (one fused dispatch) ----
    prep_vy_k<<<(NX + 2 * NC) / 1024, 256, 0, stream>>>(x, Wv, Wproj,
                                                        Q0h, WUh, WUl, flagp);

    // ---- v = x @ Wv^T  (pure bf16 MFMA) -> F1 f32 ----
    gemm_bf16<<<g128, 256, 0, stream>>>(Q0h, WUh, F1, 0, flagp, NTOK, C_, C_);

    // ---- qv = q.*v (A for Y GEMM) + second output q -> d_out[NX:2NX] ----
    qv_store_k<<<NX / 1024, 256, 0, stream>>>(ch, cl, F1, Q0l, d_out, flagp);

    // ---- Y = (q .* v) @ Wproj^T -> d_out[0:NX] ----
    gemm_bf16<<<g128, 256, 0, stream>>>(Q0l, WUl, d_out, 1, flagp, NTOK, C_, C_);
}